// Round 8
// baseline (611.456 us; speedup 1.0000x reference)
//
#include <hip/hip_runtime.h>
#include <hip/hip_bf16.h>

#define B_    4
#define KL_   128
#define XL_   4096
#define DIM_  256
#define H_    8
#define HD_   32
#define PB_   8
#define NDIS_ 66
#define TDIM_ 768
#define SCALE_ 0.17677669529663687f

// ---------------------------------------------------------------------------
// 128x128 f32 GEMM, BK=8, 8x8 per thread.
// ---------------------------------------------------------------------------
__global__ __launch_bounds__(256) void gemm128(const float* __restrict__ A,
                                               const float* __restrict__ Bw,
                                               float* __restrict__ C,
                                               const float* __restrict__ bias,
                                               int M, int N, int K) {
    __shared__ __align__(16) float As[8][132];
    __shared__ __align__(16) float Bs[8][128];
    const int tid = threadIdx.x;
    const int tx = tid & 15, ty = tid >> 4;
    const int bn = blockIdx.x * 128, bm = blockIdx.y * 128;
    const int arow = tid >> 1, acol = (tid & 1) * 4;
    const int brow = tid >> 5, bcol = (tid & 31) * 4;
    float acc[8][8] = {};
    for (int k0 = 0; k0 < K; k0 += 8) {
        float4 a4 = *(const float4*)&A[(size_t)(bm + arow) * K + k0 + acol];
        As[acol + 0][arow] = a4.x;
        As[acol + 1][arow] = a4.y;
        As[acol + 2][arow] = a4.z;
        As[acol + 3][arow] = a4.w;
        *(float4*)&Bs[brow][bcol] = *(const float4*)&Bw[(size_t)(k0 + brow) * N + bn + bcol];
        __syncthreads();
#pragma unroll
        for (int kk = 0; kk < 8; ++kk) {
            float4 a0 = *(const float4*)&As[kk][ty * 8];
            float4 a1 = *(const float4*)&As[kk][ty * 8 + 4];
            float4 b0 = *(const float4*)&Bs[kk][tx * 8];
            float4 b1 = *(const float4*)&Bs[kk][tx * 8 + 4];
            float a[8] = {a0.x, a0.y, a0.z, a0.w, a1.x, a1.y, a1.z, a1.w};
            float b[8] = {b0.x, b0.y, b0.z, b0.w, b1.x, b1.y, b1.z, b1.w};
#pragma unroll
            for (int i = 0; i < 8; ++i)
#pragma unroll
                for (int j = 0; j < 8; ++j) acc[i][j] += a[i] * b[j];
        }
        __syncthreads();
    }
#pragma unroll
    for (int i = 0; i < 8; ++i) {
        int m = bm + ty * 8 + i;
        float* cp = &C[(size_t)m * N + bn + tx * 8];
        float4 o0 = {acc[i][0], acc[i][1], acc[i][2], acc[i][3]};
        float4 o1 = {acc[i][4], acc[i][5], acc[i][6], acc[i][7]};
        if (bias) {
            const float* bp = &bias[bn + tx * 8];
            o0.x += bp[0]; o0.y += bp[1]; o0.z += bp[2]; o0.w += bp[3];
            o1.x += bp[4]; o1.y += bp[5]; o1.z += bp[6]; o1.w += bp[7];
        }
        *(float4*)cp = o0;
        *(float4*)(cp + 4) = o1;
    }
}

// ---------------------------------------------------------------------------
// 64x64 f32 GEMM (small-M)
// ---------------------------------------------------------------------------
__global__ __launch_bounds__(256) void gemm64(const float* __restrict__ A,
                                              const float* __restrict__ Bw,
                                              float* __restrict__ C,
                                              const float* __restrict__ bias,
                                              int M, int N, int K) {
    __shared__ __align__(16) float As[16][68];
    __shared__ __align__(16) float Bs[16][64];
    const int tid = threadIdx.x;
    const int tx = tid & 15, ty = tid >> 4;
    const int bn = blockIdx.x * 64, bm = blockIdx.y * 64;
    const int am = tid >> 2, ac = tid & 3;
    float acc[4][4] = {};
    for (int k0 = 0; k0 < K; k0 += 16) {
        float4 a4 = *(const float4*)&A[(size_t)(bm + am) * K + k0 + ac * 4];
        As[ac * 4 + 0][am] = a4.x;
        As[ac * 4 + 1][am] = a4.y;
        As[ac * 4 + 2][am] = a4.z;
        As[ac * 4 + 3][am] = a4.w;
        *(float4*)&Bs[ty][tx * 4] = *(const float4*)&Bw[(size_t)(k0 + ty) * N + bn + tx * 4];
        __syncthreads();
#pragma unroll
        for (int kk = 0; kk < 16; ++kk) {
            float4 av = *(const float4*)&As[kk][ty * 4];
            float4 bv = *(const float4*)&Bs[kk][tx * 4];
            float a[4] = {av.x, av.y, av.z, av.w};
            float b[4] = {bv.x, bv.y, bv.z, bv.w};
#pragma unroll
            for (int i = 0; i < 4; ++i)
#pragma unroll
                for (int j = 0; j < 4; ++j) acc[i][j] += a[i] * b[j];
        }
        __syncthreads();
    }
#pragma unroll
    for (int i = 0; i < 4; ++i) {
        int m = bm + ty * 4 + i;
#pragma unroll
        for (int j = 0; j < 4; ++j) {
            int n = bn + tx * 4 + j;
            float v = acc[i][j];
            if (bias) v += bias[n];
            C[(size_t)m * N + n] = v;
        }
    }
}

// ---------------------------------------------------------------------------
// Fused k-direction attention. Block = (b, h, 4 k-rows); 256 thr = 4 waves.
// Wave w: k-pair p=w&1 (rows k0+2p, k0+2p+1), x-half hx=w>>1 (2048 x).
// Phase 1: scores once (f32) -> exact-f32 polar bins + running max;
//          store (masked score + dis_embed) as packed bf16 in LDS.
// Argmax barrier -> main_ori + per-row upper bound M' = max(s'')+max(pe).
// Phase 3: branch-free p=exp(s''+pe-M'), acc += p*V (KR=2 reuse of V reads).
// ---------------------------------------------------------------------------
__global__ __launch_bounds__(256, 2) void attn_k_fused2(const float* __restrict__ qkv_k,
                                                        const float* __restrict__ qkv_x,
                                                        const int* __restrict__ rd,
                                                        const int* __restrict__ polar_pos,
                                                        const int* __restrict__ att_mask,
                                                        const float* __restrict__ dis_embed,
                                                        const float* __restrict__ polar_emb,
                                                        int* __restrict__ main_ori,
                                                        float* __restrict__ kout_pre) {
    const int b = blockIdx.z, h = blockIdx.y, k0 = blockIdx.x * 4;
    const int tid = threadIdx.x;
    const int w = tid >> 6, lane = tid & 63;
    const int p = w & 1, hx = w >> 1;
    const int ka = k0 + 2 * p, kb = ka + 1;
    const int id2 = p * 64 + lane;   // 0..127 within wave-pair hx

    __shared__ unsigned scp[2][XL_];                 // 32 KB packed bf16 scores
    __shared__ __align__(16) float4 xsT[2][8][66];   // K then V tiles, per half
    __shared__ int msk_s[2][64][4];
    __shared__ float de[NDIS_ * H_];
    __shared__ float pe[PB_];
    __shared__ float binsbuf[4][2][PB_];
    __shared__ float smaxbuf[4][2];
    __shared__ float Mp_s[4];
    __shared__ int mo_s[4];
    __shared__ float mergebuf[4][2][34];

    for (int i = tid; i < NDIS_ * H_; i += 256) de[i] = dis_embed[i];
    if (tid < PB_) pe[tid] = polar_emb[tid];

    // k_q rows in registers
    float4 kqa[8], kqb[8];
    {
        const float* pa = &qkv_k[(size_t)(b * KL_ + ka) * TDIM_ + h * HD_];
        const float* pb = &qkv_k[(size_t)(b * KL_ + kb) * TDIM_ + h * HD_];
#pragma unroll
        for (int c = 0; c < 8; ++c) {
            kqa[c] = *(const float4*)&pa[c * 4];
            kqb[c] = *(const float4*)&pb[c * 4];
        }
    }

    const size_t xrowbase = (size_t)b * XL_;
    const size_t bh = (size_t)(b * H_ + h);
    const size_t prow_a = (size_t)(b * KL_ + ka) * XL_;
    const size_t prow_b = (size_t)(b * KL_ + kb) * XL_;
    const int xbeg = hx * 2048;

    // ---------------- phase 1: scores + bins ----------------
    float bins_a[PB_] = {}, bins_b[PB_] = {};
    float smax_a = -3e38f, smax_b = -3e38f;
    __syncthreads();   // de/pe ready
    for (int t = 0; t < 32; ++t) {
        const int x0 = xbeg + t * 64;
        __syncthreads();
#pragma unroll
        for (int i = 0; i < 4; ++i) {
            int f = id2 + 128 * i;
            int row = f >> 3, c = f & 7;
            xsT[hx][c][row] =
                *(const float4*)&qkv_x[(xrowbase + x0 + row) * TDIM_ + DIM_ + h * HD_ + c * 4];
        }
        if (id2 < 64)
            *(int4*)&msk_s[hx][id2][0] = *(const int4*)&att_mask[(bh * XL_ + x0 + id2) * KL_ + k0];
        __syncthreads();
        const int x = x0 + lane;
        float sa = 0.f, sb = 0.f;
#pragma unroll
        for (int c = 0; c < 8; ++c) {
            float4 kx = xsT[hx][c][lane];
            sa += kqa[c].x * kx.x + kqa[c].y * kx.y + kqa[c].z * kx.z + kqa[c].w * kx.w;
            sb += kqb[c].x * kx.x + kqb[c].y * kx.y + kqb[c].z * kx.z + kqb[c].w * kx.w;
        }
        sa *= SCALE_; sb *= SCALE_;
        int pa = polar_pos[prow_a + x];
        int pb2 = polar_pos[prow_b + x];
        int ra = rd[prow_a + x];
        int rb = rd[prow_b + x];
        float aa = fabsf(sa), ab = fabsf(sb);
#pragma unroll
        for (int q = 0; q < PB_; ++q) {
            bins_a[q] += (pa == q) ? aa : 0.0f;
            bins_b[q] += (pb2 == q) ? ab : 0.0f;
        }
        int ma = msk_s[hx][lane][2 * p];
        int mb = msk_s[hx][lane][2 * p + 1];
        float spa = (ma ? -1e6f : sa) + de[ra * H_ + h];
        float spb = (mb ? -1e6f : sb) + de[rb * H_ + h];
        smax_a = fmaxf(smax_a, spa);
        smax_b = fmaxf(smax_b, spb);
        __hip_bfloat16 bfa = __float2bfloat16(spa);
        __hip_bfloat16 bfb = __float2bfloat16(spb);
        unsigned ua = *(unsigned short*)&bfa;
        unsigned ub = *(unsigned short*)&bfb;
        scp[p][x] = ua | (ub << 16);
    }
    // reduce bins + smax over the 64-lane wave
#pragma unroll
    for (int m = 1; m < 64; m <<= 1) {
#pragma unroll
        for (int q = 0; q < PB_; ++q) {
            bins_a[q] += __shfl_xor(bins_a[q], m);
            bins_b[q] += __shfl_xor(bins_b[q], m);
        }
        smax_a = fmaxf(smax_a, __shfl_xor(smax_a, m));
        smax_b = fmaxf(smax_b, __shfl_xor(smax_b, m));
    }
    if (lane == 0) {
#pragma unroll
        for (int q = 0; q < PB_; ++q) {
            binsbuf[2 * p][hx][q] = bins_a[q];
            binsbuf[2 * p + 1][hx][q] = bins_b[q];
        }
        smaxbuf[2 * p][hx] = smax_a;
        smaxbuf[2 * p + 1][hx] = smax_b;
    }
    __syncthreads();
    if (tid < 4) {
        float s[PB_];
#pragma unroll
        for (int q = 0; q < PB_; ++q) s[q] = binsbuf[tid][0][q] + binsbuf[tid][1][q];
        float best = s[0];
        int bi = 0;
#pragma unroll
        for (int q = 1; q < PB_; ++q)
            if (s[q] > best) { best = s[q]; bi = q; }
        mo_s[tid] = bi;
        main_ori[(b * H_ + h) * KL_ + k0 + tid] = bi;
        float pmax = pe[0];
#pragma unroll
        for (int q = 1; q < PB_; ++q) pmax = fmaxf(pmax, pe[q]);
        Mp_s[tid] = fmaxf(smaxbuf[tid][0], smaxbuf[tid][1]) + pmax;
    }
    __syncthreads();

    // ---------------- phase 3: exp + AV ----------------
    const int mo_a = mo_s[2 * p], mo_b = mo_s[2 * p + 1];
    const float Ma = Mp_s[2 * p], Mb = Mp_s[2 * p + 1];
    float la = 0.f, lb = 0.f;
    float4 accA[8] = {}, accB[8] = {};
    for (int t = 0; t < 32; ++t) {
        const int x0 = xbeg + t * 64;
        __syncthreads();
#pragma unroll
        for (int i = 0; i < 4; ++i) {
            int f = id2 + 128 * i;
            int row = f >> 3, c = f & 7;
            xsT[hx][c][row] =
                *(const float4*)&qkv_x[(xrowbase + x0 + row) * TDIM_ + 2 * DIM_ + h * HD_ + c * 4];
        }
        __syncthreads();
        const int x = x0 + lane;
        unsigned u = scp[p][x];
        float spa = __uint_as_float(u << 16);
        float spb = __uint_as_float(u & 0xffff0000u);
        int pa = polar_pos[prow_a + x];
        int pb2 = polar_pos[prow_b + x];
        int na = pa - mo_a; na += (na >> 31) & PB_;
        int nb = pb2 - mo_b; nb += (nb >> 31) & PB_;
        float pA = expf(spa + pe[na] - Ma);
        float pB = expf(spb + pe[nb] - Mb);
        la += pA; lb += pB;
#pragma unroll
        for (int c = 0; c < 8; ++c) {
            float4 v = xsT[hx][c][lane];
            accA[c].x += pA * v.x; accA[c].y += pA * v.y; accA[c].z += pA * v.z; accA[c].w += pA * v.w;
            accB[c].x += pB * v.x; accB[c].y += pB * v.y; accB[c].z += pB * v.z; accB[c].w += pB * v.w;
        }
    }
    // reduce over 64 lanes
#pragma unroll
    for (int m = 1; m < 64; m <<= 1) {
        la += __shfl_xor(la, m);
        lb += __shfl_xor(lb, m);
#pragma unroll
        for (int c = 0; c < 8; ++c) {
            accA[c].x += __shfl_xor(accA[c].x, m);
            accA[c].y += __shfl_xor(accA[c].y, m);
            accA[c].z += __shfl_xor(accA[c].z, m);
            accA[c].w += __shfl_xor(accA[c].w, m);
            accB[c].x += __shfl_xor(accB[c].x, m);
            accB[c].y += __shfl_xor(accB[c].y, m);
            accB[c].z += __shfl_xor(accB[c].z, m);
            accB[c].w += __shfl_xor(accB[c].w, m);
        }
    }
    if (lane == 0) {
        mergebuf[2 * p][hx][0] = la;
        mergebuf[2 * p + 1][hx][0] = lb;
#pragma unroll
        for (int c = 0; c < 8; ++c) {
            mergebuf[2 * p][hx][1 + c * 4 + 0] = accA[c].x;
            mergebuf[2 * p][hx][1 + c * 4 + 1] = accA[c].y;
            mergebuf[2 * p][hx][1 + c * 4 + 2] = accA[c].z;
            mergebuf[2 * p][hx][1 + c * 4 + 3] = accA[c].w;
            mergebuf[2 * p + 1][hx][1 + c * 4 + 0] = accB[c].x;
            mergebuf[2 * p + 1][hx][1 + c * 4 + 1] = accB[c].y;
            mergebuf[2 * p + 1][hx][1 + c * 4 + 2] = accB[c].z;
            mergebuf[2 * p + 1][hx][1 + c * 4 + 3] = accB[c].w;
        }
    }
    __syncthreads();
    if (tid < 128) {
        int k = tid >> 5, d = tid & 31;
        float num = mergebuf[k][0][1 + d] + mergebuf[k][1][1 + d];
        float den = mergebuf[k][0][0] + mergebuf[k][1][0];
        kout_pre[(size_t)(b * KL_ + k0 + k) * DIM_ + h * HD_ + d] = num / den;
    }
}

// ---------------------------------------------------------------------------
// x-direction attention (unchanged)
// ---------------------------------------------------------------------------
__global__ __launch_bounds__(256) void attn_x(const float* __restrict__ qkv_x,
                                              const float* __restrict__ qkv_k,
                                              const int* __restrict__ rd,
                                              const int* __restrict__ polar_pos,
                                              const int* __restrict__ att_mask,
                                              const float* __restrict__ dis_embed,
                                              const float* __restrict__ polar_emb,
                                              const int* __restrict__ main_ori,
                                              float* __restrict__ xout_pre) {
    const int b = blockIdx.z, h = blockIdx.y;
    const int x0 = blockIdx.x * 16;
    const int tid = threadIdx.x;
    __shared__ __align__(16) float kk_s[KL_][36];
    __shared__ __align__(16) float kv_s[KL_][36];
    __shared__ __align__(16) float q_s[16][36];
    __shared__ float de[NDIS_ * H_];
    __shared__ float pe[PB_];
    __shared__ int mo_s[KL_];

    for (int i = tid; i < KL_ * HD_; i += 256) {
        int kk = i >> 5, d = i & 31;
        size_t base = (size_t)(b * KL_ + kk) * TDIM_ + h * HD_ + d;
        kk_s[kk][d] = qkv_k[base + DIM_];
        kv_s[kk][d] = qkv_k[base + 2 * DIM_];
    }
    for (int i = tid; i < 16 * HD_; i += 256) {
        int xl = i >> 5, d = i & 31;
        q_s[xl][d] = qkv_x[(size_t)(b * XL_ + x0 + xl) * TDIM_ + h * HD_ + d];
    }
    for (int i = tid; i < NDIS_ * H_; i += 256) de[i] = dis_embed[i];
    if (tid < PB_) pe[tid] = polar_emb[tid];
    if (tid < KL_) mo_s[tid] = main_ori[(b * H_ + h) * KL_ + tid];
    __syncthreads();

    const int xl = tid >> 4, r = tid & 15;
    const int x = x0 + xl;
    float t[8];
    float lmax = -3e38f;
    const size_t mrow = ((size_t)(b * H_ + h) * XL_ + x) * KL_;
#pragma unroll
    for (int j = 0; j < 8; ++j) {
        int kk = j * 16 + r;
        float s = 0.f;
#pragma unroll
        for (int d4 = 0; d4 < 8; ++d4) {
            float4 a = *(const float4*)&q_s[xl][d4 * 4];
            float4 bb = *(const float4*)&kk_s[kk][d4 * 4];
            s += a.x * bb.x + a.y * bb.y + a.z * bb.z + a.w * bb.w;
        }
        s *= SCALE_;
        int msk = att_mask[mrow + kk];
        size_t pidx = (size_t)(b * KL_ + kk) * XL_ + x;
        int rv = rd[pidx];
        int pp = polar_pos[pidx];
        int npb = pp - mo_s[kk];
        npb += (npb >> 31) & PB_;
        t[j] = (msk ? -1e9f : s) + de[rv * H_ + h] + pe[npb];
        lmax = fmaxf(lmax, t[j]);
    }
#pragma unroll
    for (int m = 1; m < 16; m <<= 1) lmax = fmaxf(lmax, __shfl_xor(lmax, m, 16));
    float lsum = 0.f;
#pragma unroll
    for (int j = 0; j < 8; ++j) {
        t[j] = expf(t[j] - lmax);
        lsum += t[j];
    }
#pragma unroll
    for (int m = 1; m < 16; m <<= 1) lsum += __shfl_xor(lsum, m, 16);

    float acc[HD_] = {};
#pragma unroll
    for (int j = 0; j < 8; ++j) {
        int kk = j * 16 + r;
        float e = t[j];
#pragma unroll
        for (int d = 0; d < HD_; d += 4) {
            float4 vv = *(const float4*)&kv_s[kk][d];
            acc[d + 0] += e * vv.x;
            acc[d + 1] += e * vv.y;
            acc[d + 2] += e * vv.z;
            acc[d + 3] += e * vv.w;
        }
    }
#pragma unroll
    for (int d = 0; d < HD_; ++d)
#pragma unroll
        for (int m = 1; m < 16; m <<= 1) acc[d] += __shfl_xor(acc[d], m, 16);
    if (r == 0) {
        float inv = 1.0f / lsum;
        float* op = xout_pre + (size_t)(b * XL_ + x) * DIM_ + h * HD_;
#pragma unroll
        for (int d = 0; d < HD_; ++d) op[d] = acc[d] * inv;
    }
}

// ---------------------------------------------------------------------------
extern "C" void kernel_launch(void* const* d_in, const int* in_sizes, int n_in,
                              void* d_out, int out_size, void* d_ws, size_t ws_size,
                              hipStream_t stream) {
    const float* x         = (const float*)d_in[0];
    const float* kernal    = (const float*)d_in[1];
    const int* rd          = (const int*)d_in[2];
    const int* polar_pos   = (const int*)d_in[3];
    const int* att_mask    = (const int*)d_in[4];
    const float* W_qkv     = (const float*)d_in[5];
    const float* dis_embed = (const float*)d_in[6];
    const float* polar_emb = (const float*)d_in[7];
    const float* W_proj    = (const float*)d_in[8];
    const float* b_proj    = (const float*)d_in[9];
    float* out             = (float*)d_out;

    char* base = (char*)d_ws;
    size_t off = 0;
    auto alloc = [&](size_t bytes) { void* p = base + off; off = (off + bytes + 255) & ~255ULL; return p; };
    float* qkv_x    = (float*)alloc((size_t)B_ * XL_ * TDIM_ * 4);   // 50.3 MB
    float* qkv_k    = (float*)alloc((size_t)B_ * KL_ * TDIM_ * 4);   // 1.6 MB
    float* xout_pre = (float*)alloc((size_t)B_ * XL_ * DIM_ * 4);    // 16.8 MB
    float* kout_pre = (float*)alloc((size_t)B_ * KL_ * DIM_ * 4);    // 0.5 MB
    int* main_ori   = (int*)alloc(B_ * H_ * KL_ * 4);

    gemm128<<<dim3(TDIM_ / 128, (B_ * XL_) / 128), 256, 0, stream>>>(
        x, W_qkv, qkv_x, nullptr, B_ * XL_, TDIM_, DIM_);
    gemm64<<<dim3(TDIM_ / 64, (B_ * KL_) / 64), 256, 0, stream>>>(
        kernal, W_qkv, qkv_k, nullptr, B_ * KL_, TDIM_, DIM_);
    attn_k_fused2<<<dim3(KL_ / 4, H_, B_), 256, 0, stream>>>(
        qkv_k, qkv_x, rd, polar_pos, att_mask, dis_embed, polar_emb, main_ori, kout_pre);
    attn_x<<<dim3(XL_ / 16, H_, B_), 256, 0, stream>>>(
        qkv_x, qkv_k, rd, polar_pos, att_mask, dis_embed, polar_emb, main_ori, xout_pre);
    gemm128<<<dim3(DIM_ / 128, (B_ * XL_) / 128), 256, 0, stream>>>(
        xout_pre, W_proj, out, b_proj, B_ * XL_, DIM_, DIM_);
    gemm64<<<dim3(DIM_ / 64, (B_ * KL_) / 64), 256, 0, stream>>>(
        kout_pre, W_proj, out + (size_t)B_ * XL_ * DIM_, b_proj, B_ * KL_, DIM_, DIM_);
}

// Round 9
// 554.752 us; speedup vs baseline: 1.1022x; 1.1022x over previous
//
#include <hip/hip_runtime.h>
#include <hip/hip_bf16.h>

#define B_    4
#define KL_   128
#define XL_   4096
#define DIM_  256
#define H_    8
#define HD_   32
#define PB_   8
#define NDIS_ 66
#define TDIM_ 768
#define SCALE_ 0.17677669529663687f
#define XT_   64
#define KC_   8
#define NS_   4
#define XCH_  (XL_ / NS_)  // 1024

// ---------------------------------------------------------------------------
// 128x128 f32 GEMM, BK=8, 8x8 per thread.
// ---------------------------------------------------------------------------
__global__ __launch_bounds__(256) void gemm128(const float* __restrict__ A,
                                               const float* __restrict__ Bw,
                                               float* __restrict__ C,
                                               const float* __restrict__ bias,
                                               int M, int N, int K) {
    __shared__ __align__(16) float As[8][132];
    __shared__ __align__(16) float Bs[8][128];
    const int tid = threadIdx.x;
    const int tx = tid & 15, ty = tid >> 4;
    const int bn = blockIdx.x * 128, bm = blockIdx.y * 128;
    const int arow = tid >> 1, acol = (tid & 1) * 4;
    const int brow = tid >> 5, bcol = (tid & 31) * 4;
    float acc[8][8] = {};
    for (int k0 = 0; k0 < K; k0 += 8) {
        float4 a4 = *(const float4*)&A[(size_t)(bm + arow) * K + k0 + acol];
        As[acol + 0][arow] = a4.x;
        As[acol + 1][arow] = a4.y;
        As[acol + 2][arow] = a4.z;
        As[acol + 3][arow] = a4.w;
        *(float4*)&Bs[brow][bcol] = *(const float4*)&Bw[(size_t)(k0 + brow) * N + bn + bcol];
        __syncthreads();
#pragma unroll
        for (int kk = 0; kk < 8; ++kk) {
            float4 a0 = *(const float4*)&As[kk][ty * 8];
            float4 a1 = *(const float4*)&As[kk][ty * 8 + 4];
            float4 b0 = *(const float4*)&Bs[kk][tx * 8];
            float4 b1 = *(const float4*)&Bs[kk][tx * 8 + 4];
            float a[8] = {a0.x, a0.y, a0.z, a0.w, a1.x, a1.y, a1.z, a1.w};
            float b[8] = {b0.x, b0.y, b0.z, b0.w, b1.x, b1.y, b1.z, b1.w};
#pragma unroll
            for (int i = 0; i < 8; ++i)
#pragma unroll
                for (int j = 0; j < 8; ++j) acc[i][j] += a[i] * b[j];
        }
        __syncthreads();
    }
#pragma unroll
    for (int i = 0; i < 8; ++i) {
        int m = bm + ty * 8 + i;
        float* cp = &C[(size_t)m * N + bn + tx * 8];
        float4 o0 = {acc[i][0], acc[i][1], acc[i][2], acc[i][3]};
        float4 o1 = {acc[i][4], acc[i][5], acc[i][6], acc[i][7]};
        if (bias) {
            const float* bp = &bias[bn + tx * 8];
            o0.x += bp[0]; o0.y += bp[1]; o0.z += bp[2]; o0.w += bp[3];
            o1.x += bp[4]; o1.y += bp[5]; o1.z += bp[6]; o1.w += bp[7];
        }
        *(float4*)cp = o0;
        *(float4*)(cp + 4) = o1;
    }
}

// ---------------------------------------------------------------------------
// 64x64 f32 GEMM (small-M)
// ---------------------------------------------------------------------------
__global__ __launch_bounds__(256) void gemm64(const float* __restrict__ A,
                                              const float* __restrict__ Bw,
                                              float* __restrict__ C,
                                              const float* __restrict__ bias,
                                              int M, int N, int K) {
    __shared__ __align__(16) float As[16][68];
    __shared__ __align__(16) float Bs[16][64];
    const int tid = threadIdx.x;
    const int tx = tid & 15, ty = tid >> 4;
    const int bn = blockIdx.x * 64, bm = blockIdx.y * 64;
    const int am = tid >> 2, ac = tid & 3;
    float acc[4][4] = {};
    for (int k0 = 0; k0 < K; k0 += 16) {
        float4 a4 = *(const float4*)&A[(size_t)(bm + am) * K + k0 + ac * 4];
        As[ac * 4 + 0][am] = a4.x;
        As[ac * 4 + 1][am] = a4.y;
        As[ac * 4 + 2][am] = a4.z;
        As[ac * 4 + 3][am] = a4.w;
        *(float4*)&Bs[ty][tx * 4] = *(const float4*)&Bw[(size_t)(k0 + ty) * N + bn + tx * 4];
        __syncthreads();
#pragma unroll
        for (int kk = 0; kk < 16; ++kk) {
            float4 av = *(const float4*)&As[kk][ty * 4];
            float4 bv = *(const float4*)&Bs[kk][tx * 4];
            float a[4] = {av.x, av.y, av.z, av.w};
            float b[4] = {bv.x, bv.y, bv.z, bv.w};
#pragma unroll
            for (int i = 0; i < 4; ++i)
#pragma unroll
                for (int j = 0; j < 4; ++j) acc[i][j] += a[i] * b[j];
        }
        __syncthreads();
    }
#pragma unroll
    for (int i = 0; i < 4; ++i) {
        int m = bm + ty * 4 + i;
#pragma unroll
        for (int j = 0; j < 4; ++j) {
            int n = bn + tx * 4 + j;
            float v = acc[i][j];
            if (bias) v += bias[n];
            C[(size_t)m * N + n] = v;
        }
    }
}

// ===========================================================================
// CACHED PATH (needs ~107 MB workspace)
// ===========================================================================

// K1: scores once (f32) -> exact f32 polar bins + chunk smax; write bf16
// s'' = masked*scale + dis_embed to Sg. Block = (b,h,kchunk,xchunk).
__global__ __launch_bounds__(256) void score_bins(const float* __restrict__ qkv_k,
                                                  const float* __restrict__ qkv_x,
                                                  const int* __restrict__ rd,
                                                  const int* __restrict__ polar_pos,
                                                  const int* __restrict__ att_mask,
                                                  const float* __restrict__ dis_embed,
                                                  __hip_bfloat16* __restrict__ Sg,
                                                  float* __restrict__ binspart,
                                                  float* __restrict__ smaxpart) {
    const int b = blockIdx.z, h = blockIdx.y;
    const int kch = blockIdx.x / NS_, xc = blockIdx.x % NS_;
    const int k0 = kch * KC_;
    const int tid = threadIdx.x;
    const int ki = tid >> 5, xt = tid & 31;

    __shared__ __align__(16) float4 xs[XT_][9];
    __shared__ int pol_s[KC_][68];
    __shared__ int rd_s[KC_][68];
    __shared__ int msk_s[KC_][65];
    __shared__ float de[NDIS_ * H_];

    for (int i = tid; i < NDIS_ * H_; i += 256) de[i] = dis_embed[i];

    float4 kqr[8];
    {
        const float* pk = &qkv_k[(size_t)(b * KL_ + k0 + ki) * TDIM_ + h * HD_];
#pragma unroll
        for (int c = 0; c < 8; ++c) kqr[c] = *(const float4*)&pk[c * 4];
    }

    const size_t xbase = (size_t)b * XL_;
    const size_t bh = (size_t)(b * H_ + h);
    const size_t row_k = bh * KL_ + k0 + ki;
    const int xbeg = xc * XCH_;

    float bins[PB_] = {};
    float smax = -3e38f;
    __syncthreads();
    for (int t = 0; t < XCH_ / XT_; ++t) {
        const int x0 = xbeg + t * XT_;
        __syncthreads();
#pragma unroll
        for (int i = 0; i < 2; ++i) {
            int id = tid + 256 * i;
            int row = id >> 3, c = id & 7;
            xs[row][c] = *(const float4*)&qkv_x[(xbase + x0 + row) * TDIM_ + DIM_ + h * HD_ + c * 4];
        }
        if (tid < 128) {
            int kk = tid >> 4, c = tid & 15;
            size_t rb = (size_t)(b * KL_ + k0 + kk) * XL_ + x0 + c * 4;
            *(int4*)&pol_s[kk][c * 4] = *(const int4*)&polar_pos[rb];
            *(int4*)&rd_s[kk][c * 4] = *(const int4*)&rd[rb];
        } else {
            int id = tid - 128;
            int row = id >> 1, half = id & 1;
            int4 m4 = *(const int4*)&att_mask[(bh * XL_ + x0 + row) * KL_ + k0 + half * 4];
            msk_s[half * 4 + 0][row] = m4.x;
            msk_s[half * 4 + 1][row] = m4.y;
            msk_s[half * 4 + 2][row] = m4.z;
            msk_s[half * 4 + 3][row] = m4.w;
        }
        __syncthreads();
#pragma unroll
        for (int j = 0; j < 2; ++j) {
            int xl = xt + 32 * j;
            int x = x0 + xl;
            float s = 0.f;
#pragma unroll
            for (int c = 0; c < 8; ++c) {
                float4 kx = xs[xl][c];
                s += kqr[c].x * kx.x + kqr[c].y * kx.y + kqr[c].z * kx.z + kqr[c].w * kx.w;
            }
            s *= SCALE_;
            int pp = pol_s[ki][xl];
            float a = fabsf(s);
#pragma unroll
            for (int q = 0; q < PB_; ++q) bins[q] += (pp == q) ? a : 0.0f;
            int rv = rd_s[ki][xl];
            int mv = msk_s[ki][xl];
            float sp = (mv ? -1e6f : s) + de[rv * H_ + h];
            smax = fmaxf(smax, sp);
            Sg[row_k * XL_ + x] = __float2bfloat16(sp);
        }
    }
#pragma unroll
    for (int m = 1; m < 32; m <<= 1) {
#pragma unroll
        for (int q = 0; q < PB_; ++q) bins[q] += __shfl_xor(bins[q], m);
        smax = fmaxf(smax, __shfl_xor(smax, m));
    }
    if (xt == 0) {
        float* dst = &binspart[row_k * (NS_ * PB_) + xc * PB_];
#pragma unroll
        for (int q = 0; q < PB_; ++q) dst[q] = bins[q];
        smaxpart[row_k * NS_ + xc] = smax;
    }
}

// K2: argmax + upper bound M per row
__global__ __launch_bounds__(256) void argmax_M(const float* __restrict__ binspart,
                                                const float* __restrict__ smaxpart,
                                                const float* __restrict__ polar_emb,
                                                int* __restrict__ main_ori,
                                                float* __restrict__ Mrow) {
    int row = blockIdx.x * 256 + threadIdx.x;
    if (row >= B_ * H_ * KL_) return;
    float s[PB_] = {};
    const float* bp = &binspart[(size_t)row * (NS_ * PB_)];
#pragma unroll
    for (int c = 0; c < NS_; ++c)
#pragma unroll
        for (int q = 0; q < PB_; ++q) s[q] += bp[c * PB_ + q];
    float best = s[0];
    int bi = 0;
#pragma unroll
    for (int q = 1; q < PB_; ++q)
        if (s[q] > best) { best = s[q]; bi = q; }
    main_ori[row] = bi;
    float sm = -3e38f;
#pragma unroll
    for (int c = 0; c < NS_; ++c) sm = fmaxf(sm, smaxpart[row * NS_ + c]);
    float pmax = polar_emb[0];
#pragma unroll
    for (int q = 1; q < PB_; ++q) pmax = fmaxf(pmax, polar_emb[q]);
    Mrow[row] = sm + pmax;
}

// K3: stream scores + V; branch-free exp; AV partials per x-chunk.
__global__ __launch_bounds__(256) void flash_cached(const float* __restrict__ qkv_x,
                                                    const __hip_bfloat16* __restrict__ Sg,
                                                    const int* __restrict__ polar_pos,
                                                    const float* __restrict__ polar_emb,
                                                    const int* __restrict__ main_ori,
                                                    const float* __restrict__ Mrow,
                                                    float* __restrict__ part) {
    const int b = blockIdx.z, h = blockIdx.y;
    const int kch = blockIdx.x / NS_, xc = blockIdx.x % NS_;
    const int k0 = kch * KC_;
    const int tid = threadIdx.x;
    const int ki = tid >> 5, xt = tid & 31;

    __shared__ __align__(16) float4 vs[XT_][9];
    __shared__ int pol_s[KC_][68];
    __shared__ float pe[PB_];

    if (tid < PB_) pe[tid] = polar_emb[tid];
    const size_t xbase = (size_t)b * XL_;
    const size_t bh = (size_t)(b * H_ + h);
    const size_t row_k = bh * KL_ + k0 + ki;
    const int mo = main_ori[row_k];
    const float M = Mrow[row_k];
    const int xbeg = xc * XCH_;

    float l = 0.f;
    float4 acc[8] = {};
    __syncthreads();
    for (int t = 0; t < XCH_ / XT_; ++t) {
        const int x0 = xbeg + t * XT_;
        __syncthreads();
#pragma unroll
        for (int i = 0; i < 2; ++i) {
            int id = tid + 256 * i;
            int row = id >> 3, c = id & 7;
            vs[row][c] = *(const float4*)&qkv_x[(xbase + x0 + row) * TDIM_ + 2 * DIM_ + h * HD_ + c * 4];
        }
        if (tid < 128) {
            int kk = tid >> 4, c = tid & 15;
            *(int4*)&pol_s[kk][c * 4] =
                *(const int4*)&polar_pos[(size_t)(b * KL_ + k0 + kk) * XL_ + x0 + c * 4];
        }
        __syncthreads();
#pragma unroll
        for (int j = 0; j < 2; ++j) {
            int xl = xt + 32 * j;
            int x = x0 + xl;
            float sp = __bfloat162float(Sg[row_k * XL_ + x]);
            int pp = pol_s[ki][xl];
            int np = pp - mo;
            np += (np >> 31) & PB_;
            float p = expf(sp + pe[np] - M);
            l += p;
#pragma unroll
            for (int c = 0; c < 8; ++c) {
                float4 v = vs[xl][c];
                acc[c].x += p * v.x; acc[c].y += p * v.y;
                acc[c].z += p * v.z; acc[c].w += p * v.w;
            }
        }
    }
#pragma unroll
    for (int m = 1; m < 32; m <<= 1) {
        l += __shfl_xor(l, m);
#pragma unroll
        for (int c = 0; c < 8; ++c) {
            acc[c].x += __shfl_xor(acc[c].x, m);
            acc[c].y += __shfl_xor(acc[c].y, m);
            acc[c].z += __shfl_xor(acc[c].z, m);
            acc[c].w += __shfl_xor(acc[c].w, m);
        }
    }
    if (xt == 0) {
        float* dst = &part[(size_t)(row_k * NS_ + xc) * 36];
#pragma unroll
        for (int c = 0; c < 8; ++c) *(float4*)&dst[c * 4] = acc[c];
        dst[32] = l;
    }
}

// K4: plain-sum merge (global M shared by all chunks)
__global__ __launch_bounds__(256) void merge_cached(const float* __restrict__ part,
                                                    float* __restrict__ kout_pre) {
    const int tid = threadIdx.x;
    const int ri = tid >> 5, d = tid & 31;
    const int row = blockIdx.x * 8 + ri;
    float l = 0.f, a = 0.f;
#pragma unroll
    for (int c = 0; c < NS_; ++c) {
        const float* p = &part[(size_t)(row * NS_ + c) * 36];
        l += p[32];
        a += p[d];
    }
    int k = row & (KL_ - 1);
    int bh = row >> 7;
    int h = bh & (H_ - 1), b = bh >> 3;
    kout_pre[(size_t)(b * KL_ + k) * DIM_ + h * HD_ + d] = a / l;
}

// ===========================================================================
// FALLBACK PATH (R7, proven) — used when workspace < NEED_BIG
// ===========================================================================
__global__ __launch_bounds__(256) void bins_part(const float* __restrict__ qkv_k,
                                                 const float* __restrict__ qkv_x,
                                                 const int* __restrict__ polar_pos,
                                                 float* __restrict__ binspart) {
    const int b = blockIdx.z, h = blockIdx.y;
    const int kch = blockIdx.x / NS_, xc = blockIdx.x % NS_;
    const int k0 = kch * KC_;
    const int tid = threadIdx.x;
    const int ki = tid >> 5, xt = tid & 31;
    __shared__ __align__(16) float4 xs[XT_][9];
    __shared__ __align__(16) float kq_s[KC_][32];
    __shared__ int pol_s[KC_][68];
    if (tid < KC_ * 8) {
        int kk = tid >> 3, c = tid & 7;
        *(float4*)&kq_s[kk][c * 4] =
            *(const float4*)&qkv_k[(size_t)(b * KL_ + k0 + kk) * TDIM_ + h * HD_ + c * 4];
    }
    __syncthreads();
    float4 kqr[8];
#pragma unroll
    for (int c = 0; c < 8; ++c) kqr[c] = *(const float4*)&kq_s[ki][c * 4];
    const size_t xbase = (size_t)b * XL_;
    const int xbeg = xc * XCH_;
    float bins[PB_] = {};
    for (int t = 0; t < XCH_ / XT_; ++t) {
        const int x0 = xbeg + t * XT_;
        __syncthreads();
#pragma unroll
        for (int i = 0; i < 2; ++i) {
            int id = tid + 256 * i;
            int row = id >> 3, c = id & 7;
            xs[row][c] = *(const float4*)&qkv_x[(xbase + x0 + row) * TDIM_ + DIM_ + h * HD_ + c * 4];
        }
        if (tid < 128) {
            int kk = tid >> 4, c = tid & 15;
            *(int4*)&pol_s[kk][c * 4] =
                *(const int4*)&polar_pos[(size_t)(b * KL_ + k0 + kk) * XL_ + x0 + c * 4];
        }
        __syncthreads();
#pragma unroll
        for (int j = 0; j < 2; ++j) {
            int x = xt + 32 * j;
            float s = 0.f;
#pragma unroll
            for (int c = 0; c < 8; ++c) {
                float4 kv = xs[x][c];
                s += kqr[c].x * kv.x + kqr[c].y * kv.y + kqr[c].z * kv.z + kqr[c].w * kv.w;
            }
            float a = fabsf(s * SCALE_);
            int o = pol_s[ki][x];
#pragma unroll
            for (int q = 0; q < PB_; ++q) bins[q] += (o == q) ? a : 0.0f;
        }
    }
#pragma unroll
    for (int q = 0; q < PB_; ++q)
#pragma unroll
        for (int m = 1; m < 32; m <<= 1) bins[q] += __shfl_xor(bins[q], m, 32);
    if (xt == 0) {
        int row = (b * H_ + h) * KL_ + k0 + ki;
        float* dst = &binspart[(size_t)row * (NS_ * PB_) + xc * PB_];
#pragma unroll
        for (int q = 0; q < PB_; ++q) dst[q] = bins[q];
    }
}

__global__ __launch_bounds__(256) void bins_argmax(const float* __restrict__ binspart,
                                                   int* __restrict__ main_ori) {
    int row = blockIdx.x * 256 + threadIdx.x;
    if (row >= B_ * H_ * KL_) return;
    float s[PB_] = {};
    const float* bp = &binspart[(size_t)row * (NS_ * PB_)];
#pragma unroll
    for (int c = 0; c < NS_; ++c)
#pragma unroll
        for (int q = 0; q < PB_; ++q) s[q] += bp[c * PB_ + q];
    float best = s[0];
    int bi = 0;
#pragma unroll
    for (int q = 1; q < PB_; ++q)
        if (s[q] > best) { best = s[q]; bi = q; }
    main_ori[row] = bi;
}

__global__ __launch_bounds__(256) void flash_part(const float* __restrict__ qkv_k,
                                                  const float* __restrict__ qkv_x,
                                                  const int* __restrict__ rd,
                                                  const int* __restrict__ polar_pos,
                                                  const int* __restrict__ att_mask,
                                                  const float* __restrict__ dis_embed,
                                                  const float* __restrict__ polar_emb,
                                                  const int* __restrict__ main_ori,
                                                  float* __restrict__ part) {
    const int b = blockIdx.z, h = blockIdx.y;
    const int kch = blockIdx.x / NS_, xc = blockIdx.x % NS_;
    const int k0 = kch * KC_;
    const int tid = threadIdx.x;
    const int ki = tid >> 5, xt = tid & 31;
    __shared__ __align__(16) float4 xs[XT_][9];
    __shared__ __align__(16) float4 vs[XT_][9];
    __shared__ __align__(16) float kq_s[KC_][32];
    __shared__ int pol_s[KC_][68];
    __shared__ int rd_s[KC_][68];
    __shared__ int msk_s[KC_][65];
    __shared__ float de[NDIS_ * H_];
    __shared__ float pe[PB_];
    for (int i = tid; i < NDIS_ * H_; i += 256) de[i] = dis_embed[i];
    if (tid < PB_) pe[tid] = polar_emb[tid];
    if (tid < KC_ * 8) {
        int kk = tid >> 3, c = tid & 7;
        *(float4*)&kq_s[kk][c * 4] =
            *(const float4*)&qkv_k[(size_t)(b * KL_ + k0 + kk) * TDIM_ + h * HD_ + c * 4];
    }
    __syncthreads();
    float4 kqr[8];
#pragma unroll
    for (int c = 0; c < 8; ++c) kqr[c] = *(const float4*)&kq_s[ki][c * 4];
    const int mo = main_ori[(b * H_ + h) * KL_ + k0 + ki];
    const size_t xbase = (size_t)b * XL_;
    const size_t mrow_base = (size_t)(b * H_ + h) * XL_;
    const int xbeg = xc * XCH_;
    float m_run = -3e38f, l_run = 0.f;
    float4 acc[8] = {};
    for (int t = 0; t < XCH_ / XT_; ++t) {
        const int x0 = xbeg + t * XT_;
        __syncthreads();
#pragma unroll
        for (int i = 0; i < 2; ++i) {
            int id = tid + 256 * i;
            int row = id >> 3, c = id & 7;
            size_t rb = (xbase + x0 + row) * TDIM_ + h * HD_ + c * 4;
            xs[row][c] = *(const float4*)&qkv_x[rb + DIM_];
            vs[row][c] = *(const float4*)&qkv_x[rb + 2 * DIM_];
        }
        if (tid < 128) {
            int kk = tid >> 4, c = tid & 15;
            size_t rb = (size_t)(b * KL_ + k0 + kk) * XL_ + x0 + c * 4;
            *(int4*)&pol_s[kk][c * 4] = *(const int4*)&polar_pos[rb];
            *(int4*)&rd_s[kk][c * 4] = *(const int4*)&rd[rb];
        } else {
            int id = tid - 128;
            int row = id >> 1, half = id & 1;
            int4 m4 = *(const int4*)&att_mask[(mrow_base + x0 + row) * KL_ + k0 + half * 4];
            msk_s[half * 4 + 0][row] = m4.x;
            msk_s[half * 4 + 1][row] = m4.y;
            msk_s[half * 4 + 2][row] = m4.z;
            msk_s[half * 4 + 3][row] = m4.w;
        }
        __syncthreads();
#pragma unroll
        for (int j = 0; j < 2; ++j) {
            int x = xt + 32 * j;
            float s = 0.f;
#pragma unroll
            for (int c = 0; c < 8; ++c) {
                float4 kv = xs[x][c];
                s += kqr[c].x * kv.x + kqr[c].y * kv.y + kqr[c].z * kv.z + kqr[c].w * kv.w;
            }
            s *= SCALE_;
            int r = rd_s[ki][x];
            int pp = pol_s[ki][x];
            int npb = pp - mo;
            npb += (npb >> 31) & PB_;
            float tval = (msk_s[ki][x] ? -1e6f : s) + de[r * H_ + h] + pe[npb];
            if (tval > m_run) {
                float alpha = expf(m_run - tval);
                l_run = l_run * alpha + 1.0f;
#pragma unroll
                for (int c = 0; c < 8; ++c) {
                    float4 vv = vs[x][c];
                    acc[c].x = acc[c].x * alpha + vv.x;
                    acc[c].y = acc[c].y * alpha + vv.y;
                    acc[c].z = acc[c].z * alpha + vv.z;
                    acc[c].w = acc[c].w * alpha + vv.w;
                }
                m_run = tval;
            } else {
                float p = expf(tval - m_run);
                l_run += p;
#pragma unroll
                for (int c = 0; c < 8; ++c) {
                    float4 vv = vs[x][c];
                    acc[c].x += p * vv.x;
                    acc[c].y += p * vv.y;
                    acc[c].z += p * vv.z;
                    acc[c].w += p * vv.w;
                }
            }
        }
    }
    float M = m_run;
#pragma unroll
    for (int m = 1; m < 32; m <<= 1) M = fmaxf(M, __shfl_xor(M, m, 32));
    float factor = expf(m_run - M);
    l_run *= factor;
#pragma unroll
    for (int c = 0; c < 8; ++c) {
        acc[c].x *= factor; acc[c].y *= factor; acc[c].z *= factor; acc[c].w *= factor;
    }
#pragma unroll
    for (int m = 1; m < 32; m <<= 1) {
        l_run += __shfl_xor(l_run, m, 32);
#pragma unroll
        for (int c = 0; c < 8; ++c) {
            acc[c].x += __shfl_xor(acc[c].x, m, 32);
            acc[c].y += __shfl_xor(acc[c].y, m, 32);
            acc[c].z += __shfl_xor(acc[c].z, m, 32);
            acc[c].w += __shfl_xor(acc[c].w, m, 32);
        }
    }
    if (xt == 0) {
        int row = (b * H_ + h) * KL_ + k0 + ki;
        float* dst = &part[(size_t)(row * NS_ + xc) * 36];
#pragma unroll
        for (int c = 0; c < 8; ++c) *(float4*)&dst[c * 4] = acc[c];
        dst[32] = M;
        dst[33] = l_run;
    }
}

__global__ __launch_bounds__(256) void flash_merge(const float* __restrict__ part,
                                                   float* __restrict__ kout_pre) {
    const int tid = threadIdx.x;
    const int ri = tid >> 5, d = tid & 31;
    const int row = blockIdx.x * 8 + ri;
    float mc[NS_], lc[NS_];
    float M = -3e38f;
#pragma unroll
    for (int c = 0; c < NS_; ++c) {
        const float* p = &part[(size_t)(row * NS_ + c) * 36];
        mc[c] = p[32];
        lc[c] = p[33];
        M = fmaxf(M, mc[c]);
    }
    float l = 0.f, a = 0.f;
#pragma unroll
    for (int c = 0; c < NS_; ++c) {
        float w = expf(mc[c] - M);
        l += lc[c] * w;
        a += part[(size_t)(row * NS_ + c) * 36 + d] * w;
    }
    int k = row & (KL_ - 1);
    int bh = row >> 7;
    int h = bh & (H_ - 1), b = bh >> 3;
    kout_pre[(size_t)(b * KL_ + k) * DIM_ + h * HD_ + d] = a / l;
}

// ---------------------------------------------------------------------------
// x-direction attention (unchanged)
// ---------------------------------------------------------------------------
__global__ __launch_bounds__(256) void attn_x(const float* __restrict__ qkv_x,
                                              const float* __restrict__ qkv_k,
                                              const int* __restrict__ rd,
                                              const int* __restrict__ polar_pos,
                                              const int* __restrict__ att_mask,
                                              const float* __restrict__ dis_embed,
                                              const float* __restrict__ polar_emb,
                                              const int* __restrict__ main_ori,
                                              float* __restrict__ xout_pre) {
    const int b = blockIdx.z, h = blockIdx.y;
    const int x0 = blockIdx.x * 16;
    const int tid = threadIdx.x;
    __shared__ __align__(16) float kk_s[KL_][36];
    __shared__ __align__(16) float kv_s[KL_][36];
    __shared__ __align__(16) float q_s[16][36];
    __shared__ float de[NDIS_ * H_];
    __shared__ float pe[PB_];
    __shared__ int mo_s[KL_];

    for (int i = tid; i < KL_ * HD_; i += 256) {
        int kk = i >> 5, d = i & 31;
        size_t base = (size_t)(b * KL_ + kk) * TDIM_ + h * HD_ + d;
        kk_s[kk][d] = qkv_k[base + DIM_];
        kv_s[kk][d] = qkv_k[base + 2 * DIM_];
    }
    for (int i = tid; i < 16 * HD_; i += 256) {
        int xl = i >> 5, d = i & 31;
        q_s[xl][d] = qkv_x[(size_t)(b * XL_ + x0 + xl) * TDIM_ + h * HD_ + d];
    }
    for (int i = tid; i < NDIS_ * H_; i += 256) de[i] = dis_embed[i];
    if (tid < PB_) pe[tid] = polar_emb[tid];
    if (tid < KL_) mo_s[tid] = main_ori[(b * H_ + h) * KL_ + tid];
    __syncthreads();

    const int xl = tid >> 4, r = tid & 15;
    const int x = x0 + xl;
    float t[8];
    float lmax = -3e38f;
    const size_t mrow = ((size_t)(b * H_ + h) * XL_ + x) * KL_;
#pragma unroll
    for (int j = 0; j < 8; ++j) {
        int kk = j * 16 + r;
        float s = 0.f;
#pragma unroll
        for (int d4 = 0; d4 < 8; ++d4) {
            float4 a = *(const float4*)&q_s[xl][d4 * 4];
            float4 bb = *(const float4*)&kk_s[kk][d4 * 4];
            s += a.x * bb.x + a.y * bb.y + a.z * bb.z + a.w * bb.w;
        }
        s *= SCALE_;
        int msk = att_mask[mrow + kk];
        size_t pidx = (size_t)(b * KL_ + kk) * XL_ + x;
        int rv = rd[pidx];
        int pp = polar_pos[pidx];
        int npb = pp - mo_s[kk];
        npb += (npb >> 31) & PB_;
        t[j] = (msk ? -1e9f : s) + de[rv * H_ + h] + pe[npb];
        lmax = fmaxf(lmax, t[j]);
    }
#pragma unroll
    for (int m = 1; m < 16; m <<= 1) lmax = fmaxf(lmax, __shfl_xor(lmax, m, 16));
    float lsum = 0.f;
#pragma unroll
    for (int j = 0; j < 8; ++j) {
        t[j] = expf(t[j] - lmax);
        lsum += t[j];
    }
#pragma unroll
    for (int m = 1; m < 16; m <<= 1) lsum += __shfl_xor(lsum, m, 16);

    float acc[HD_] = {};
#pragma unroll
    for (int j = 0; j < 8; ++j) {
        int kk = j * 16 + r;
        float e = t[j];
#pragma unroll
        for (int d = 0; d < HD_; d += 4) {
            float4 vv = *(const float4*)&kv_s[kk][d];
            acc[d + 0] += e * vv.x;
            acc[d + 1] += e * vv.y;
            acc[d + 2] += e * vv.z;
            acc[d + 3] += e * vv.w;
        }
    }
#pragma unroll
    for (int d = 0; d < HD_; ++d)
#pragma unroll
        for (int m = 1; m < 16; m <<= 1) acc[d] += __shfl_xor(acc[d], m, 16);
    if (r == 0) {
        float inv = 1.0f / lsum;
        float* op = xout_pre + (size_t)(b * XL_ + x) * DIM_ + h * HD_;
#pragma unroll
        for (int d = 0; d < HD_; ++d) op[d] = acc[d] * inv;
    }
}

// ---------------------------------------------------------------------------
extern "C" void kernel_launch(void* const* d_in, const int* in_sizes, int n_in,
                              void* d_out, int out_size, void* d_ws, size_t ws_size,
                              hipStream_t stream) {
    const float* x         = (const float*)d_in[0];
    const float* kernal    = (const float*)d_in[1];
    const int* rd          = (const int*)d_in[2];
    const int* polar_pos   = (const int*)d_in[3];
    const int* att_mask    = (const int*)d_in[4];
    const float* W_qkv     = (const float*)d_in[5];
    const float* dis_embed = (const float*)d_in[6];
    const float* polar_emb = (const float*)d_in[7];
    const float* W_proj    = (const float*)d_in[8];
    const float* b_proj    = (const float*)d_in[9];
    float* out             = (float*)d_out;

    char* base = (char*)d_ws;
    size_t off = 0;
    auto alloc = [&](size_t bytes) { void* p = base + off; off = (off + bytes + 255) & ~255ULL; return p; };
    float* qkv_x    = (float*)alloc((size_t)B_ * XL_ * TDIM_ * 4);
    float* qkv_k    = (float*)alloc((size_t)B_ * KL_ * TDIM_ * 4);
    float* xout_pre = (float*)alloc((size_t)B_ * XL_ * DIM_ * 4);
    float* kout_pre = (float*)alloc((size_t)B_ * KL_ * DIM_ * 4);
    int* main_ori   = (int*)alloc(B_ * H_ * KL_ * 4);
    float* Mrow     = (float*)alloc(B_ * H_ * KL_ * 4);
    float* binspart = (float*)alloc((size_t)B_ * H_ * KL_ * NS_ * PB_ * 4);
    float* smaxpart = (float*)alloc((size_t)B_ * H_ * KL_ * NS_ * 4);
    float* part     = (float*)alloc((size_t)B_ * H_ * KL_ * NS_ * 36 * 4);
    const size_t NEED_SMALL = off;
    __hip_bfloat16* Sg = (__hip_bfloat16*)alloc((size_t)B_ * H_ * KL_ * XL_ * 2);
    const size_t NEED_BIG = off;
    const bool big = (ws_size >= NEED_BIG);

    gemm128<<<dim3(TDIM_ / 128, (B_ * XL_) / 128), 256, 0, stream>>>(
        x, W_qkv, qkv_x, nullptr, B_ * XL_, TDIM_, DIM_);
    gemm64<<<dim3(TDIM_ / 64, (B_ * KL_) / 64), 256, 0, stream>>>(
        kernal, W_qkv, qkv_k, nullptr, B_ * KL_, TDIM_, DIM_);

    if (big) {
        score_bins<<<dim3((KL_ / KC_) * NS_, H_, B_), 256, 0, stream>>>(
            qkv_k, qkv_x, rd, polar_pos, att_mask, dis_embed, Sg, binspart, smaxpart);
        argmax_M<<<dim3((B_ * H_ * KL_ + 255) / 256), 256, 0, stream>>>(
            binspart, smaxpart, polar_emb, main_ori, Mrow);
        flash_cached<<<dim3((KL_ / KC_) * NS_, H_, B_), 256, 0, stream>>>(
            qkv_x, Sg, polar_pos, polar_emb, main_ori, Mrow, part);
        merge_cached<<<dim3(B_ * H_ * KL_ / 8), 256, 0, stream>>>(part, kout_pre);
    } else {
        bins_part<<<dim3((KL_ / KC_) * NS_, H_, B_), 256, 0, stream>>>(
            qkv_k, qkv_x, polar_pos, binspart);
        bins_argmax<<<dim3((B_ * H_ * KL_ + 255) / 256), 256, 0, stream>>>(binspart, main_ori);
        flash_part<<<dim3((KL_ / KC_) * NS_, H_, B_), 256, 0, stream>>>(
            qkv_k, qkv_x, rd, polar_pos, att_mask, dis_embed, polar_emb, main_ori, part);
        flash_merge<<<dim3(B_ * H_ * KL_ / 8), 256, 0, stream>>>(part, kout_pre);
    }

    attn_x<<<dim3(XL_ / 16, H_, B_), 256, 0, stream>>>(
        qkv_x, qkv_k, rd, polar_pos, att_mask, dis_embed, polar_emb, main_ori, xout_pre);
    gemm128<<<dim3(DIM_ / 128, (B_ * XL_) / 128), 256, 0, stream>>>(
        xout_pre, W_proj, out, b_proj, B_ * XL_, DIM_, DIM_);
    gemm64<<<dim3(DIM_ / 64, (B_ * KL_) / 64), 256, 0, stream>>>(
        kout_pre, W_proj, out + (size_t)B_ * XL_ * DIM_, b_proj, B_ * KL_, DIM_, DIM_);
}

// Round 10
// 540.608 us; speedup vs baseline: 1.1311x; 1.0262x over previous
//
#include <hip/hip_runtime.h>
#include <hip/hip_bf16.h>

#define B_    4
#define KL_   128
#define XL_   4096
#define DIM_  256
#define H_    8
#define HD_   32
#define PB_   8
#define NDIS_ 66
#define TDIM_ 768
#define SCALE_ 0.17677669529663687f
#define XT_   64
#define KC_   8
#define NS_   4
#define XCH_  (XL_ / NS_)  // 1024

// ---------------------------------------------------------------------------
// 128x128 f32 GEMM, BK=8, 8x8 per thread.
// ---------------------------------------------------------------------------
__global__ __launch_bounds__(256) void gemm128(const float* __restrict__ A,
                                               const float* __restrict__ Bw,
                                               float* __restrict__ C,
                                               const float* __restrict__ bias,
                                               int M, int N, int K) {
    __shared__ __align__(16) float As[8][132];
    __shared__ __align__(16) float Bs[8][128];
    const int tid = threadIdx.x;
    const int tx = tid & 15, ty = tid >> 4;
    const int bn = blockIdx.x * 128, bm = blockIdx.y * 128;
    const int arow = tid >> 1, acol = (tid & 1) * 4;
    const int brow = tid >> 5, bcol = (tid & 31) * 4;
    float acc[8][8] = {};
    for (int k0 = 0; k0 < K; k0 += 8) {
        float4 a4 = *(const float4*)&A[(size_t)(bm + arow) * K + k0 + acol];
        As[acol + 0][arow] = a4.x;
        As[acol + 1][arow] = a4.y;
        As[acol + 2][arow] = a4.z;
        As[acol + 3][arow] = a4.w;
        *(float4*)&Bs[brow][bcol] = *(const float4*)&Bw[(size_t)(k0 + brow) * N + bn + bcol];
        __syncthreads();
#pragma unroll
        for (int kk = 0; kk < 8; ++kk) {
            float4 a0 = *(const float4*)&As[kk][ty * 8];
            float4 a1 = *(const float4*)&As[kk][ty * 8 + 4];
            float4 b0 = *(const float4*)&Bs[kk][tx * 8];
            float4 b1 = *(const float4*)&Bs[kk][tx * 8 + 4];
            float a[8] = {a0.x, a0.y, a0.z, a0.w, a1.x, a1.y, a1.z, a1.w};
            float b[8] = {b0.x, b0.y, b0.z, b0.w, b1.x, b1.y, b1.z, b1.w};
#pragma unroll
            for (int i = 0; i < 8; ++i)
#pragma unroll
                for (int j = 0; j < 8; ++j) acc[i][j] += a[i] * b[j];
        }
        __syncthreads();
    }
#pragma unroll
    for (int i = 0; i < 8; ++i) {
        int m = bm + ty * 8 + i;
        float* cp = &C[(size_t)m * N + bn + tx * 8];
        float4 o0 = {acc[i][0], acc[i][1], acc[i][2], acc[i][3]};
        float4 o1 = {acc[i][4], acc[i][5], acc[i][6], acc[i][7]};
        if (bias) {
            const float* bp = &bias[bn + tx * 8];
            o0.x += bp[0]; o0.y += bp[1]; o0.z += bp[2]; o0.w += bp[3];
            o1.x += bp[4]; o1.y += bp[5]; o1.z += bp[6]; o1.w += bp[7];
        }
        *(float4*)cp = o0;
        *(float4*)(cp + 4) = o1;
    }
}

// ---------------------------------------------------------------------------
// 64x64 f32 GEMM (small-M)
// ---------------------------------------------------------------------------
__global__ __launch_bounds__(256) void gemm64(const float* __restrict__ A,
                                              const float* __restrict__ Bw,
                                              float* __restrict__ C,
                                              const float* __restrict__ bias,
                                              int M, int N, int K) {
    __shared__ __align__(16) float As[16][68];
    __shared__ __align__(16) float Bs[16][64];
    const int tid = threadIdx.x;
    const int tx = tid & 15, ty = tid >> 4;
    const int bn = blockIdx.x * 64, bm = blockIdx.y * 64;
    const int am = tid >> 2, ac = tid & 3;
    float acc[4][4] = {};
    for (int k0 = 0; k0 < K; k0 += 16) {
        float4 a4 = *(const float4*)&A[(size_t)(bm + am) * K + k0 + ac * 4];
        As[ac * 4 + 0][am] = a4.x;
        As[ac * 4 + 1][am] = a4.y;
        As[ac * 4 + 2][am] = a4.z;
        As[ac * 4 + 3][am] = a4.w;
        *(float4*)&Bs[ty][tx * 4] = *(const float4*)&Bw[(size_t)(k0 + ty) * N + bn + tx * 4];
        __syncthreads();
#pragma unroll
        for (int kk = 0; kk < 16; ++kk) {
            float4 av = *(const float4*)&As[kk][ty * 4];
            float4 bv = *(const float4*)&Bs[kk][tx * 4];
            float a[4] = {av.x, av.y, av.z, av.w};
            float b[4] = {bv.x, bv.y, bv.z, bv.w};
#pragma unroll
            for (int i = 0; i < 4; ++i)
#pragma unroll
                for (int j = 0; j < 4; ++j) acc[i][j] += a[i] * b[j];
        }
        __syncthreads();
    }
#pragma unroll
    for (int i = 0; i < 4; ++i) {
        int m = bm + ty * 4 + i;
#pragma unroll
        for (int j = 0; j < 4; ++j) {
            int n = bn + tx * 4 + j;
            float v = acc[i][j];
            if (bias) v += bias[n];
            C[(size_t)m * N + n] = v;
        }
    }
}

// ===========================================================================
// CACHED PATH
// ===========================================================================

// K1: scores once (f32) -> exact f32 polar bins + chunk smax; write bf16
// s'' = masked*scale + dis_embed to Sg.
__global__ __launch_bounds__(256) void score_bins(const float* __restrict__ qkv_k,
                                                  const float* __restrict__ qkv_x,
                                                  const int* __restrict__ rd,
                                                  const int* __restrict__ polar_pos,
                                                  const int* __restrict__ att_mask,
                                                  const float* __restrict__ dis_embed,
                                                  __hip_bfloat16* __restrict__ Sg,
                                                  float* __restrict__ binspart,
                                                  float* __restrict__ smaxpart) {
    const int b = blockIdx.z, h = blockIdx.y;
    const int kch = blockIdx.x / NS_, xc = blockIdx.x % NS_;
    const int k0 = kch * KC_;
    const int tid = threadIdx.x;
    const int ki = tid >> 5, xt = tid & 31;

    __shared__ __align__(16) float4 xs[XT_][9];
    __shared__ int pol_s[KC_][68];
    __shared__ int rd_s[KC_][68];
    __shared__ int msk_s[KC_][65];
    __shared__ float de_h[NDIS_];

    if (tid < NDIS_) de_h[tid] = dis_embed[tid * H_ + h];

    float4 kqr[8];
    {
        const float* pk = &qkv_k[(size_t)(b * KL_ + k0 + ki) * TDIM_ + h * HD_];
#pragma unroll
        for (int c = 0; c < 8; ++c) kqr[c] = *(const float4*)&pk[c * 4];
    }

    const size_t xbase = (size_t)b * XL_;
    const size_t bh = (size_t)(b * H_ + h);
    const size_t row_k = bh * KL_ + k0 + ki;
    const int xbeg = xc * XCH_;

    float bins[PB_] = {};
    float smax = -3e38f;
    __syncthreads();
    for (int t = 0; t < XCH_ / XT_; ++t) {
        const int x0 = xbeg + t * XT_;
        __syncthreads();
#pragma unroll
        for (int i = 0; i < 2; ++i) {
            int id = tid + 256 * i;
            int row = id >> 3, c = id & 7;
            xs[row][c] = *(const float4*)&qkv_x[(xbase + x0 + row) * TDIM_ + DIM_ + h * HD_ + c * 4];
        }
        if (tid < 128) {
            int kk = tid >> 4, c = tid & 15;
            size_t rb = (size_t)(b * KL_ + k0 + kk) * XL_ + x0 + c * 4;
            *(int4*)&pol_s[kk][c * 4] = *(const int4*)&polar_pos[rb];
            *(int4*)&rd_s[kk][c * 4] = *(const int4*)&rd[rb];
        } else {
            int id = tid - 128;
            int row = id >> 1, half = id & 1;
            int4 m4 = *(const int4*)&att_mask[(bh * XL_ + x0 + row) * KL_ + k0 + half * 4];
            msk_s[half * 4 + 0][row] = m4.x;
            msk_s[half * 4 + 1][row] = m4.y;
            msk_s[half * 4 + 2][row] = m4.z;
            msk_s[half * 4 + 3][row] = m4.w;
        }
        __syncthreads();
#pragma unroll
        for (int j = 0; j < 2; ++j) {
            int xl = xt + 32 * j;
            int x = x0 + xl;
            float s = 0.f;
#pragma unroll
            for (int c = 0; c < 8; ++c) {
                float4 kx = xs[xl][c];
                s += kqr[c].x * kx.x + kqr[c].y * kx.y + kqr[c].z * kx.z + kqr[c].w * kx.w;
            }
            s *= SCALE_;
            int pp = pol_s[ki][xl];
            float a = fabsf(s);
#pragma unroll
            for (int q = 0; q < PB_; ++q) bins[q] += (pp == q) ? a : 0.0f;
            int rv = rd_s[ki][xl];
            int mv = msk_s[ki][xl];
            float sp = (mv ? -1e6f : s) + de_h[rv];
            smax = fmaxf(smax, sp);
            Sg[row_k * XL_ + x] = __float2bfloat16(sp);
        }
    }
#pragma unroll
    for (int m = 1; m < 32; m <<= 1) {
#pragma unroll
        for (int q = 0; q < PB_; ++q) bins[q] += __shfl_xor(bins[q], m);
        smax = fmaxf(smax, __shfl_xor(smax, m));
    }
    if (xt == 0) {
        float* dst = &binspart[row_k * (NS_ * PB_) + xc * PB_];
#pragma unroll
        for (int q = 0; q < PB_; ++q) dst[q] = bins[q];
        smaxpart[row_k * NS_ + xc] = smax;
    }
}

// K2: argmax + upper bound M per row
__global__ __launch_bounds__(256) void argmax_M(const float* __restrict__ binspart,
                                                const float* __restrict__ smaxpart,
                                                const float* __restrict__ polar_emb,
                                                int* __restrict__ main_ori,
                                                float* __restrict__ Mrow) {
    int row = blockIdx.x * 256 + threadIdx.x;
    if (row >= B_ * H_ * KL_) return;
    float s[PB_] = {};
    const float* bp = &binspart[(size_t)row * (NS_ * PB_)];
#pragma unroll
    for (int c = 0; c < NS_; ++c)
#pragma unroll
        for (int q = 0; q < PB_; ++q) s[q] += bp[c * PB_ + q];
    float best = s[0];
    int bi = 0;
#pragma unroll
    for (int q = 1; q < PB_; ++q)
        if (s[q] > best) { best = s[q]; bi = q; }
    main_ori[row] = bi;
    float sm = -3e38f;
#pragma unroll
    for (int c = 0; c < NS_; ++c) sm = fmaxf(sm, smaxpart[row * NS_ + c]);
    float pmax = polar_emb[0];
#pragma unroll
    for (int q = 1; q < PB_; ++q) pmax = fmaxf(pmax, polar_emb[q]);
    Mrow[row] = sm + pmax;
}

// K3: stream scores + V; branch-free exp; AV partials per x-chunk.
__global__ __launch_bounds__(256) void flash_cached(const float* __restrict__ qkv_x,
                                                    const __hip_bfloat16* __restrict__ Sg,
                                                    const int* __restrict__ polar_pos,
                                                    const float* __restrict__ polar_emb,
                                                    const int* __restrict__ main_ori,
                                                    const float* __restrict__ Mrow,
                                                    float* __restrict__ part) {
    const int b = blockIdx.z, h = blockIdx.y;
    const int kch = blockIdx.x / NS_, xc = blockIdx.x % NS_;
    const int k0 = kch * KC_;
    const int tid = threadIdx.x;
    const int ki = tid >> 5, xt = tid & 31;

    __shared__ __align__(16) float4 vs[XT_][9];
    __shared__ int pol_s[KC_][68];
    __shared__ float pe[PB_];

    if (tid < PB_) pe[tid] = polar_emb[tid];
    const size_t xbase = (size_t)b * XL_;
    const size_t bh = (size_t)(b * H_ + h);
    const size_t row_k = bh * KL_ + k0 + ki;
    const int mo = main_ori[row_k];
    const float M = Mrow[row_k];
    const int xbeg = xc * XCH_;

    float l = 0.f;
    float4 acc[8] = {};
    __syncthreads();
    for (int t = 0; t < XCH_ / XT_; ++t) {
        const int x0 = xbeg + t * XT_;
        __syncthreads();
#pragma unroll
        for (int i = 0; i < 2; ++i) {
            int id = tid + 256 * i;
            int row = id >> 3, c = id & 7;
            vs[row][c] = *(const float4*)&qkv_x[(xbase + x0 + row) * TDIM_ + 2 * DIM_ + h * HD_ + c * 4];
        }
        if (tid < 128) {
            int kk = tid >> 4, c = tid & 15;
            *(int4*)&pol_s[kk][c * 4] =
                *(const int4*)&polar_pos[(size_t)(b * KL_ + k0 + kk) * XL_ + x0 + c * 4];
        }
        __syncthreads();
#pragma unroll
        for (int j = 0; j < 2; ++j) {
            int xl = xt + 32 * j;
            int x = x0 + xl;
            float sp = __bfloat162float(Sg[row_k * XL_ + x]);
            int pp = pol_s[ki][xl];
            int np = pp - mo;
            np += (np >> 31) & PB_;
            float p = expf(sp + pe[np] - M);
            l += p;
#pragma unroll
            for (int c = 0; c < 8; ++c) {
                float4 v = vs[xl][c];
                acc[c].x += p * v.x; acc[c].y += p * v.y;
                acc[c].z += p * v.z; acc[c].w += p * v.w;
            }
        }
    }
#pragma unroll
    for (int m = 1; m < 32; m <<= 1) {
        l += __shfl_xor(l, m);
#pragma unroll
        for (int c = 0; c < 8; ++c) {
            acc[c].x += __shfl_xor(acc[c].x, m);
            acc[c].y += __shfl_xor(acc[c].y, m);
            acc[c].z += __shfl_xor(acc[c].z, m);
            acc[c].w += __shfl_xor(acc[c].w, m);
        }
    }
    if (xt == 0) {
        float* dst = &part[(size_t)(row_k * NS_ + xc) * 36];
#pragma unroll
        for (int c = 0; c < 8; ++c) *(float4*)&dst[c * 4] = acc[c];
        dst[32] = l;
    }
}

// K4: plain-sum merge
__global__ __launch_bounds__(256) void merge_cached(const float* __restrict__ part,
                                                    float* __restrict__ kout_pre) {
    const int tid = threadIdx.x;
    const int ri = tid >> 5, d = tid & 31;
    const int row = blockIdx.x * 8 + ri;
    float l = 0.f, a = 0.f;
#pragma unroll
    for (int c = 0; c < NS_; ++c) {
        const float* p = &part[(size_t)(row * NS_ + c) * 36];
        l += p[32];
        a += p[d];
    }
    int k = row & (KL_ - 1);
    int bh = row >> 7;
    int h = bh & (H_ - 1), b = bh >> 3;
    kout_pre[(size_t)(b * KL_ + k) * DIM_ + h * HD_ + d] = a / l;
}

// ===========================================================================
// FALLBACK PATH (R7, proven)
// ===========================================================================
__global__ __launch_bounds__(256) void bins_part(const float* __restrict__ qkv_k,
                                                 const float* __restrict__ qkv_x,
                                                 const int* __restrict__ polar_pos,
                                                 float* __restrict__ binspart) {
    const int b = blockIdx.z, h = blockIdx.y;
    const int kch = blockIdx.x / NS_, xc = blockIdx.x % NS_;
    const int k0 = kch * KC_;
    const int tid = threadIdx.x;
    const int ki = tid >> 5, xt = tid & 31;
    __shared__ __align__(16) float4 xs[XT_][9];
    __shared__ __align__(16) float kq_s[KC_][32];
    __shared__ int pol_s[KC_][68];
    if (tid < KC_ * 8) {
        int kk = tid >> 3, c = tid & 7;
        *(float4*)&kq_s[kk][c * 4] =
            *(const float4*)&qkv_k[(size_t)(b * KL_ + k0 + kk) * TDIM_ + h * HD_ + c * 4];
    }
    __syncthreads();
    float4 kqr[8];
#pragma unroll
    for (int c = 0; c < 8; ++c) kqr[c] = *(const float4*)&kq_s[ki][c * 4];
    const size_t xbase = (size_t)b * XL_;
    const int xbeg = xc * XCH_;
    float bins[PB_] = {};
    for (int t = 0; t < XCH_ / XT_; ++t) {
        const int x0 = xbeg + t * XT_;
        __syncthreads();
#pragma unroll
        for (int i = 0; i < 2; ++i) {
            int id = tid + 256 * i;
            int row = id >> 3, c = id & 7;
            xs[row][c] = *(const float4*)&qkv_x[(xbase + x0 + row) * TDIM_ + DIM_ + h * HD_ + c * 4];
        }
        if (tid < 128) {
            int kk = tid >> 4, c = tid & 15;
            *(int4*)&pol_s[kk][c * 4] =
                *(const int4*)&polar_pos[(size_t)(b * KL_ + k0 + kk) * XL_ + x0 + c * 4];
        }
        __syncthreads();
#pragma unroll
        for (int j = 0; j < 2; ++j) {
            int x = xt + 32 * j;
            float s = 0.f;
#pragma unroll
            for (int c = 0; c < 8; ++c) {
                float4 kv = xs[x][c];
                s += kqr[c].x * kv.x + kqr[c].y * kv.y + kqr[c].z * kv.z + kqr[c].w * kv.w;
            }
            float a = fabsf(s * SCALE_);
            int o = pol_s[ki][x];
#pragma unroll
            for (int q = 0; q < PB_; ++q) bins[q] += (o == q) ? a : 0.0f;
        }
    }
#pragma unroll
    for (int q = 0; q < PB_; ++q)
#pragma unroll
        for (int m = 1; m < 32; m <<= 1) bins[q] += __shfl_xor(bins[q], m, 32);
    if (xt == 0) {
        int row = (b * H_ + h) * KL_ + k0 + ki;
        float* dst = &binspart[(size_t)row * (NS_ * PB_) + xc * PB_];
#pragma unroll
        for (int q = 0; q < PB_; ++q) dst[q] = bins[q];
    }
}

__global__ __launch_bounds__(256) void bins_argmax(const float* __restrict__ binspart,
                                                   int* __restrict__ main_ori) {
    int row = blockIdx.x * 256 + threadIdx.x;
    if (row >= B_ * H_ * KL_) return;
    float s[PB_] = {};
    const float* bp = &binspart[(size_t)row * (NS_ * PB_)];
#pragma unroll
    for (int c = 0; c < NS_; ++c)
#pragma unroll
        for (int q = 0; q < PB_; ++q) s[q] += bp[c * PB_ + q];
    float best = s[0];
    int bi = 0;
#pragma unroll
    for (int q = 1; q < PB_; ++q)
        if (s[q] > best) { best = s[q]; bi = q; }
    main_ori[row] = bi;
}

__global__ __launch_bounds__(256) void flash_part(const float* __restrict__ qkv_k,
                                                  const float* __restrict__ qkv_x,
                                                  const int* __restrict__ rd,
                                                  const int* __restrict__ polar_pos,
                                                  const int* __restrict__ att_mask,
                                                  const float* __restrict__ dis_embed,
                                                  const float* __restrict__ polar_emb,
                                                  const int* __restrict__ main_ori,
                                                  float* __restrict__ part) {
    const int b = blockIdx.z, h = blockIdx.y;
    const int kch = blockIdx.x / NS_, xc = blockIdx.x % NS_;
    const int k0 = kch * KC_;
    const int tid = threadIdx.x;
    const int ki = tid >> 5, xt = tid & 31;
    __shared__ __align__(16) float4 xs[XT_][9];
    __shared__ __align__(16) float4 vs[XT_][9];
    __shared__ __align__(16) float kq_s[KC_][32];
    __shared__ int pol_s[KC_][68];
    __shared__ int rd_s[KC_][68];
    __shared__ int msk_s[KC_][65];
    __shared__ float de[NDIS_ * H_];
    __shared__ float pe[PB_];
    for (int i = tid; i < NDIS_ * H_; i += 256) de[i] = dis_embed[i];
    if (tid < PB_) pe[tid] = polar_emb[tid];
    if (tid < KC_ * 8) {
        int kk = tid >> 3, c = tid & 7;
        *(float4*)&kq_s[kk][c * 4] =
            *(const float4*)&qkv_k[(size_t)(b * KL_ + k0 + kk) * TDIM_ + h * HD_ + c * 4];
    }
    __syncthreads();
    float4 kqr[8];
#pragma unroll
    for (int c = 0; c < 8; ++c) kqr[c] = *(const float4*)&kq_s[ki][c * 4];
    const int mo = main_ori[(b * H_ + h) * KL_ + k0 + ki];
    const size_t xbase = (size_t)b * XL_;
    const size_t mrow_base = (size_t)(b * H_ + h) * XL_;
    const int xbeg = xc * XCH_;
    float m_run = -3e38f, l_run = 0.f;
    float4 acc[8] = {};
    for (int t = 0; t < XCH_ / XT_; ++t) {
        const int x0 = xbeg + t * XT_;
        __syncthreads();
#pragma unroll
        for (int i = 0; i < 2; ++i) {
            int id = tid + 256 * i;
            int row = id >> 3, c = id & 7;
            size_t rb = (xbase + x0 + row) * TDIM_ + h * HD_ + c * 4;
            xs[row][c] = *(const float4*)&qkv_x[rb + DIM_];
            vs[row][c] = *(const float4*)&qkv_x[rb + 2 * DIM_];
        }
        if (tid < 128) {
            int kk = tid >> 4, c = tid & 15;
            size_t rb = (size_t)(b * KL_ + k0 + kk) * XL_ + x0 + c * 4;
            *(int4*)&pol_s[kk][c * 4] = *(const int4*)&polar_pos[rb];
            *(int4*)&rd_s[kk][c * 4] = *(const int4*)&rd[rb];
        } else {
            int id = tid - 128;
            int row = id >> 1, half = id & 1;
            int4 m4 = *(const int4*)&att_mask[(mrow_base + x0 + row) * KL_ + k0 + half * 4];
            msk_s[half * 4 + 0][row] = m4.x;
            msk_s[half * 4 + 1][row] = m4.y;
            msk_s[half * 4 + 2][row] = m4.z;
            msk_s[half * 4 + 3][row] = m4.w;
        }
        __syncthreads();
#pragma unroll
        for (int j = 0; j < 2; ++j) {
            int x = xt + 32 * j;
            float s = 0.f;
#pragma unroll
            for (int c = 0; c < 8; ++c) {
                float4 kv = xs[x][c];
                s += kqr[c].x * kv.x + kqr[c].y * kv.y + kqr[c].z * kv.z + kqr[c].w * kv.w;
            }
            s *= SCALE_;
            int r = rd_s[ki][x];
            int pp = pol_s[ki][x];
            int npb = pp - mo;
            npb += (npb >> 31) & PB_;
            float tval = (msk_s[ki][x] ? -1e6f : s) + de[r * H_ + h] + pe[npb];
            if (tval > m_run) {
                float alpha = expf(m_run - tval);
                l_run = l_run * alpha + 1.0f;
#pragma unroll
                for (int c = 0; c < 8; ++c) {
                    float4 vv = vs[x][c];
                    acc[c].x = acc[c].x * alpha + vv.x;
                    acc[c].y = acc[c].y * alpha + vv.y;
                    acc[c].z = acc[c].z * alpha + vv.z;
                    acc[c].w = acc[c].w * alpha + vv.w;
                }
                m_run = tval;
            } else {
                float p = expf(tval - m_run);
                l_run += p;
#pragma unroll
                for (int c = 0; c < 8; ++c) {
                    float4 vv = vs[x][c];
                    acc[c].x += p * vv.x;
                    acc[c].y += p * vv.y;
                    acc[c].z += p * vv.z;
                    acc[c].w += p * vv.w;
                }
            }
        }
    }
    float M = m_run;
#pragma unroll
    for (int m = 1; m < 32; m <<= 1) M = fmaxf(M, __shfl_xor(M, m, 32));
    float factor = expf(m_run - M);
    l_run *= factor;
#pragma unroll
    for (int c = 0; c < 8; ++c) {
        acc[c].x *= factor; acc[c].y *= factor; acc[c].z *= factor; acc[c].w *= factor;
    }
#pragma unroll
    for (int m = 1; m < 32; m <<= 1) {
        l_run += __shfl_xor(l_run, m, 32);
#pragma unroll
        for (int c = 0; c < 8; ++c) {
            acc[c].x += __shfl_xor(acc[c].x, m, 32);
            acc[c].y += __shfl_xor(acc[c].y, m, 32);
            acc[c].z += __shfl_xor(acc[c].z, m, 32);
            acc[c].w += __shfl_xor(acc[c].w, m, 32);
        }
    }
    if (xt == 0) {
        int row = (b * H_ + h) * KL_ + k0 + ki;
        float* dst = &part[(size_t)(row * NS_ + xc) * 36];
#pragma unroll
        for (int c = 0; c < 8; ++c) *(float4*)&dst[c * 4] = acc[c];
        dst[32] = M;
        dst[33] = l_run;
    }
}

__global__ __launch_bounds__(256) void flash_merge(const float* __restrict__ part,
                                                   float* __restrict__ kout_pre) {
    const int tid = threadIdx.x;
    const int ri = tid >> 5, d = tid & 31;
    const int row = blockIdx.x * 8 + ri;
    float mc[NS_], lc[NS_];
    float M = -3e38f;
#pragma unroll
    for (int c = 0; c < NS_; ++c) {
        const float* p = &part[(size_t)(row * NS_ + c) * 36];
        mc[c] = p[32];
        lc[c] = p[33];
        M = fmaxf(M, mc[c]);
    }
    float l = 0.f, a = 0.f;
#pragma unroll
    for (int c = 0; c < NS_; ++c) {
        float w = expf(mc[c] - M);
        l += lc[c] * w;
        a += part[(size_t)(row * NS_ + c) * 36 + d] * w;
    }
    int k = row & (KL_ - 1);
    int bh = row >> 7;
    int h = bh & (H_ - 1), b = bh >> 3;
    kout_pre[(size_t)(b * KL_ + k) * DIM_ + h * HD_ + d] = a / l;
}

// ---------------------------------------------------------------------------
// x-direction attention v2: rd/pol/msk packed into one LDS tile (coalesced
// staging, zero scattered global loads in the hot loop); de as per-h column.
// ---------------------------------------------------------------------------
__global__ __launch_bounds__(256) void attn_x(const float* __restrict__ qkv_x,
                                              const float* __restrict__ qkv_k,
                                              const int* __restrict__ rd,
                                              const int* __restrict__ polar_pos,
                                              const int* __restrict__ att_mask,
                                              const float* __restrict__ dis_embed,
                                              const float* __restrict__ polar_emb,
                                              const int* __restrict__ main_ori,
                                              float* __restrict__ xout_pre) {
    const int b = blockIdx.z, h = blockIdx.y;
    const int x0 = blockIdx.x * 16;
    const int tid = threadIdx.x;
    __shared__ __align__(16) float kk_s[KL_][36];
    __shared__ __align__(16) float kv_s[KL_][36];
    __shared__ __align__(16) float q_s[16][36];
    __shared__ int rp_t[KL_][17];   // rd | pol<<8 | msk<<16
    __shared__ float de_h[NDIS_];
    __shared__ float pe[PB_];
    __shared__ int mo_s[KL_];

    const size_t bh = (size_t)(b * H_ + h);

    // kk/kv: 128 rows x 8 float4 each
#pragma unroll
    for (int i = 0; i < 4; ++i) {
        int id = tid + 256 * i;
        int row = id >> 3, c = id & 7;
        size_t base = (size_t)(b * KL_ + row) * TDIM_ + h * HD_ + c * 4;
        *(float4*)&kk_s[row][c * 4] = *(const float4*)&qkv_k[base + DIM_];
        *(float4*)&kv_s[row][c * 4] = *(const float4*)&qkv_k[base + 2 * DIM_];
    }
    if (tid < 128) {
        int xl = tid >> 3, c = tid & 7;
        *(float4*)&q_s[xl][c * 4] =
            *(const float4*)&qkv_x[(size_t)(b * XL_ + x0 + xl) * TDIM_ + h * HD_ + c * 4];
    }
    // rd|pol: 128 kk x 16 x ints -> 512 int4, 2 per thread
#pragma unroll
    for (int i = 0; i < 2; ++i) {
        int id = tid + 256 * i;
        int kk = id >> 2, c = id & 3;
        size_t rb = (size_t)(b * KL_ + kk) * XL_ + x0 + c * 4;
        int4 r4 = *(const int4*)&rd[rb];
        int4 p4 = *(const int4*)&polar_pos[rb];
        rp_t[kk][c * 4 + 0] = r4.x | (p4.x << 8);
        rp_t[kk][c * 4 + 1] = r4.y | (p4.y << 8);
        rp_t[kk][c * 4 + 2] = r4.z | (p4.z << 8);
        rp_t[kk][c * 4 + 3] = r4.w | (p4.w << 8);
    }
    if (tid < NDIS_) de_h[tid] = dis_embed[tid * H_ + h];
    if (tid < PB_) pe[tid] = polar_emb[tid];
    if (tid < KL_) mo_s[tid] = main_ori[bh * KL_ + tid];
    __syncthreads();
    // fold mask bits into rp_t (coalesced reads of [x][kl] layout)
#pragma unroll
    for (int i = 0; i < 2; ++i) {
        int id = tid + 256 * i;
        int xrow = id >> 5, kc = id & 31;
        int4 m4 = *(const int4*)&att_mask[(bh * XL_ + x0 + xrow) * KL_ + kc * 4];
        if (m4.x) rp_t[kc * 4 + 0][xrow] |= 0x10000;
        if (m4.y) rp_t[kc * 4 + 1][xrow] |= 0x10000;
        if (m4.z) rp_t[kc * 4 + 2][xrow] |= 0x10000;
        if (m4.w) rp_t[kc * 4 + 3][xrow] |= 0x10000;
    }
    __syncthreads();

    const int xl = tid >> 4, r = tid & 15;
    const int x = x0 + xl;
    float t[8];
    float lmax = -3e38f;
#pragma unroll
    for (int j = 0; j < 8; ++j) {
        int kk = j * 16 + r;
        float s = 0.f;
#pragma unroll
        for (int d4 = 0; d4 < 8; ++d4) {
            float4 a = *(const float4*)&q_s[xl][d4 * 4];
            float4 bb = *(const float4*)&kk_s[kk][d4 * 4];
            s += a.x * bb.x + a.y * bb.y + a.z * bb.z + a.w * bb.w;
        }
        s *= SCALE_;
        int rp = rp_t[kk][xl];
        int rv = rp & 0xff;
        int pp = (rp >> 8) & 0xff;
        int npb = pp - mo_s[kk];
        npb += (npb >> 31) & PB_;
        t[j] = ((rp & 0x10000) ? -1e9f : s) + de_h[rv] + pe[npb];
        lmax = fmaxf(lmax, t[j]);
    }
#pragma unroll
    for (int m = 1; m < 16; m <<= 1) lmax = fmaxf(lmax, __shfl_xor(lmax, m, 16));
    float lsum = 0.f;
#pragma unroll
    for (int j = 0; j < 8; ++j) {
        t[j] = expf(t[j] - lmax);
        lsum += t[j];
    }
#pragma unroll
    for (int m = 1; m < 16; m <<= 1) lsum += __shfl_xor(lsum, m, 16);

    float acc[HD_] = {};
#pragma unroll
    for (int j = 0; j < 8; ++j) {
        int kk = j * 16 + r;
        float e = t[j];
#pragma unroll
        for (int d = 0; d < HD_; d += 4) {
            float4 vv = *(const float4*)&kv_s[kk][d];
            acc[d + 0] += e * vv.x;
            acc[d + 1] += e * vv.y;
            acc[d + 2] += e * vv.z;
            acc[d + 3] += e * vv.w;
        }
    }
#pragma unroll
    for (int d = 0; d < HD_; ++d)
#pragma unroll
        for (int m = 1; m < 16; m <<= 1) acc[d] += __shfl_xor(acc[d], m, 16);
    if (r == 0) {
        float inv = 1.0f / lsum;
        float* op = xout_pre + (size_t)(b * XL_ + x) * DIM_ + h * HD_;
#pragma unroll
        for (int d = 0; d < HD_; ++d) op[d] = acc[d] * inv;
    }
}

// ---------------------------------------------------------------------------
extern "C" void kernel_launch(void* const* d_in, const int* in_sizes, int n_in,
                              void* d_out, int out_size, void* d_ws, size_t ws_size,
                              hipStream_t stream) {
    const float* x         = (const float*)d_in[0];
    const float* kernal    = (const float*)d_in[1];
    const int* rd          = (const int*)d_in[2];
    const int* polar_pos   = (const int*)d_in[3];
    const int* att_mask    = (const int*)d_in[4];
    const float* W_qkv     = (const float*)d_in[5];
    const float* dis_embed = (const float*)d_in[6];
    const float* polar_emb = (const float*)d_in[7];
    const float* W_proj    = (const float*)d_in[8];
    const float* b_proj    = (const float*)d_in[9];
    float* out             = (float*)d_out;

    char* base = (char*)d_ws;
    size_t off = 0;
    auto alloc = [&](size_t bytes) { void* p = base + off; off = (off + bytes + 255) & ~255ULL; return p; };
    float* qkv_x    = (float*)alloc((size_t)B_ * XL_ * TDIM_ * 4);
    float* qkv_k    = (float*)alloc((size_t)B_ * KL_ * TDIM_ * 4);
    float* xout_pre = (float*)alloc((size_t)B_ * XL_ * DIM_ * 4);
    float* kout_pre = (float*)alloc((size_t)B_ * KL_ * DIM_ * 4);
    int* main_ori   = (int*)alloc(B_ * H_ * KL_ * 4);
    float* Mrow     = (float*)alloc(B_ * H_ * KL_ * 4);
    float* binspart = (float*)alloc((size_t)B_ * H_ * KL_ * NS_ * PB_ * 4);
    float* smaxpart = (float*)alloc((size_t)B_ * H_ * KL_ * NS_ * 4);
    float* part     = (float*)alloc((size_t)B_ * H_ * KL_ * NS_ * 36 * 4);
    __hip_bfloat16* Sg = (__hip_bfloat16*)alloc((size_t)B_ * H_ * KL_ * XL_ * 2);
    const size_t NEED_BIG = off;
    const bool big = (ws_size >= NEED_BIG);

    gemm128<<<dim3(TDIM_ / 128, (B_ * XL_) / 128), 256, 0, stream>>>(
        x, W_qkv, qkv_x, nullptr, B_ * XL_, TDIM_, DIM_);
    gemm64<<<dim3(TDIM_ / 64, (B_ * KL_) / 64), 256, 0, stream>>>(
        kernal, W_qkv, qkv_k, nullptr, B_ * KL_, TDIM_, DIM_);

    if (big) {
        score_bins<<<dim3((KL_ / KC_) * NS_, H_, B_), 256, 0, stream>>>(
            qkv_k, qkv_x, rd, polar_pos, att_mask, dis_embed, Sg, binspart, smaxpart);
        argmax_M<<<dim3((B_ * H_ * KL_ + 255) / 256), 256, 0, stream>>>(
            binspart, smaxpart, polar_emb, main_ori, Mrow);
        flash_cached<<<dim3((KL_ / KC_) * NS_, H_, B_), 256, 0, stream>>>(
            qkv_x, Sg, polar_pos, polar_emb, main_ori, Mrow, part);
        merge_cached<<<dim3(B_ * H_ * KL_ / 8), 256, 0, stream>>>(part, kout_pre);
    } else {
        bins_part<<<dim3((KL_ / KC_) * NS_, H_, B_), 256, 0, stream>>>(
            qkv_k, qkv_x, polar_pos, binspart);
        bins_argmax<<<dim3((B_ * H_ * KL_ + 255) / 256), 256, 0, stream>>>(binspart, main_ori);
        flash_part<<<dim3((KL_ / KC_) * NS_, H_, B_), 256, 0, stream>>>(
            qkv_k, qkv_x, rd, polar_pos, att_mask, dis_embed, polar_emb, main_ori, part);
        flash_merge<<<dim3(B_ * H_ * KL_ / 8), 256, 0, stream>>>(part, kout_pre);
    }

    attn_x<<<dim3(XL_ / 16, H_, B_), 256, 0, stream>>>(
        qkv_x, qkv_k, rd, polar_pos, att_mask, dis_embed, polar_emb, main_ori, xout_pre);
    gemm128<<<dim3(DIM_ / 128, (B_ * XL_) / 128), 256, 0, stream>>>(
        xout_pre, W_proj, out, b_proj, B_ * XL_, DIM_, DIM_);
    gemm64<<<dim3(DIM_ / 64, (B_ * KL_) / 64), 256, 0, stream>>>(
        kout_pre, W_proj, out + (size_t)B_ * XL_ * DIM_, b_proj, B_ * KL_, DIM_, DIM_);
}

// Round 11
// 472.469 us; speedup vs baseline: 1.2942x; 1.1442x over previous
//
#include <hip/hip_runtime.h>
#include <hip/hip_bf16.h>

#define B_    4
#define KL_   128
#define XL_   4096
#define DIM_  256
#define H_    8
#define HD_   32
#define PB_   8
#define NDIS_ 66
#define TDIM_ 768
#define SCALE_ 0.17677669529663687f
#define XT_   64
#define KC_   8
#define NS_   4
#define XCH_  (XL_ / NS_)  // 1024

typedef float v4f __attribute__((ext_vector_type(4)));
typedef short v8s __attribute__((ext_vector_type(8)));

__device__ __forceinline__ unsigned short f2bf(float f) {
    __hip_bfloat16 h = __float2bfloat16(f);
    return __builtin_bit_cast(unsigned short, h);
}
__device__ __forceinline__ float bf2f(unsigned short u) {
    return __bfloat162float(__builtin_bit_cast(__hip_bfloat16, u));
}

// ---------------------------------------------------------------------------
// 128x128 f32 GEMM, BK=8, 8x8 per thread.
// ---------------------------------------------------------------------------
__global__ __launch_bounds__(256) void gemm128(const float* __restrict__ A,
                                               const float* __restrict__ Bw,
                                               float* __restrict__ C,
                                               const float* __restrict__ bias,
                                               int M, int N, int K) {
    __shared__ __align__(16) float As[8][132];
    __shared__ __align__(16) float Bs[8][128];
    const int tid = threadIdx.x;
    const int tx = tid & 15, ty = tid >> 4;
    const int bn = blockIdx.x * 128, bm = blockIdx.y * 128;
    const int arow = tid >> 1, acol = (tid & 1) * 4;
    const int brow = tid >> 5, bcol = (tid & 31) * 4;
    float acc[8][8] = {};
    for (int k0 = 0; k0 < K; k0 += 8) {
        float4 a4 = *(const float4*)&A[(size_t)(bm + arow) * K + k0 + acol];
        As[acol + 0][arow] = a4.x;
        As[acol + 1][arow] = a4.y;
        As[acol + 2][arow] = a4.z;
        As[acol + 3][arow] = a4.w;
        *(float4*)&Bs[brow][bcol] = *(const float4*)&Bw[(size_t)(k0 + brow) * N + bn + bcol];
        __syncthreads();
#pragma unroll
        for (int kk = 0; kk < 8; ++kk) {
            float4 a0 = *(const float4*)&As[kk][ty * 8];
            float4 a1 = *(const float4*)&As[kk][ty * 8 + 4];
            float4 b0 = *(const float4*)&Bs[kk][tx * 8];
            float4 b1 = *(const float4*)&Bs[kk][tx * 8 + 4];
            float a[8] = {a0.x, a0.y, a0.z, a0.w, a1.x, a1.y, a1.z, a1.w};
            float b[8] = {b0.x, b0.y, b0.z, b0.w, b1.x, b1.y, b1.z, b1.w};
#pragma unroll
            for (int i = 0; i < 8; ++i)
#pragma unroll
                for (int j = 0; j < 8; ++j) acc[i][j] += a[i] * b[j];
        }
        __syncthreads();
    }
#pragma unroll
    for (int i = 0; i < 8; ++i) {
        int m = bm + ty * 8 + i;
        float* cp = &C[(size_t)m * N + bn + tx * 8];
        float4 o0 = {acc[i][0], acc[i][1], acc[i][2], acc[i][3]};
        float4 o1 = {acc[i][4], acc[i][5], acc[i][6], acc[i][7]};
        if (bias) {
            const float* bp = &bias[bn + tx * 8];
            o0.x += bp[0]; o0.y += bp[1]; o0.z += bp[2]; o0.w += bp[3];
            o1.x += bp[4]; o1.y += bp[5]; o1.z += bp[6]; o1.w += bp[7];
        }
        *(float4*)cp = o0;
        *(float4*)(cp + 4) = o1;
    }
}

// ---------------------------------------------------------------------------
// 64x64 f32 GEMM (small-M)
// ---------------------------------------------------------------------------
__global__ __launch_bounds__(256) void gemm64(const float* __restrict__ A,
                                              const float* __restrict__ Bw,
                                              float* __restrict__ C,
                                              const float* __restrict__ bias,
                                              int M, int N, int K) {
    __shared__ __align__(16) float As[16][68];
    __shared__ __align__(16) float Bs[16][64];
    const int tid = threadIdx.x;
    const int tx = tid & 15, ty = tid >> 4;
    const int bn = blockIdx.x * 64, bm = blockIdx.y * 64;
    const int am = tid >> 2, ac = tid & 3;
    float acc[4][4] = {};
    for (int k0 = 0; k0 < K; k0 += 16) {
        float4 a4 = *(const float4*)&A[(size_t)(bm + am) * K + k0 + ac * 4];
        As[ac * 4 + 0][am] = a4.x;
        As[ac * 4 + 1][am] = a4.y;
        As[ac * 4 + 2][am] = a4.z;
        As[ac * 4 + 3][am] = a4.w;
        *(float4*)&Bs[ty][tx * 4] = *(const float4*)&Bw[(size_t)(k0 + ty) * N + bn + tx * 4];
        __syncthreads();
#pragma unroll
        for (int kk = 0; kk < 16; ++kk) {
            float4 av = *(const float4*)&As[kk][ty * 4];
            float4 bv = *(const float4*)&Bs[kk][tx * 4];
            float a[4] = {av.x, av.y, av.z, av.w};
            float b[4] = {bv.x, bv.y, bv.z, bv.w};
#pragma unroll
            for (int i = 0; i < 4; ++i)
#pragma unroll
                for (int j = 0; j < 4; ++j) acc[i][j] += a[i] * b[j];
        }
        __syncthreads();
    }
#pragma unroll
    for (int i = 0; i < 4; ++i) {
        int m = bm + ty * 4 + i;
#pragma unroll
        for (int j = 0; j < 4; ++j) {
            int n = bn + tx * 4 + j;
            float v = acc[i][j];
            if (bias) v += bias[n];
            C[(size_t)m * N + n] = v;
        }
    }
}

// ===========================================================================
// CACHED PATH (attn_k direction)
// ===========================================================================

// K1: scores once (f32) -> exact f32 polar bins + chunk smax; write bf16
// s'' = masked*scale + dis_embed to Sg.
__global__ __launch_bounds__(256) void score_bins(const float* __restrict__ qkv_k,
                                                  const float* __restrict__ qkv_x,
                                                  const int* __restrict__ rd,
                                                  const int* __restrict__ polar_pos,
                                                  const int* __restrict__ att_mask,
                                                  const float* __restrict__ dis_embed,
                                                  __hip_bfloat16* __restrict__ Sg,
                                                  float* __restrict__ binspart,
                                                  float* __restrict__ smaxpart) {
    const int b = blockIdx.z, h = blockIdx.y;
    const int kch = blockIdx.x / NS_, xc = blockIdx.x % NS_;
    const int k0 = kch * KC_;
    const int tid = threadIdx.x;
    const int ki = tid >> 5, xt = tid & 31;

    __shared__ __align__(16) float4 xs[XT_][9];
    __shared__ int pol_s[KC_][68];
    __shared__ int rd_s[KC_][68];
    __shared__ int msk_s[KC_][65];
    __shared__ float de_h[NDIS_];

    if (tid < NDIS_) de_h[tid] = dis_embed[tid * H_ + h];

    float4 kqr[8];
    {
        const float* pk = &qkv_k[(size_t)(b * KL_ + k0 + ki) * TDIM_ + h * HD_];
#pragma unroll
        for (int c = 0; c < 8; ++c) kqr[c] = *(const float4*)&pk[c * 4];
    }

    const size_t xbase = (size_t)b * XL_;
    const size_t bh = (size_t)(b * H_ + h);
    const size_t row_k = bh * KL_ + k0 + ki;
    const int xbeg = xc * XCH_;

    float bins[PB_] = {};
    float smax = -3e38f;
    __syncthreads();
    for (int t = 0; t < XCH_ / XT_; ++t) {
        const int x0 = xbeg + t * XT_;
        __syncthreads();
#pragma unroll
        for (int i = 0; i < 2; ++i) {
            int id = tid + 256 * i;
            int row = id >> 3, c = id & 7;
            xs[row][c] = *(const float4*)&qkv_x[(xbase + x0 + row) * TDIM_ + DIM_ + h * HD_ + c * 4];
        }
        if (tid < 128) {
            int kk = tid >> 4, c = tid & 15;
            size_t rb = (size_t)(b * KL_ + k0 + kk) * XL_ + x0 + c * 4;
            *(int4*)&pol_s[kk][c * 4] = *(const int4*)&polar_pos[rb];
            *(int4*)&rd_s[kk][c * 4] = *(const int4*)&rd[rb];
        } else {
            int id = tid - 128;
            int row = id >> 1, half = id & 1;
            int4 m4 = *(const int4*)&att_mask[(bh * XL_ + x0 + row) * KL_ + k0 + half * 4];
            msk_s[half * 4 + 0][row] = m4.x;
            msk_s[half * 4 + 1][row] = m4.y;
            msk_s[half * 4 + 2][row] = m4.z;
            msk_s[half * 4 + 3][row] = m4.w;
        }
        __syncthreads();
#pragma unroll
        for (int j = 0; j < 2; ++j) {
            int xl = xt + 32 * j;
            int x = x0 + xl;
            float s = 0.f;
#pragma unroll
            for (int c = 0; c < 8; ++c) {
                float4 kx = xs[xl][c];
                s += kqr[c].x * kx.x + kqr[c].y * kx.y + kqr[c].z * kx.z + kqr[c].w * kx.w;
            }
            s *= SCALE_;
            int pp = pol_s[ki][xl];
            float a = fabsf(s);
#pragma unroll
            for (int q = 0; q < PB_; ++q) bins[q] += (pp == q) ? a : 0.0f;
            int rv = rd_s[ki][xl];
            int mv = msk_s[ki][xl];
            float sp = (mv ? -1e6f : s) + de_h[rv];
            smax = fmaxf(smax, sp);
            Sg[row_k * XL_ + x] = __float2bfloat16(sp);
        }
    }
#pragma unroll
    for (int m = 1; m < 32; m <<= 1) {
#pragma unroll
        for (int q = 0; q < PB_; ++q) bins[q] += __shfl_xor(bins[q], m);
        smax = fmaxf(smax, __shfl_xor(smax, m));
    }
    if (xt == 0) {
        float* dst = &binspart[row_k * (NS_ * PB_) + xc * PB_];
#pragma unroll
        for (int q = 0; q < PB_; ++q) dst[q] = bins[q];
        smaxpart[row_k * NS_ + xc] = smax;
    }
}

// K2: argmax + upper bound M per row
__global__ __launch_bounds__(256) void argmax_M(const float* __restrict__ binspart,
                                                const float* __restrict__ smaxpart,
                                                const float* __restrict__ polar_emb,
                                                int* __restrict__ main_ori,
                                                float* __restrict__ Mrow) {
    int row = blockIdx.x * 256 + threadIdx.x;
    if (row >= B_ * H_ * KL_) return;
    float s[PB_] = {};
    const float* bp = &binspart[(size_t)row * (NS_ * PB_)];
#pragma unroll
    for (int c = 0; c < NS_; ++c)
#pragma unroll
        for (int q = 0; q < PB_; ++q) s[q] += bp[c * PB_ + q];
    float best = s[0];
    int bi = 0;
#pragma unroll
    for (int q = 1; q < PB_; ++q)
        if (s[q] > best) { best = s[q]; bi = q; }
    main_ori[row] = bi;
    float sm = -3e38f;
#pragma unroll
    for (int c = 0; c < NS_; ++c) sm = fmaxf(sm, smaxpart[row * NS_ + c]);
    float pmax = polar_emb[0];
#pragma unroll
    for (int q = 1; q < PB_; ++q) pmax = fmaxf(pmax, polar_emb[q]);
    Mrow[row] = sm + pmax;
}

// K3: stream scores + V; branch-free exp; AV partials per x-chunk.
__global__ __launch_bounds__(256) void flash_cached(const float* __restrict__ qkv_x,
                                                    const __hip_bfloat16* __restrict__ Sg,
                                                    const int* __restrict__ polar_pos,
                                                    const float* __restrict__ polar_emb,
                                                    const int* __restrict__ main_ori,
                                                    const float* __restrict__ Mrow,
                                                    float* __restrict__ part) {
    const int b = blockIdx.z, h = blockIdx.y;
    const int kch = blockIdx.x / NS_, xc = blockIdx.x % NS_;
    const int k0 = kch * KC_;
    const int tid = threadIdx.x;
    const int ki = tid >> 5, xt = tid & 31;

    __shared__ __align__(16) float4 vs[XT_][9];
    __shared__ int pol_s[KC_][68];
    __shared__ float pe[PB_];

    if (tid < PB_) pe[tid] = polar_emb[tid];
    const size_t xbase = (size_t)b * XL_;
    const size_t bh = (size_t)(b * H_ + h);
    const size_t row_k = bh * KL_ + k0 + ki;
    const int mo = main_ori[row_k];
    const float M = Mrow[row_k];
    const int xbeg = xc * XCH_;

    float l = 0.f;
    float4 acc[8] = {};
    __syncthreads();
    for (int t = 0; t < XCH_ / XT_; ++t) {
        const int x0 = xbeg + t * XT_;
        __syncthreads();
#pragma unroll
        for (int i = 0; i < 2; ++i) {
            int id = tid + 256 * i;
            int row = id >> 3, c = id & 7;
            vs[row][c] = *(const float4*)&qkv_x[(xbase + x0 + row) * TDIM_ + 2 * DIM_ + h * HD_ + c * 4];
        }
        if (tid < 128) {
            int kk = tid >> 4, c = tid & 15;
            *(int4*)&pol_s[kk][c * 4] =
                *(const int4*)&polar_pos[(size_t)(b * KL_ + k0 + kk) * XL_ + x0 + c * 4];
        }
        __syncthreads();
#pragma unroll
        for (int j = 0; j < 2; ++j) {
            int xl = xt + 32 * j;
            int x = x0 + xl;
            float sp = __bfloat162float(Sg[row_k * XL_ + x]);
            int pp = pol_s[ki][xl];
            int np = pp - mo;
            np += (np >> 31) & PB_;
            float p = __expf(sp + pe[np] - M);
            l += p;
#pragma unroll
            for (int c = 0; c < 8; ++c) {
                float4 v = vs[xl][c];
                acc[c].x += p * v.x; acc[c].y += p * v.y;
                acc[c].z += p * v.z; acc[c].w += p * v.w;
            }
        }
    }
#pragma unroll
    for (int m = 1; m < 32; m <<= 1) {
        l += __shfl_xor(l, m);
#pragma unroll
        for (int c = 0; c < 8; ++c) {
            acc[c].x += __shfl_xor(acc[c].x, m);
            acc[c].y += __shfl_xor(acc[c].y, m);
            acc[c].z += __shfl_xor(acc[c].z, m);
            acc[c].w += __shfl_xor(acc[c].w, m);
        }
    }
    if (xt == 0) {
        float* dst = &part[(size_t)(row_k * NS_ + xc) * 36];
#pragma unroll
        for (int c = 0; c < 8; ++c) *(float4*)&dst[c * 4] = acc[c];
        dst[32] = l;
    }
}

// K4: plain-sum merge
__global__ __launch_bounds__(256) void merge_cached(const float* __restrict__ part,
                                                    float* __restrict__ kout_pre) {
    const int tid = threadIdx.x;
    const int ri = tid >> 5, d = tid & 31;
    const int row = blockIdx.x * 8 + ri;
    float l = 0.f, a = 0.f;
#pragma unroll
    for (int c = 0; c < NS_; ++c) {
        const float* p = &part[(size_t)(row * NS_ + c) * 36];
        l += p[32];
        a += p[d];
    }
    int k = row & (KL_ - 1);
    int bh = row >> 7;
    int h = bh & (H_ - 1), b = bh >> 3;
    kout_pre[(size_t)(b * KL_ + k) * DIM_ + h * HD_ + d] = a / l;
}

// ===========================================================================
// x-direction attention — bf16 MFMA flash kernel.
// Block = 64 x (4 waves x 16), full KL=128. QK^T and PV on matrix cores.
// Constant-shift softmax (shift-invariant); mask value -25 => e^-25 ~ 1e-11
// relative contribution (matches reference softmax(de+pe) on all-masked rows).
// ===========================================================================
__global__ __launch_bounds__(256) void attn_x_mfma(const float* __restrict__ qkv_x,
                                                   const float* __restrict__ qkv_k,
                                                   const int* __restrict__ rd,
                                                   const int* __restrict__ polar_pos,
                                                   const int* __restrict__ att_mask,
                                                   const float* __restrict__ dis_embed,
                                                   const float* __restrict__ polar_emb,
                                                   const int* __restrict__ main_ori,
                                                   float* __restrict__ xout_pre) {
    const int b = blockIdx.z, h = blockIdx.y;
    const int x0 = blockIdx.x * 64;
    const int tid = threadIdx.x;
    const int wave = tid >> 6, lane = tid & 63;
    const int c = lane & 15, q = lane >> 4;

    __shared__ __align__(16) unsigned short Kk_s[KL_][40];   // bf16 Kk[k][d]
    __shared__ __align__(16) unsigned short VT_s[HD_][136];  // bf16 V^T[d][k]
    __shared__ __align__(16) unsigned short P_s[4][16][136]; // bf16 P per wave
    __shared__ unsigned short rp_s[KL_][72];                 // rv | npb<<8 | msk<<15
    __shared__ float de_h[NDIS_];
    __shared__ float pe[PB_];
    __shared__ int mo_s[KL_];

    const size_t bh = (size_t)(b * H_ + h);
    if (tid < NDIS_) de_h[tid] = dis_embed[tid * H_ + h];
    if (tid < PB_) pe[tid] = polar_emb[tid];
    if (tid < KL_) mo_s[tid] = main_ori[bh * KL_ + tid];

    // stage Kk (bf16) and V transposed (bf16)
    {
        int row = tid >> 1, half = tid & 1;
        const float* src = &qkv_k[(size_t)(b * KL_ + row) * TDIM_ + h * HD_ + half * 16];
#pragma unroll
        for (int j = 0; j < 16; ++j) Kk_s[row][half * 16 + j] = f2bf(src[DIM_ + j]);
#pragma unroll
        for (int j = 0; j < 16; ++j) VT_s[half * 16 + j][row] = f2bf(src[2 * DIM_ + j]);
    }
    __syncthreads();  // mo_s ready

    // rp pass 1: rv | npb<<8 (coalesced [k][x] loads)
#pragma unroll
    for (int i = 0; i < 8; ++i) {
        int id = tid + 256 * i;
        int k = id >> 4, cc = id & 15;
        size_t gb = (size_t)(b * KL_ + k) * XL_ + x0 + cc * 4;
        int4 r4 = *(const int4*)&rd[gb];
        int4 p4 = *(const int4*)&polar_pos[gb];
        int mo = mo_s[k];
        int n0 = p4.x - mo; n0 += (n0 >> 31) & PB_;
        int n1 = p4.y - mo; n1 += (n1 >> 31) & PB_;
        int n2 = p4.z - mo; n2 += (n2 >> 31) & PB_;
        int n3 = p4.w - mo; n3 += (n3 >> 31) & PB_;
        rp_s[k][cc * 4 + 0] = (unsigned short)(r4.x | (n0 << 8));
        rp_s[k][cc * 4 + 1] = (unsigned short)(r4.y | (n1 << 8));
        rp_s[k][cc * 4 + 2] = (unsigned short)(r4.z | (n2 << 8));
        rp_s[k][cc * 4 + 3] = (unsigned short)(r4.w | (n3 << 8));
    }
    __syncthreads();
    // rp pass 2: fold mask bit (coalesced [x][k] loads)
#pragma unroll
    for (int i = 0; i < 8; ++i) {
        int id = tid + 256 * i;
        int xr = id >> 5, kc = id & 31;
        int4 m4 = *(const int4*)&att_mask[(bh * XL_ + x0 + xr) * KL_ + kc * 4];
        if (m4.x) rp_s[kc * 4 + 0][xr] |= 0x8000;
        if (m4.y) rp_s[kc * 4 + 1][xr] |= 0x8000;
        if (m4.z) rp_s[kc * 4 + 2][xr] |= 0x8000;
        if (m4.w) rp_s[kc * 4 + 3][xr] |= 0x8000;
    }
    __syncthreads();

    // Q A-fragment: lane holds Q[x = x0+wave*16+c][d = q*8 .. +7] as bf16x8
    v8s aq;
    {
        const float* qp = &qkv_x[(size_t)(b * XL_ + x0 + wave * 16 + c) * TDIM_ + h * HD_ + q * 8];
        float4 q0 = *(const float4*)&qp[0];
        float4 q1 = *(const float4*)&qp[4];
        aq[0] = (short)f2bf(q0.x); aq[1] = (short)f2bf(q0.y);
        aq[2] = (short)f2bf(q0.z); aq[3] = (short)f2bf(q0.w);
        aq[4] = (short)f2bf(q1.x); aq[5] = (short)f2bf(q1.y);
        aq[6] = (short)f2bf(q1.z); aq[7] = (short)f2bf(q1.w);
    }

    // QK^T: 8 k-tiles of 16
    v4f S[8];
#pragma unroll
    for (int t = 0; t < 8; ++t) {
        v8s bk = *(v8s*)&Kk_s[t * 16 + c][q * 8];
        S[t] = __builtin_amdgcn_mfma_f32_16x16x32_bf16(aq, bk, (v4f){0.f, 0.f, 0.f, 0.f}, 0, 0, 0);
    }

    // bias + exp + P store (bf16) + row sums (of the bf16-rounded p)
    const int xloc = wave * 16;
    float lr[4] = {0.f, 0.f, 0.f, 0.f};
#pragma unroll
    for (int t = 0; t < 8; ++t) {
#pragma unroll
        for (int r = 0; r < 4; ++r) {
            int krow = t * 16 + c;
            int xrow = q * 4 + r;
            unsigned short rp = rp_s[krow][xloc + xrow];
            float sval = S[t][r] * SCALE_;
            float tval = ((rp & 0x8000) ? -25.0f : sval) + de_h[rp & 0x7f] + pe[(rp >> 8) & 7];
            float p = __expf(tval);
            unsigned short pb = f2bf(p);
            P_s[wave][xrow][krow] = pb;
            lr[r] += bf2f(pb);
        }
    }
#pragma unroll
    for (int r = 0; r < 4; ++r) {
#pragma unroll
        for (int m = 1; m < 16; m <<= 1) lr[r] += __shfl_xor(lr[r], m);
    }
    __syncthreads();  // P_s visible

    // PV: O[16x][32d] accumulated over 4 K=32 chunks, 2 d-tiles
    v4f O0 = {0.f, 0.f, 0.f, 0.f}, O1 = {0.f, 0.f, 0.f, 0.f};
#pragma unroll
    for (int kc = 0; kc < 4; ++kc) {
        v8s ap = *(v8s*)&P_s[wave][c][kc * 32 + q * 8];
        v8s bv0 = *(v8s*)&VT_s[c][kc * 32 + q * 8];
        v8s bv1 = *(v8s*)&VT_s[16 + c][kc * 32 + q * 8];
        O0 = __builtin_amdgcn_mfma_f32_16x16x32_bf16(ap, bv0, O0, 0, 0, 0);
        O1 = __builtin_amdgcn_mfma_f32_16x16x32_bf16(ap, bv1, O1, 0, 0, 0);
    }

    // write out: x = x0 + wave*16 + q*4 + r; d = c (O0) / 16+c (O1)
#pragma unroll
    for (int r = 0; r < 4; ++r) {
        int xg = x0 + wave * 16 + q * 4 + r;
        float inv = 1.0f / lr[r];
        float* op = &xout_pre[(size_t)(b * XL_ + xg) * DIM_ + h * HD_];
        op[c] = O0[r] * inv;
        op[16 + c] = O1[r] * inv;
    }
}

// ---------------------------------------------------------------------------
extern "C" void kernel_launch(void* const* d_in, const int* in_sizes, int n_in,
                              void* d_out, int out_size, void* d_ws, size_t ws_size,
                              hipStream_t stream) {
    const float* x         = (const float*)d_in[0];
    const float* kernal    = (const float*)d_in[1];
    const int* rd          = (const int*)d_in[2];
    const int* polar_pos   = (const int*)d_in[3];
    const int* att_mask    = (const int*)d_in[4];
    const float* W_qkv     = (const float*)d_in[5];
    const float* dis_embed = (const float*)d_in[6];
    const float* polar_emb = (const float*)d_in[7];
    const float* W_proj    = (const float*)d_in[8];
    const float* b_proj    = (const float*)d_in[9];
    float* out             = (float*)d_out;

    char* base = (char*)d_ws;
    size_t off = 0;
    auto alloc = [&](size_t bytes) { void* p = base + off; off = (off + bytes + 255) & ~255ULL; return p; };
    float* qkv_x    = (float*)alloc((size_t)B_ * XL_ * TDIM_ * 4);
    float* qkv_k    = (float*)alloc((size_t)B_ * KL_ * TDIM_ * 4);
    float* xout_pre = (float*)alloc((size_t)B_ * XL_ * DIM_ * 4);
    float* kout_pre = (float*)alloc((size_t)B_ * KL_ * DIM_ * 4);
    int* main_ori   = (int*)alloc(B_ * H_ * KL_ * 4);
    float* Mrow     = (float*)alloc(B_ * H_ * KL_ * 4);
    float* binspart = (float*)alloc((size_t)B_ * H_ * KL_ * NS_ * PB_ * 4);
    float* smaxpart = (float*)alloc((size_t)B_ * H_ * KL_ * NS_ * 4);
    float* part     = (float*)alloc((size_t)B_ * H_ * KL_ * NS_ * 36 * 4);
    __hip_bfloat16* Sg = (__hip_bfloat16*)alloc((size_t)B_ * H_ * KL_ * XL_ * 2);

    gemm128<<<dim3(TDIM_ / 128, (B_ * XL_) / 128), 256, 0, stream>>>(
        x, W_qkv, qkv_x, nullptr, B_ * XL_, TDIM_, DIM_);
    gemm64<<<dim3(TDIM_ / 64, (B_ * KL_) / 64), 256, 0, stream>>>(
        kernal, W_qkv, qkv_k, nullptr, B_ * KL_, TDIM_, DIM_);

    score_bins<<<dim3((KL_ / KC_) * NS_, H_, B_), 256, 0, stream>>>(
        qkv_k, qkv_x, rd, polar_pos, att_mask, dis_embed, Sg, binspart, smaxpart);
    argmax_M<<<dim3((B_ * H_ * KL_ + 255) / 256), 256, 0, stream>>>(
        binspart, smaxpart, polar_emb, main_ori, Mrow);
    flash_cached<<<dim3((KL_ / KC_) * NS_, H_, B_), 256, 0, stream>>>(
        qkv_x, Sg, polar_pos, polar_emb, main_ori, Mrow, part);
    merge_cached<<<dim3(B_ * H_ * KL_ / 8), 256, 0, stream>>>(part, kout_pre);

    attn_x_mfma<<<dim3(XL_ / 64, H_, B_), 256, 0, stream>>>(
        qkv_x, qkv_k, rd, polar_pos, att_mask, dis_embed, polar_emb, main_ori, xout_pre);

    gemm128<<<dim3(DIM_ / 128, (B_ * XL_) / 128), 256, 0, stream>>>(
        xout_pre, W_proj, out, b_proj, B_ * XL_, DIM_, DIM_);
    gemm64<<<dim3(DIM_ / 64, (B_ * KL_) / 64), 256, 0, stream>>>(
        kout_pre, W_proj, out + (size_t)B_ * XL_ * DIM_, b_proj, B_ * KL_, DIM_, DIM_);
}

// Round 12
// 455.328 us; speedup vs baseline: 1.3429x; 1.0376x over previous
//
#include <hip/hip_runtime.h>
#include <hip/hip_bf16.h>

#define B_    4
#define KL_   128
#define XL_   4096
#define DIM_  256
#define H_    8
#define HD_   32
#define PB_   8
#define NDIS_ 66
#define TDIM_ 768
#define SCALE_ 0.17677669529663687f
#define XT_   64
#define KC_   8
#define NS_   4
#define XCH_  (XL_ / NS_)  // 1024 (flash_cached chunking)
#define NCH_  64           // score_bins x-chunks (64 x each)

typedef float v4f __attribute__((ext_vector_type(4)));
typedef short v8s __attribute__((ext_vector_type(8)));

__device__ __forceinline__ unsigned short f2bf(float f) {
    __hip_bfloat16 h = __float2bfloat16(f);
    return __builtin_bit_cast(unsigned short, h);
}
__device__ __forceinline__ float bf2f(unsigned short u) {
    return __bfloat162float(__builtin_bit_cast(__hip_bfloat16, u));
}
__device__ __forceinline__ void cvt_hilo(float v, unsigned short& hi, unsigned short& lo) {
    hi = f2bf(v);
    lo = f2bf(v - bf2f(hi));
}

// ---------------------------------------------------------------------------
// 128x128 f32 GEMM, BK=8, 8x8 per thread.
// ---------------------------------------------------------------------------
__global__ __launch_bounds__(256) void gemm128(const float* __restrict__ A,
                                               const float* __restrict__ Bw,
                                               float* __restrict__ C,
                                               const float* __restrict__ bias,
                                               int M, int N, int K) {
    __shared__ __align__(16) float As[8][132];
    __shared__ __align__(16) float Bs[8][128];
    const int tid = threadIdx.x;
    const int tx = tid & 15, ty = tid >> 4;
    const int bn = blockIdx.x * 128, bm = blockIdx.y * 128;
    const int arow = tid >> 1, acol = (tid & 1) * 4;
    const int brow = tid >> 5, bcol = (tid & 31) * 4;
    float acc[8][8] = {};
    for (int k0 = 0; k0 < K; k0 += 8) {
        float4 a4 = *(const float4*)&A[(size_t)(bm + arow) * K + k0 + acol];
        As[acol + 0][arow] = a4.x;
        As[acol + 1][arow] = a4.y;
        As[acol + 2][arow] = a4.z;
        As[acol + 3][arow] = a4.w;
        *(float4*)&Bs[brow][bcol] = *(const float4*)&Bw[(size_t)(k0 + brow) * N + bn + bcol];
        __syncthreads();
#pragma unroll
        for (int kk = 0; kk < 8; ++kk) {
            float4 a0 = *(const float4*)&As[kk][ty * 8];
            float4 a1 = *(const float4*)&As[kk][ty * 8 + 4];
            float4 b0 = *(const float4*)&Bs[kk][tx * 8];
            float4 b1 = *(const float4*)&Bs[kk][tx * 8 + 4];
            float a[8] = {a0.x, a0.y, a0.z, a0.w, a1.x, a1.y, a1.z, a1.w};
            float b[8] = {b0.x, b0.y, b0.z, b0.w, b1.x, b1.y, b1.z, b1.w};
#pragma unroll
            for (int i = 0; i < 8; ++i)
#pragma unroll
                for (int j = 0; j < 8; ++j) acc[i][j] += a[i] * b[j];
        }
        __syncthreads();
    }
#pragma unroll
    for (int i = 0; i < 8; ++i) {
        int m = bm + ty * 8 + i;
        float* cp = &C[(size_t)m * N + bn + tx * 8];
        float4 o0 = {acc[i][0], acc[i][1], acc[i][2], acc[i][3]};
        float4 o1 = {acc[i][4], acc[i][5], acc[i][6], acc[i][7]};
        if (bias) {
            const float* bp = &bias[bn + tx * 8];
            o0.x += bp[0]; o0.y += bp[1]; o0.z += bp[2]; o0.w += bp[3];
            o1.x += bp[4]; o1.y += bp[5]; o1.z += bp[6]; o1.w += bp[7];
        }
        *(float4*)cp = o0;
        *(float4*)(cp + 4) = o1;
    }
}

// ---------------------------------------------------------------------------
// 64x64 f32 GEMM (small-M)
// ---------------------------------------------------------------------------
__global__ __launch_bounds__(256) void gemm64(const float* __restrict__ A,
                                              const float* __restrict__ Bw,
                                              float* __restrict__ C,
                                              const float* __restrict__ bias,
                                              int M, int N, int K) {
    __shared__ __align__(16) float As[16][68];
    __shared__ __align__(16) float Bs[16][64];
    const int tid = threadIdx.x;
    const int tx = tid & 15, ty = tid >> 4;
    const int bn = blockIdx.x * 64, bm = blockIdx.y * 64;
    const int am = tid >> 2, ac = tid & 3;
    float acc[4][4] = {};
    for (int k0 = 0; k0 < K; k0 += 16) {
        float4 a4 = *(const float4*)&A[(size_t)(bm + am) * K + k0 + ac * 4];
        As[ac * 4 + 0][am] = a4.x;
        As[ac * 4 + 1][am] = a4.y;
        As[ac * 4 + 2][am] = a4.z;
        As[ac * 4 + 3][am] = a4.w;
        *(float4*)&Bs[ty][tx * 4] = *(const float4*)&Bw[(size_t)(k0 + ty) * N + bn + tx * 4];
        __syncthreads();
#pragma unroll
        for (int kk = 0; kk < 16; ++kk) {
            float4 av = *(const float4*)&As[kk][ty * 4];
            float4 bv = *(const float4*)&Bs[kk][tx * 4];
            float a[4] = {av.x, av.y, av.z, av.w};
            float b[4] = {bv.x, bv.y, bv.z, bv.w};
#pragma unroll
            for (int i = 0; i < 4; ++i)
#pragma unroll
                for (int j = 0; j < 4; ++j) acc[i][j] += a[i] * b[j];
        }
        __syncthreads();
    }
#pragma unroll
    for (int i = 0; i < 4; ++i) {
        int m = bm + ty * 4 + i;
#pragma unroll
        for (int j = 0; j < 4; ++j) {
            int n = bn + tx * 4 + j;
            float v = acc[i][j];
            if (bias) v += bias[n];
            C[(size_t)m * N + n] = v;
        }
    }
}

// ===========================================================================
// K1: score_bins_mfma — split-bf16 MFMA QK^T for the k-direction.
// Block = (b, h, 64-x chunk); full KL=128. D[row=x][col=k] per 16x16 tile.
// Outputs: Sg (bf16 masked+de scores), binspart (f32-exact polar bins per
// 64-x chunk). Masked score = -1e6+de => exp underflows to exact 0 later,
// so no row-max pass is needed anywhere (constant-shift softmax).
// ===========================================================================
__global__ __launch_bounds__(256) void score_bins_mfma(const float* __restrict__ qkv_k,
                                                       const float* __restrict__ qkv_x,
                                                       const int* __restrict__ rd,
                                                       const int* __restrict__ polar_pos,
                                                       const int* __restrict__ att_mask,
                                                       const float* __restrict__ dis_embed,
                                                       __hip_bfloat16* __restrict__ Sg,
                                                       float* __restrict__ binspart) {
    const int b = blockIdx.z, h = blockIdx.y, xc = blockIdx.x;
    const int x0 = xc * 64;
    const int tid = threadIdx.x;
    const int w = tid >> 6, lane = tid & 63;
    const int c15 = lane & 15, q = lane >> 4;
    const size_t bh = (size_t)(b * H_ + h);

    __shared__ __align__(16) unsigned short Kxh[64][40];
    __shared__ __align__(16) unsigned short Kxl[64][40];
    __shared__ __align__(16) unsigned short Kqh[KL_][40];
    __shared__ __align__(16) unsigned short Kql[KL_][40];
    __shared__ __align__(16) unsigned short combo[KL_][68];  // rd | pol<<8 | msk<<15
    __shared__ float binsW[4][16][PB_];
    __shared__ float de_h[NDIS_];

    if (tid < NDIS_) de_h[tid] = dis_embed[tid * H_ + h];

    // stage Kx (keys of this x-chunk) hi/lo bf16
    {
        int row = tid >> 2, dg = (tid & 3) * 8;
        const float* src = &qkv_x[((size_t)b * XL_ + x0 + row) * TDIM_ + DIM_ + h * HD_ + dg];
        float4 v0 = *(const float4*)&src[0];
        float4 v1 = *(const float4*)&src[4];
        float vv[8] = {v0.x, v0.y, v0.z, v0.w, v1.x, v1.y, v1.z, v1.w};
        unsigned short hi[8], lo[8];
#pragma unroll
        for (int j = 0; j < 8; ++j) cvt_hilo(vv[j], hi[j], lo[j]);
        *(ushort4*)&Kxh[row][dg] = *(ushort4*)&hi[0];
        *(ushort4*)&Kxh[row][dg + 4] = *(ushort4*)&hi[4];
        *(ushort4*)&Kxl[row][dg] = *(ushort4*)&lo[0];
        *(ushort4*)&Kxl[row][dg + 4] = *(ushort4*)&lo[4];
    }
    // stage Kq (k_q rows, all 128) hi/lo bf16
    {
        int k = tid >> 1, dg = (tid & 1) * 16;
        const float* src = &qkv_k[((size_t)(b * KL_ + k)) * TDIM_ + h * HD_ + dg];
        unsigned short hi[16], lo[16];
#pragma unroll
        for (int j4 = 0; j4 < 4; ++j4) {
            float4 v = *(const float4*)&src[j4 * 4];
            cvt_hilo(v.x, hi[j4 * 4 + 0], lo[j4 * 4 + 0]);
            cvt_hilo(v.y, hi[j4 * 4 + 1], lo[j4 * 4 + 1]);
            cvt_hilo(v.z, hi[j4 * 4 + 2], lo[j4 * 4 + 2]);
            cvt_hilo(v.w, hi[j4 * 4 + 3], lo[j4 * 4 + 3]);
        }
#pragma unroll
        for (int j4 = 0; j4 < 4; ++j4) {
            *(ushort4*)&Kqh[k][dg + j4 * 4] = *(ushort4*)&hi[j4 * 4];
            *(ushort4*)&Kql[k][dg + j4 * 4] = *(ushort4*)&lo[j4 * 4];
        }
    }
    // stage combo: rd | pol<<8
    {
        int k = tid >> 1, xh = (tid & 1) * 32;
        size_t gb = ((size_t)(b * KL_ + k)) * XL_ + x0 + xh;
#pragma unroll
        for (int i = 0; i < 8; ++i) {
            int4 r4 = *(const int4*)&rd[gb + i * 4];
            int4 p4 = *(const int4*)&polar_pos[gb + i * 4];
            ushort4 cv;
            cv.x = (unsigned short)(r4.x | (p4.x << 8));
            cv.y = (unsigned short)(r4.y | (p4.y << 8));
            cv.z = (unsigned short)(r4.z | (p4.z << 8));
            cv.w = (unsigned short)(r4.w | (p4.w << 8));
            *(ushort4*)&combo[k][xh + i * 4] = cv;
        }
    }
    __syncthreads();
    // fold mask bit ([x][k] layout, coalesced)
    {
        int xr = tid >> 2, kc = (tid & 3) * 32;
        size_t gb = (bh * XL_ + x0 + xr) * KL_ + kc;
#pragma unroll
        for (int i = 0; i < 8; ++i) {
            int4 m4 = *(const int4*)&att_mask[gb + i * 4];
            if (m4.x) combo[kc + i * 4 + 0][xr] |= 0x8000;
            if (m4.y) combo[kc + i * 4 + 1][xr] |= 0x8000;
            if (m4.z) combo[kc + i * 4 + 2][xr] |= 0x8000;
            if (m4.w) combo[kc + i * 4 + 3][xr] |= 0x8000;
        }
    }
    __syncthreads();

    // A-frags for this wave's 16-x tile (constant across nt)
    v8s axh = *(v8s*)&Kxh[w * 16 + c15][q * 8];
    v8s axl = *(v8s*)&Kxl[w * 16 + c15][q * 8];

    for (int nt = 0; nt < 8; ++nt) {
        v8s bqh = *(v8s*)&Kqh[nt * 16 + c15][q * 8];
        v8s bql = *(v8s*)&Kql[nt * 16 + c15][q * 8];
        v4f D = {0.f, 0.f, 0.f, 0.f};
        D = __builtin_amdgcn_mfma_f32_16x16x32_bf16(axl, bqh, D, 0, 0, 0);
        D = __builtin_amdgcn_mfma_f32_16x16x32_bf16(axh, bql, D, 0, 0, 0);
        D = __builtin_amdgcn_mfma_f32_16x16x32_bf16(axh, bqh, D, 0, 0, 0);

        const int k = nt * 16 + c15;
        const size_t row_k = bh * KL_ + k;
        float bins[PB_] = {};
        ushort4 pack;
#pragma unroll
        for (int r = 0; r < 4; ++r) {
            int xl_ = w * 16 + q * 4 + r;
            float s = D[r] * SCALE_;
            unsigned cb = combo[k][xl_];
            float a = fabsf(s);
            int pp = (cb >> 8) & 7;
#pragma unroll
            for (int pb = 0; pb < PB_; ++pb) bins[pb] += (pp == pb) ? a : 0.0f;
            float sp = ((cb & 0x8000) ? -1e6f : s) + de_h[cb & 0x7f];
            ((unsigned short*)&pack)[r] = f2bf(sp);
        }
        *(ushort4*)((unsigned short*)Sg + row_k * XL_ + x0 + w * 16 + q * 4) = pack;

        // reduce bins across quads (same k shared by 4 quads)
#pragma unroll
        for (int pb = 0; pb < PB_; ++pb) {
            bins[pb] += __shfl_xor(bins[pb], 16);
            bins[pb] += __shfl_xor(bins[pb], 32);
        }
        if (q == 0) {
#pragma unroll
            for (int pb = 0; pb < PB_; ++pb) binsW[w][c15][pb] = bins[pb];
        }
        __syncthreads();
        if (tid < 128) {
            int k16 = tid >> 3, pb = tid & 7;
            float v = binsW[0][k16][pb] + binsW[1][k16][pb] + binsW[2][k16][pb] + binsW[3][k16][pb];
            binspart[(bh * KL_ + nt * 16 + k16) * (NCH_ * PB_) + xc * PB_ + pb] = v;
        }
        __syncthreads();
    }
}

// K2: argmax over summed bins -> main_ori. One wave per (b,h,k) row.
__global__ __launch_bounds__(256) void bins_argmax(const float* __restrict__ binspart,
                                                   int* __restrict__ main_ori) {
    const int w = threadIdx.x >> 6, lane = threadIdx.x & 63;
    const int row = blockIdx.x * 4 + w;
    const float* bp = &binspart[(size_t)row * (NCH_ * PB_) + lane * PB_];
    float s[PB_];
#pragma unroll
    for (int pb = 0; pb < PB_; ++pb) s[pb] = bp[pb];
#pragma unroll
    for (int m = 1; m < 64; m <<= 1)
#pragma unroll
        for (int pb = 0; pb < PB_; ++pb) s[pb] += __shfl_xor(s[pb], m);
    if (lane == 0) {
        float best = s[0];
        int bi = 0;
#pragma unroll
        for (int pb = 1; pb < PB_; ++pb)
            if (s[pb] > best) { best = s[pb]; bi = pb; }
        main_ori[row] = bi;
    }
}

// K3: stream scores + V; exp (no shift; masked scores underflow to 0); AV.
__global__ __launch_bounds__(256) void flash_cached(const float* __restrict__ qkv_x,
                                                    const __hip_bfloat16* __restrict__ Sg,
                                                    const int* __restrict__ polar_pos,
                                                    const float* __restrict__ polar_emb,
                                                    const int* __restrict__ main_ori,
                                                    float* __restrict__ part) {
    const int b = blockIdx.z, h = blockIdx.y;
    const int kch = blockIdx.x / NS_, xc = blockIdx.x % NS_;
    const int k0 = kch * KC_;
    const int tid = threadIdx.x;
    const int ki = tid >> 5, xt = tid & 31;

    __shared__ __align__(16) float4 vs[XT_][9];
    __shared__ int pol_s[KC_][68];
    __shared__ float pe[PB_];

    if (tid < PB_) pe[tid] = polar_emb[tid];
    const size_t xbase = (size_t)b * XL_;
    const size_t bh = (size_t)(b * H_ + h);
    const size_t row_k = bh * KL_ + k0 + ki;
    const int mo = main_ori[row_k];
    const int xbeg = xc * XCH_;

    float l = 0.f;
    float4 acc[8] = {};
    __syncthreads();
    for (int t = 0; t < XCH_ / XT_; ++t) {
        const int x0 = xbeg + t * XT_;
        __syncthreads();
#pragma unroll
        for (int i = 0; i < 2; ++i) {
            int id = tid + 256 * i;
            int row = id >> 3, c = id & 7;
            vs[row][c] = *(const float4*)&qkv_x[(xbase + x0 + row) * TDIM_ + 2 * DIM_ + h * HD_ + c * 4];
        }
        if (tid < 128) {
            int kk = tid >> 4, c = tid & 15;
            *(int4*)&pol_s[kk][c * 4] =
                *(const int4*)&polar_pos[(size_t)(b * KL_ + k0 + kk) * XL_ + x0 + c * 4];
        }
        __syncthreads();
#pragma unroll
        for (int j = 0; j < 2; ++j) {
            int xl = xt + 32 * j;
            int x = x0 + xl;
            float sp = __bfloat162float(Sg[row_k * XL_ + x]);
            int pp = pol_s[ki][xl];
            int np = pp - mo;
            np += (np >> 31) & PB_;
            float p = __expf(sp + pe[np]);
            l += p;
#pragma unroll
            for (int c = 0; c < 8; ++c) {
                float4 v = vs[xl][c];
                acc[c].x += p * v.x; acc[c].y += p * v.y;
                acc[c].z += p * v.z; acc[c].w += p * v.w;
            }
        }
    }
#pragma unroll
    for (int m = 1; m < 32; m <<= 1) {
        l += __shfl_xor(l, m);
#pragma unroll
        for (int c = 0; c < 8; ++c) {
            acc[c].x += __shfl_xor(acc[c].x, m);
            acc[c].y += __shfl_xor(acc[c].y, m);
            acc[c].z += __shfl_xor(acc[c].z, m);
            acc[c].w += __shfl_xor(acc[c].w, m);
        }
    }
    if (xt == 0) {
        float* dst = &part[(size_t)(row_k * NS_ + xc) * 36];
#pragma unroll
        for (int c = 0; c < 8; ++c) *(float4*)&dst[c * 4] = acc[c];
        dst[32] = l;
    }
}

// K4: plain-sum merge
__global__ __launch_bounds__(256) void merge_cached(const float* __restrict__ part,
                                                    float* __restrict__ kout_pre) {
    const int tid = threadIdx.x;
    const int ri = tid >> 5, d = tid & 31;
    const int row = blockIdx.x * 8 + ri;
    float l = 0.f, a = 0.f;
#pragma unroll
    for (int c = 0; c < NS_; ++c) {
        const float* p = &part[(size_t)(row * NS_ + c) * 36];
        l += p[32];
        a += p[d];
    }
    int k = row & (KL_ - 1);
    int bh = row >> 7;
    int h = bh & (H_ - 1), b = bh >> 3;
    kout_pre[(size_t)(b * KL_ + k) * DIM_ + h * HD_ + d] = a / l;
}

// ===========================================================================
// x-direction attention — bf16 MFMA flash kernel (unchanged from R11).
// ===========================================================================
__global__ __launch_bounds__(256) void attn_x_mfma(const float* __restrict__ qkv_x,
                                                   const float* __restrict__ qkv_k,
                                                   const int* __restrict__ rd,
                                                   const int* __restrict__ polar_pos,
                                                   const int* __restrict__ att_mask,
                                                   const float* __restrict__ dis_embed,
                                                   const float* __restrict__ polar_emb,
                                                   const int* __restrict__ main_ori,
                                                   float* __restrict__ xout_pre) {
    const int b = blockIdx.z, h = blockIdx.y;
    const int x0 = blockIdx.x * 64;
    const int tid = threadIdx.x;
    const int wave = tid >> 6, lane = tid & 63;
    const int c = lane & 15, q = lane >> 4;

    __shared__ __align__(16) unsigned short Kk_s[KL_][40];
    __shared__ __align__(16) unsigned short VT_s[HD_][136];
    __shared__ __align__(16) unsigned short P_s[4][16][136];
    __shared__ unsigned short rp_s[KL_][72];
    __shared__ float de_h[NDIS_];
    __shared__ float pe[PB_];
    __shared__ int mo_s[KL_];

    const size_t bh = (size_t)(b * H_ + h);
    if (tid < NDIS_) de_h[tid] = dis_embed[tid * H_ + h];
    if (tid < PB_) pe[tid] = polar_emb[tid];
    if (tid < KL_) mo_s[tid] = main_ori[bh * KL_ + tid];

    {
        int row = tid >> 1, half = tid & 1;
        const float* src = &qkv_k[(size_t)(b * KL_ + row) * TDIM_ + h * HD_ + half * 16];
#pragma unroll
        for (int j = 0; j < 16; ++j) Kk_s[row][half * 16 + j] = f2bf(src[DIM_ + j]);
#pragma unroll
        for (int j = 0; j < 16; ++j) VT_s[half * 16 + j][row] = f2bf(src[2 * DIM_ + j]);
    }
    __syncthreads();

#pragma unroll
    for (int i = 0; i < 8; ++i) {
        int id = tid + 256 * i;
        int k = id >> 4, cc = id & 15;
        size_t gb = (size_t)(b * KL_ + k) * XL_ + x0 + cc * 4;
        int4 r4 = *(const int4*)&rd[gb];
        int4 p4 = *(const int4*)&polar_pos[gb];
        int mo = mo_s[k];
        int n0 = p4.x - mo; n0 += (n0 >> 31) & PB_;
        int n1 = p4.y - mo; n1 += (n1 >> 31) & PB_;
        int n2 = p4.z - mo; n2 += (n2 >> 31) & PB_;
        int n3 = p4.w - mo; n3 += (n3 >> 31) & PB_;
        rp_s[k][cc * 4 + 0] = (unsigned short)(r4.x | (n0 << 8));
        rp_s[k][cc * 4 + 1] = (unsigned short)(r4.y | (n1 << 8));
        rp_s[k][cc * 4 + 2] = (unsigned short)(r4.z | (n2 << 8));
        rp_s[k][cc * 4 + 3] = (unsigned short)(r4.w | (n3 << 8));
    }
    __syncthreads();
#pragma unroll
    for (int i = 0; i < 8; ++i) {
        int id = tid + 256 * i;
        int xr = id >> 5, kc = id & 31;
        int4 m4 = *(const int4*)&att_mask[(bh * XL_ + x0 + xr) * KL_ + kc * 4];
        if (m4.x) rp_s[kc * 4 + 0][xr] |= 0x8000;
        if (m4.y) rp_s[kc * 4 + 1][xr] |= 0x8000;
        if (m4.z) rp_s[kc * 4 + 2][xr] |= 0x8000;
        if (m4.w) rp_s[kc * 4 + 3][xr] |= 0x8000;
    }
    __syncthreads();

    v8s aq;
    {
        const float* qp = &qkv_x[(size_t)(b * XL_ + x0 + wave * 16 + c) * TDIM_ + h * HD_ + q * 8];
        float4 q0 = *(const float4*)&qp[0];
        float4 q1 = *(const float4*)&qp[4];
        aq[0] = (short)f2bf(q0.x); aq[1] = (short)f2bf(q0.y);
        aq[2] = (short)f2bf(q0.z); aq[3] = (short)f2bf(q0.w);
        aq[4] = (short)f2bf(q1.x); aq[5] = (short)f2bf(q1.y);
        aq[6] = (short)f2bf(q1.z); aq[7] = (short)f2bf(q1.w);
    }

    v4f S[8];
#pragma unroll
    for (int t = 0; t < 8; ++t) {
        v8s bk = *(v8s*)&Kk_s[t * 16 + c][q * 8];
        S[t] = __builtin_amdgcn_mfma_f32_16x16x32_bf16(aq, bk, (v4f){0.f, 0.f, 0.f, 0.f}, 0, 0, 0);
    }

    const int xloc = wave * 16;
    float lr[4] = {0.f, 0.f, 0.f, 0.f};
#pragma unroll
    for (int t = 0; t < 8; ++t) {
#pragma unroll
        for (int r = 0; r < 4; ++r) {
            int krow = t * 16 + c;
            int xrow = q * 4 + r;
            unsigned short rp = rp_s[krow][xloc + xrow];
            float sval = S[t][r] * SCALE_;
            float tval = ((rp & 0x8000) ? -25.0f : sval) + de_h[rp & 0x7f] + pe[(rp >> 8) & 7];
            float p = __expf(tval);
            unsigned short pb = f2bf(p);
            P_s[wave][xrow][krow] = pb;
            lr[r] += bf2f(pb);
        }
    }
#pragma unroll
    for (int r = 0; r < 4; ++r) {
#pragma unroll
        for (int m = 1; m < 16; m <<= 1) lr[r] += __shfl_xor(lr[r], m);
    }
    __syncthreads();

    v4f O0 = {0.f, 0.f, 0.f, 0.f}, O1 = {0.f, 0.f, 0.f, 0.f};
#pragma unroll
    for (int kc = 0; kc < 4; ++kc) {
        v8s ap = *(v8s*)&P_s[wave][c][kc * 32 + q * 8];
        v8s bv0 = *(v8s*)&VT_s[c][kc * 32 + q * 8];
        v8s bv1 = *(v8s*)&VT_s[16 + c][kc * 32 + q * 8];
        O0 = __builtin_amdgcn_mfma_f32_16x16x32_bf16(ap, bv0, O0, 0, 0, 0);
        O1 = __builtin_amdgcn_mfma_f32_16x16x32_bf16(ap, bv1, O1, 0, 0, 0);
    }

#pragma unroll
    for (int r = 0; r < 4; ++r) {
        int xg = x0 + wave * 16 + q * 4 + r;
        float inv = 1.0f / lr[r];
        float* op = &xout_pre[(size_t)(b * XL_ + xg) * DIM_ + h * HD_];
        op[c] = O0[r] * inv;
        op[16 + c] = O1[r] * inv;
    }
}

// ---------------------------------------------------------------------------
extern "C" void kernel_launch(void* const* d_in, const int* in_sizes, int n_in,
                              void* d_out, int out_size, void* d_ws, size_t ws_size,
                              hipStream_t stream) {
    const float* x         = (const float*)d_in[0];
    const float* kernal    = (const float*)d_in[1];
    const int* rd          = (const int*)d_in[2];
    const int* polar_pos   = (const int*)d_in[3];
    const int* att_mask    = (const int*)d_in[4];
    const float* W_qkv     = (const float*)d_in[5];
    const float* dis_embed = (const float*)d_in[6];
    const float* polar_emb = (const float*)d_in[7];
    const float* W_proj    = (const float*)d_in[8];
    const float* b_proj    = (const float*)d_in[9];
    float* out             = (float*)d_out;

    char* base = (char*)d_ws;
    size_t off = 0;
    auto alloc = [&](size_t bytes) { void* p = base + off; off = (off + bytes + 255) & ~255ULL; return p; };
    float* qkv_x    = (float*)alloc((size_t)B_ * XL_ * TDIM_ * 4);     // 50.3 MB
    float* qkv_k    = (float*)alloc((size_t)B_ * KL_ * TDIM_ * 4);     // 1.6 MB
    float* xout_pre = (float*)alloc((size_t)B_ * XL_ * DIM_ * 4);      // 16.8 MB
    float* kout_pre = (float*)alloc((size_t)B_ * KL_ * DIM_ * 4);      // 0.5 MB
    int* main_ori   = (int*)alloc(B_ * H_ * KL_ * 4);
    float* part     = (float*)alloc((size_t)B_ * H_ * KL_ * NS_ * 36 * 4);  // 2.4 MB
    __hip_bfloat16* Sg = (__hip_bfloat16*)alloc((size_t)B_ * H_ * KL_ * XL_ * 2);  // 33.5 MB
    // binspart (8.4 MB) aliases xout_pre — dead until attn_x_mfma runs (after bins_argmax)
    float* binspart = xout_pre;

    gemm128<<<dim3(TDIM_ / 128, (B_ * XL_) / 128), 256, 0, stream>>>(
        x, W_qkv, qkv_x, nullptr, B_ * XL_, TDIM_, DIM_);
    gemm64<<<dim3(TDIM_ / 64, (B_ * KL_) / 64), 256, 0, stream>>>(
        kernal, W_qkv, qkv_k, nullptr, B_ * KL_, TDIM_, DIM_);

    score_bins_mfma<<<dim3(NCH_, H_, B_), 256, 0, stream>>>(
        qkv_k, qkv_x, rd, polar_pos, att_mask, dis_embed, Sg, binspart);
    bins_argmax<<<dim3(B_ * H_ * KL_ / 4), 256, 0, stream>>>(binspart, main_ori);
    flash_cached<<<dim3((KL_ / KC_) * NS_, H_, B_), 256, 0, stream>>>(
        qkv_x, Sg, polar_pos, polar_emb, main_ori, part);
    merge_cached<<<dim3(B_ * H_ * KL_ / 8), 256, 0, stream>>>(part, kout_pre);

    attn_x_mfma<<<dim3(XL_ / 64, H_, B_), 256, 0, stream>>>(
        qkv_x, qkv_k, rd, polar_pos, att_mask, dis_embed, polar_emb, main_ori, xout_pre);

    gemm128<<<dim3(DIM_ / 128, (B_ * XL_) / 128), 256, 0, stream>>>(
        xout_pre, W_proj, out, b_proj, B_ * XL_, DIM_, DIM_);
    gemm64<<<dim3(DIM_ / 64, (B_ * KL_) / 64), 256, 0, stream>>>(
        kout_pre, W_proj, out + (size_t)B_ * XL_ * DIM_, b_proj, B_ * KL_, DIM_, DIM_);
}

// Round 13
// 399.877 us; speedup vs baseline: 1.5291x; 1.1387x over previous
//
#include <hip/hip_runtime.h>
#include <hip/hip_bf16.h>

#define B_    4
#define KL_   128
#define XL_   4096
#define DIM_  256
#define H_    8
#define HD_   32
#define PB_   8
#define NDIS_ 66
#define TDIM_ 768
#define SCALE_ 0.17677669529663687f
#define XT_   64
#define KC_   8
#define NS_   4
#define XCH_  (XL_ / NS_)
#define NCH_  64

typedef float v4f __attribute__((ext_vector_type(4)));
typedef short v8s __attribute__((ext_vector_type(8)));

__device__ __forceinline__ unsigned short f2bf(float f) {
    __hip_bfloat16 h = __float2bfloat16(f);
    return __builtin_bit_cast(unsigned short, h);
}
__device__ __forceinline__ float bf2f(unsigned short u) {
    return __bfloat162float(__builtin_bit_cast(__hip_bfloat16, u));
}
__device__ __forceinline__ void cvt_hilo(float v, unsigned short& hi, unsigned short& lo) {
    hi = f2bf(v);
    lo = f2bf(v - bf2f(hi));
}

// ---------------------------------------------------------------------------
// cvt: f32 row-major [M][K] -> hi/lo bf16 row-major
// ---------------------------------------------------------------------------
__global__ __launch_bounds__(256) void cvt_mat(const float* __restrict__ A,
                                               unsigned short* __restrict__ Ah,
                                               unsigned short* __restrict__ Al,
                                               size_t n4) {
    size_t i = ((size_t)blockIdx.x * 256 + threadIdx.x);
    if (i >= n4) return;
    float4 v = *(const float4*)&A[i * 4];
    ushort4 h, l;
    cvt_hilo(v.x, h.x, l.x);
    cvt_hilo(v.y, h.y, l.y);
    cvt_hilo(v.z, h.z, l.z);
    cvt_hilo(v.w, h.w, l.w);
    *(ushort4*)&Ah[i * 4] = h;
    *(ushort4*)&Al[i * 4] = l;
}

// cvt + transpose: W f32 [K][N] -> Wh/Wl bf16 [N][K]
__global__ __launch_bounds__(256) void cvt_wT(const float* __restrict__ W,
                                              unsigned short* __restrict__ Wh,
                                              unsigned short* __restrict__ Wl,
                                              int K, int N) {
    int n = blockIdx.x, k = threadIdx.x;
    float v = W[(size_t)k * N + n];
    unsigned short h, l;
    cvt_hilo(v, h, l);
    Wh[(size_t)n * K + k] = h;
    Wl[(size_t)n * K + k] = l;
}

// ---------------------------------------------------------------------------
// Split-bf16 MFMA GEMM: C[M,N] = A[M,K] @ B[K,N] (+bias), A as hi/lo [M][K],
// B as hi/lo transposed [N][K]. Tile 128x128, 4 waves (2m x 8n 16x16 tiles),
// K-chunk 32. 3-term split: D += Al*Bh + Ah*Bl + Ah*Bh  (~f32 accuracy).
// ---------------------------------------------------------------------------
__global__ __launch_bounds__(256) void gemm_mfma(const unsigned short* __restrict__ Ah,
                                                 const unsigned short* __restrict__ Al,
                                                 const unsigned short* __restrict__ Bh,
                                                 const unsigned short* __restrict__ Bl,
                                                 float* __restrict__ C,
                                                 const float* __restrict__ bias,
                                                 int M, int N, int K) {
    __shared__ __align__(16) unsigned short Ah_s[128][40];
    __shared__ __align__(16) unsigned short Al_s[128][40];
    __shared__ __align__(16) unsigned short Bh_s[128][40];
    __shared__ __align__(16) unsigned short Bl_s[128][40];
    const int tid = threadIdx.x;
    const int w = tid >> 6, lane = tid & 63;
    const int c = lane & 15, q = lane >> 4;
    const int bm = blockIdx.y * 128, bn = blockIdx.x * 128;
    const int srow = tid >> 1, shf = (tid & 1) * 16;

    v4f acc[2][8] = {};
    for (int k0 = 0; k0 < K; k0 += 32) {
        __syncthreads();
        {
            const size_t ab = (size_t)(bm + srow) * K + k0 + shf;
            *(uint4*)&Ah_s[srow][shf] = *(const uint4*)&Ah[ab];
            *(uint4*)&Ah_s[srow][shf + 8] = *(const uint4*)&Ah[ab + 8];
            *(uint4*)&Al_s[srow][shf] = *(const uint4*)&Al[ab];
            *(uint4*)&Al_s[srow][shf + 8] = *(const uint4*)&Al[ab + 8];
            const size_t bb = (size_t)(bn + srow) * K + k0 + shf;
            *(uint4*)&Bh_s[srow][shf] = *(const uint4*)&Bh[bb];
            *(uint4*)&Bh_s[srow][shf + 8] = *(const uint4*)&Bh[bb + 8];
            *(uint4*)&Bl_s[srow][shf] = *(const uint4*)&Bl[bb];
            *(uint4*)&Bl_s[srow][shf + 8] = *(const uint4*)&Bl[bb + 8];
        }
        __syncthreads();
        v8s afh[2], afl[2];
#pragma unroll
        for (int mt = 0; mt < 2; ++mt) {
            afh[mt] = *(v8s*)&Ah_s[w * 32 + mt * 16 + c][q * 8];
            afl[mt] = *(v8s*)&Al_s[w * 32 + mt * 16 + c][q * 8];
        }
#pragma unroll
        for (int nt = 0; nt < 8; ++nt) {
            v8s bfh = *(v8s*)&Bh_s[nt * 16 + c][q * 8];
            v8s bfl = *(v8s*)&Bl_s[nt * 16 + c][q * 8];
#pragma unroll
            for (int mt = 0; mt < 2; ++mt) {
                acc[mt][nt] = __builtin_amdgcn_mfma_f32_16x16x32_bf16(afl[mt], bfh, acc[mt][nt], 0, 0, 0);
                acc[mt][nt] = __builtin_amdgcn_mfma_f32_16x16x32_bf16(afh[mt], bfl, acc[mt][nt], 0, 0, 0);
                acc[mt][nt] = __builtin_amdgcn_mfma_f32_16x16x32_bf16(afh[mt], bfh, acc[mt][nt], 0, 0, 0);
            }
        }
    }
#pragma unroll
    for (int mt = 0; mt < 2; ++mt) {
#pragma unroll
        for (int nt = 0; nt < 8; ++nt) {
            int col = bn + nt * 16 + c;
            float bv = bias ? bias[col] : 0.0f;
#pragma unroll
            for (int r = 0; r < 4; ++r) {
                int row = bm + w * 32 + mt * 16 + q * 4 + r;
                C[(size_t)row * N + col] = acc[mt][nt][r] + bv;
            }
        }
    }
}

// ---------------------------------------------------------------------------
// 64x64 f32 GEMM (small-M: kernal qkv + kout proj)
// ---------------------------------------------------------------------------
__global__ __launch_bounds__(256) void gemm64(const float* __restrict__ A,
                                              const float* __restrict__ Bw,
                                              float* __restrict__ C,
                                              const float* __restrict__ bias,
                                              int M, int N, int K) {
    __shared__ __align__(16) float As[16][68];
    __shared__ __align__(16) float Bs[16][64];
    const int tid = threadIdx.x;
    const int tx = tid & 15, ty = tid >> 4;
    const int bn = blockIdx.x * 64, bm = blockIdx.y * 64;
    const int am = tid >> 2, ac = tid & 3;
    float acc[4][4] = {};
    for (int k0 = 0; k0 < K; k0 += 16) {
        float4 a4 = *(const float4*)&A[(size_t)(bm + am) * K + k0 + ac * 4];
        As[ac * 4 + 0][am] = a4.x;
        As[ac * 4 + 1][am] = a4.y;
        As[ac * 4 + 2][am] = a4.z;
        As[ac * 4 + 3][am] = a4.w;
        *(float4*)&Bs[ty][tx * 4] = *(const float4*)&Bw[(size_t)(k0 + ty) * N + bn + tx * 4];
        __syncthreads();
#pragma unroll
        for (int kk = 0; kk < 16; ++kk) {
            float4 av = *(const float4*)&As[kk][ty * 4];
            float4 bv = *(const float4*)&Bs[kk][tx * 4];
            float a[4] = {av.x, av.y, av.z, av.w};
            float b[4] = {bv.x, bv.y, bv.z, bv.w};
#pragma unroll
            for (int i = 0; i < 4; ++i)
#pragma unroll
                for (int j = 0; j < 4; ++j) acc[i][j] += a[i] * b[j];
        }
        __syncthreads();
    }
#pragma unroll
    for (int i = 0; i < 4; ++i) {
        int m = bm + ty * 4 + i;
#pragma unroll
        for (int j = 0; j < 4; ++j) {
            int n = bn + tx * 4 + j;
            float v = acc[i][j];
            if (bias) v += bias[n];
            C[(size_t)m * N + n] = v;
        }
    }
}

// ===========================================================================
// K1: score_bins_mfma (unchanged from R12)
// ===========================================================================
__global__ __launch_bounds__(256) void score_bins_mfma(const float* __restrict__ qkv_k,
                                                       const float* __restrict__ qkv_x,
                                                       const int* __restrict__ rd,
                                                       const int* __restrict__ polar_pos,
                                                       const int* __restrict__ att_mask,
                                                       const float* __restrict__ dis_embed,
                                                       __hip_bfloat16* __restrict__ Sg,
                                                       float* __restrict__ binspart) {
    const int b = blockIdx.z, h = blockIdx.y, xc = blockIdx.x;
    const int x0 = xc * 64;
    const int tid = threadIdx.x;
    const int w = tid >> 6, lane = tid & 63;
    const int c15 = lane & 15, q = lane >> 4;
    const size_t bh = (size_t)(b * H_ + h);

    __shared__ __align__(16) unsigned short Kxh[64][40];
    __shared__ __align__(16) unsigned short Kxl[64][40];
    __shared__ __align__(16) unsigned short Kqh[KL_][40];
    __shared__ __align__(16) unsigned short Kql[KL_][40];
    __shared__ __align__(16) unsigned short combo[KL_][68];
    __shared__ float binsW[4][16][PB_];
    __shared__ float de_h[NDIS_];

    if (tid < NDIS_) de_h[tid] = dis_embed[tid * H_ + h];

    {
        int row = tid >> 2, dg = (tid & 3) * 8;
        const float* src = &qkv_x[((size_t)b * XL_ + x0 + row) * TDIM_ + DIM_ + h * HD_ + dg];
        float4 v0 = *(const float4*)&src[0];
        float4 v1 = *(const float4*)&src[4];
        float vv[8] = {v0.x, v0.y, v0.z, v0.w, v1.x, v1.y, v1.z, v1.w};
        unsigned short hi[8], lo[8];
#pragma unroll
        for (int j = 0; j < 8; ++j) cvt_hilo(vv[j], hi[j], lo[j]);
        *(ushort4*)&Kxh[row][dg] = *(ushort4*)&hi[0];
        *(ushort4*)&Kxh[row][dg + 4] = *(ushort4*)&hi[4];
        *(ushort4*)&Kxl[row][dg] = *(ushort4*)&lo[0];
        *(ushort4*)&Kxl[row][dg + 4] = *(ushort4*)&lo[4];
    }
    {
        int k = tid >> 1, dg = (tid & 1) * 16;
        const float* src = &qkv_k[((size_t)(b * KL_ + k)) * TDIM_ + h * HD_ + dg];
        unsigned short hi[16], lo[16];
#pragma unroll
        for (int j4 = 0; j4 < 4; ++j4) {
            float4 v = *(const float4*)&src[j4 * 4];
            cvt_hilo(v.x, hi[j4 * 4 + 0], lo[j4 * 4 + 0]);
            cvt_hilo(v.y, hi[j4 * 4 + 1], lo[j4 * 4 + 1]);
            cvt_hilo(v.z, hi[j4 * 4 + 2], lo[j4 * 4 + 2]);
            cvt_hilo(v.w, hi[j4 * 4 + 3], lo[j4 * 4 + 3]);
        }
#pragma unroll
        for (int j4 = 0; j4 < 4; ++j4) {
            *(ushort4*)&Kqh[k][dg + j4 * 4] = *(ushort4*)&hi[j4 * 4];
            *(ushort4*)&Kql[k][dg + j4 * 4] = *(ushort4*)&lo[j4 * 4];
        }
    }
    {
        int k = tid >> 1, xh = (tid & 1) * 32;
        size_t gb = ((size_t)(b * KL_ + k)) * XL_ + x0 + xh;
#pragma unroll
        for (int i = 0; i < 8; ++i) {
            int4 r4 = *(const int4*)&rd[gb + i * 4];
            int4 p4 = *(const int4*)&polar_pos[gb + i * 4];
            ushort4 cv;
            cv.x = (unsigned short)(r4.x | (p4.x << 8));
            cv.y = (unsigned short)(r4.y | (p4.y << 8));
            cv.z = (unsigned short)(r4.z | (p4.z << 8));
            cv.w = (unsigned short)(r4.w | (p4.w << 8));
            *(ushort4*)&combo[k][xh + i * 4] = cv;
        }
    }
    __syncthreads();
    {
        int xr = tid >> 2, kc = (tid & 3) * 32;
        size_t gb = (bh * XL_ + x0 + xr) * KL_ + kc;
#pragma unroll
        for (int i = 0; i < 8; ++i) {
            int4 m4 = *(const int4*)&att_mask[gb + i * 4];
            if (m4.x) combo[kc + i * 4 + 0][xr] |= 0x8000;
            if (m4.y) combo[kc + i * 4 + 1][xr] |= 0x8000;
            if (m4.z) combo[kc + i * 4 + 2][xr] |= 0x8000;
            if (m4.w) combo[kc + i * 4 + 3][xr] |= 0x8000;
        }
    }
    __syncthreads();

    v8s axh = *(v8s*)&Kxh[w * 16 + c15][q * 8];
    v8s axl = *(v8s*)&Kxl[w * 16 + c15][q * 8];

    for (int nt = 0; nt < 8; ++nt) {
        v8s bqh = *(v8s*)&Kqh[nt * 16 + c15][q * 8];
        v8s bql = *(v8s*)&Kql[nt * 16 + c15][q * 8];
        v4f D = {0.f, 0.f, 0.f, 0.f};
        D = __builtin_amdgcn_mfma_f32_16x16x32_bf16(axl, bqh, D, 0, 0, 0);
        D = __builtin_amdgcn_mfma_f32_16x16x32_bf16(axh, bql, D, 0, 0, 0);
        D = __builtin_amdgcn_mfma_f32_16x16x32_bf16(axh, bqh, D, 0, 0, 0);

        const int k = nt * 16 + c15;
        const size_t row_k = bh * KL_ + k;
        float bins[PB_] = {};
        ushort4 pack;
#pragma unroll
        for (int r = 0; r < 4; ++r) {
            int xl_ = w * 16 + q * 4 + r;
            float s = D[r] * SCALE_;
            unsigned cb = combo[k][xl_];
            float a = fabsf(s);
            int pp = (cb >> 8) & 7;
#pragma unroll
            for (int pb = 0; pb < PB_; ++pb) bins[pb] += (pp == pb) ? a : 0.0f;
            float sp = ((cb & 0x8000) ? -1e6f : s) + de_h[cb & 0x7f];
            ((unsigned short*)&pack)[r] = f2bf(sp);
        }
        *(ushort4*)((unsigned short*)Sg + row_k * XL_ + x0 + w * 16 + q * 4) = pack;

#pragma unroll
        for (int pb = 0; pb < PB_; ++pb) {
            bins[pb] += __shfl_xor(bins[pb], 16);
            bins[pb] += __shfl_xor(bins[pb], 32);
        }
        if (q == 0) {
#pragma unroll
            for (int pb = 0; pb < PB_; ++pb) binsW[w][c15][pb] = bins[pb];
        }
        __syncthreads();
        if (tid < 128) {
            int k16 = tid >> 3, pb = tid & 7;
            float v = binsW[0][k16][pb] + binsW[1][k16][pb] + binsW[2][k16][pb] + binsW[3][k16][pb];
            binspart[(bh * KL_ + nt * 16 + k16) * (NCH_ * PB_) + xc * PB_ + pb] = v;
        }
        __syncthreads();
    }
}

// K2: argmax
__global__ __launch_bounds__(256) void bins_argmax(const float* __restrict__ binspart,
                                                   int* __restrict__ main_ori) {
    const int w = threadIdx.x >> 6, lane = threadIdx.x & 63;
    const int row = blockIdx.x * 4 + w;
    const float* bp = &binspart[(size_t)row * (NCH_ * PB_) + lane * PB_];
    float s[PB_];
#pragma unroll
    for (int pb = 0; pb < PB_; ++pb) s[pb] = bp[pb];
#pragma unroll
    for (int m = 1; m < 64; m <<= 1)
#pragma unroll
        for (int pb = 0; pb < PB_; ++pb) s[pb] += __shfl_xor(s[pb], m);
    if (lane == 0) {
        float best = s[0];
        int bi = 0;
#pragma unroll
        for (int pb = 1; pb < PB_; ++pb)
            if (s[pb] > best) { best = s[pb]; bi = pb; }
        main_ori[row] = bi;
    }
}

// K3: flash_cached (unchanged)
__global__ __launch_bounds__(256) void flash_cached(const float* __restrict__ qkv_x,
                                                    const __hip_bfloat16* __restrict__ Sg,
                                                    const int* __restrict__ polar_pos,
                                                    const float* __restrict__ polar_emb,
                                                    const int* __restrict__ main_ori,
                                                    float* __restrict__ part) {
    const int b = blockIdx.z, h = blockIdx.y;
    const int kch = blockIdx.x / NS_, xc = blockIdx.x % NS_;
    const int k0 = kch * KC_;
    const int tid = threadIdx.x;
    const int ki = tid >> 5, xt = tid & 31;

    __shared__ __align__(16) float4 vs[XT_][9];
    __shared__ int pol_s[KC_][68];
    __shared__ float pe[PB_];

    if (tid < PB_) pe[tid] = polar_emb[tid];
    const size_t xbase = (size_t)b * XL_;
    const size_t bh = (size_t)(b * H_ + h);
    const size_t row_k = bh * KL_ + k0 + ki;
    const int mo = main_ori[row_k];
    const int xbeg = xc * XCH_;

    float l = 0.f;
    float4 acc[8] = {};
    __syncthreads();
    for (int t = 0; t < XCH_ / XT_; ++t) {
        const int x0 = xbeg + t * XT_;
        __syncthreads();
#pragma unroll
        for (int i = 0; i < 2; ++i) {
            int id = tid + 256 * i;
            int row = id >> 3, c = id & 7;
            vs[row][c] = *(const float4*)&qkv_x[(xbase + x0 + row) * TDIM_ + 2 * DIM_ + h * HD_ + c * 4];
        }
        if (tid < 128) {
            int kk = tid >> 4, c = tid & 15;
            *(int4*)&pol_s[kk][c * 4] =
                *(const int4*)&polar_pos[(size_t)(b * KL_ + k0 + kk) * XL_ + x0 + c * 4];
        }
        __syncthreads();
#pragma unroll
        for (int j = 0; j < 2; ++j) {
            int xl = xt + 32 * j;
            int x = x0 + xl;
            float sp = __bfloat162float(Sg[row_k * XL_ + x]);
            int pp = pol_s[ki][xl];
            int np = pp - mo;
            np += (np >> 31) & PB_;
            float p = __expf(sp + pe[np]);
            l += p;
#pragma unroll
            for (int c = 0; c < 8; ++c) {
                float4 v = vs[xl][c];
                acc[c].x += p * v.x; acc[c].y += p * v.y;
                acc[c].z += p * v.z; acc[c].w += p * v.w;
            }
        }
    }
#pragma unroll
    for (int m = 1; m < 32; m <<= 1) {
        l += __shfl_xor(l, m);
#pragma unroll
        for (int c = 0; c < 8; ++c) {
            acc[c].x += __shfl_xor(acc[c].x, m);
            acc[c].y += __shfl_xor(acc[c].y, m);
            acc[c].z += __shfl_xor(acc[c].z, m);
            acc[c].w += __shfl_xor(acc[c].w, m);
        }
    }
    if (xt == 0) {
        float* dst = &part[(size_t)(row_k * NS_ + xc) * 36];
#pragma unroll
        for (int c = 0; c < 8; ++c) *(float4*)&dst[c * 4] = acc[c];
        dst[32] = l;
    }
}

// K4: merge
__global__ __launch_bounds__(256) void merge_cached(const float* __restrict__ part,
                                                    float* __restrict__ kout_pre) {
    const int tid = threadIdx.x;
    const int ri = tid >> 5, d = tid & 31;
    const int row = blockIdx.x * 8 + ri;
    float l = 0.f, a = 0.f;
#pragma unroll
    for (int c = 0; c < NS_; ++c) {
        const float* p = &part[(size_t)(row * NS_ + c) * 36];
        l += p[32];
        a += p[d];
    }
    int k = row & (KL_ - 1);
    int bh = row >> 7;
    int h = bh & (H_ - 1), b = bh >> 3;
    kout_pre[(size_t)(b * KL_ + k) * DIM_ + h * HD_ + d] = a / l;
}

// ===========================================================================
// attn_x_mfma (unchanged from R11)
// ===========================================================================
__global__ __launch_bounds__(256) void attn_x_mfma(const float* __restrict__ qkv_x,
                                                   const float* __restrict__ qkv_k,
                                                   const int* __restrict__ rd,
                                                   const int* __restrict__ polar_pos,
                                                   const int* __restrict__ att_mask,
                                                   const float* __restrict__ dis_embed,
                                                   const float* __restrict__ polar_emb,
                                                   const int* __restrict__ main_ori,
                                                   float* __restrict__ xout_pre) {
    const int b = blockIdx.z, h = blockIdx.y;
    const int x0 = blockIdx.x * 64;
    const int tid = threadIdx.x;
    const int wave = tid >> 6, lane = tid & 63;
    const int c = lane & 15, q = lane >> 4;

    __shared__ __align__(16) unsigned short Kk_s[KL_][40];
    __shared__ __align__(16) unsigned short VT_s[HD_][136];
    __shared__ __align__(16) unsigned short P_s[4][16][136];
    __shared__ unsigned short rp_s[KL_][72];
    __shared__ float de_h[NDIS_];
    __shared__ float pe[PB_];
    __shared__ int mo_s[KL_];

    const size_t bh = (size_t)(b * H_ + h);
    if (tid < NDIS_) de_h[tid] = dis_embed[tid * H_ + h];
    if (tid < PB_) pe[tid] = polar_emb[tid];
    if (tid < KL_) mo_s[tid] = main_ori[bh * KL_ + tid];

    {
        int row = tid >> 1, half = tid & 1;
        const float* src = &qkv_k[(size_t)(b * KL_ + row) * TDIM_ + h * HD_ + half * 16];
#pragma unroll
        for (int j = 0; j < 16; ++j) Kk_s[row][half * 16 + j] = f2bf(src[DIM_ + j]);
#pragma unroll
        for (int j = 0; j < 16; ++j) VT_s[half * 16 + j][row] = f2bf(src[2 * DIM_ + j]);
    }
    __syncthreads();

#pragma unroll
    for (int i = 0; i < 8; ++i) {
        int id = tid + 256 * i;
        int k = id >> 4, cc = id & 15;
        size_t gb = (size_t)(b * KL_ + k) * XL_ + x0 + cc * 4;
        int4 r4 = *(const int4*)&rd[gb];
        int4 p4 = *(const int4*)&polar_pos[gb];
        int mo = mo_s[k];
        int n0 = p4.x - mo; n0 += (n0 >> 31) & PB_;
        int n1 = p4.y - mo; n1 += (n1 >> 31) & PB_;
        int n2 = p4.z - mo; n2 += (n2 >> 31) & PB_;
        int n3 = p4.w - mo; n3 += (n3 >> 31) & PB_;
        rp_s[k][cc * 4 + 0] = (unsigned short)(r4.x | (n0 << 8));
        rp_s[k][cc * 4 + 1] = (unsigned short)(r4.y | (n1 << 8));
        rp_s[k][cc * 4 + 2] = (unsigned short)(r4.z | (n2 << 8));
        rp_s[k][cc * 4 + 3] = (unsigned short)(r4.w | (n3 << 8));
    }
    __syncthreads();
#pragma unroll
    for (int i = 0; i < 8; ++i) {
        int id = tid + 256 * i;
        int xr = id >> 5, kc = id & 31;
        int4 m4 = *(const int4*)&att_mask[(bh * XL_ + x0 + xr) * KL_ + kc * 4];
        if (m4.x) rp_s[kc * 4 + 0][xr] |= 0x8000;
        if (m4.y) rp_s[kc * 4 + 1][xr] |= 0x8000;
        if (m4.z) rp_s[kc * 4 + 2][xr] |= 0x8000;
        if (m4.w) rp_s[kc * 4 + 3][xr] |= 0x8000;
    }
    __syncthreads();

    v8s aq;
    {
        const float* qp = &qkv_x[(size_t)(b * XL_ + x0 + wave * 16 + c) * TDIM_ + h * HD_ + q * 8];
        float4 q0 = *(const float4*)&qp[0];
        float4 q1 = *(const float4*)&qp[4];
        aq[0] = (short)f2bf(q0.x); aq[1] = (short)f2bf(q0.y);
        aq[2] = (short)f2bf(q0.z); aq[3] = (short)f2bf(q0.w);
        aq[4] = (short)f2bf(q1.x); aq[5] = (short)f2bf(q1.y);
        aq[6] = (short)f2bf(q1.z); aq[7] = (short)f2bf(q1.w);
    }

    v4f S[8];
#pragma unroll
    for (int t = 0; t < 8; ++t) {
        v8s bk = *(v8s*)&Kk_s[t * 16 + c][q * 8];
        S[t] = __builtin_amdgcn_mfma_f32_16x16x32_bf16(aq, bk, (v4f){0.f, 0.f, 0.f, 0.f}, 0, 0, 0);
    }

    const int xloc = wave * 16;
    float lr[4] = {0.f, 0.f, 0.f, 0.f};
#pragma unroll
    for (int t = 0; t < 8; ++t) {
#pragma unroll
        for (int r = 0; r < 4; ++r) {
            int krow = t * 16 + c;
            int xrow = q * 4 + r;
            unsigned short rp = rp_s[krow][xloc + xrow];
            float sval = S[t][r] * SCALE_;
            float tval = ((rp & 0x8000) ? -25.0f : sval) + de_h[rp & 0x7f] + pe[(rp >> 8) & 7];
            float p = __expf(tval);
            unsigned short pb = f2bf(p);
            P_s[wave][xrow][krow] = pb;
            lr[r] += bf2f(pb);
        }
    }
#pragma unroll
    for (int r = 0; r < 4; ++r) {
#pragma unroll
        for (int m = 1; m < 16; m <<= 1) lr[r] += __shfl_xor(lr[r], m);
    }
    __syncthreads();

    v4f O0 = {0.f, 0.f, 0.f, 0.f}, O1 = {0.f, 0.f, 0.f, 0.f};
#pragma unroll
    for (int kc = 0; kc < 4; ++kc) {
        v8s ap = *(v8s*)&P_s[wave][c][kc * 32 + q * 8];
        v8s bv0 = *(v8s*)&VT_s[c][kc * 32 + q * 8];
        v8s bv1 = *(v8s*)&VT_s[16 + c][kc * 32 + q * 8];
        O0 = __builtin_amdgcn_mfma_f32_16x16x32_bf16(ap, bv0, O0, 0, 0, 0);
        O1 = __builtin_amdgcn_mfma_f32_16x16x32_bf16(ap, bv1, O1, 0, 0, 0);
    }

#pragma unroll
    for (int r = 0; r < 4; ++r) {
        int xg = x0 + wave * 16 + q * 4 + r;
        float inv = 1.0f / lr[r];
        float* op = &xout_pre[(size_t)(b * XL_ + xg) * DIM_ + h * HD_];
        op[c] = O0[r] * inv;
        op[16 + c] = O1[r] * inv;
    }
}

// ---------------------------------------------------------------------------
extern "C" void kernel_launch(void* const* d_in, const int* in_sizes, int n_in,
                              void* d_out, int out_size, void* d_ws, size_t ws_size,
                              hipStream_t stream) {
    const float* x         = (const float*)d_in[0];
    const float* kernal    = (const float*)d_in[1];
    const int* rd          = (const int*)d_in[2];
    const int* polar_pos   = (const int*)d_in[3];
    const int* att_mask    = (const int*)d_in[4];
    const float* W_qkv     = (const float*)d_in[5];
    const float* dis_embed = (const float*)d_in[6];
    const float* polar_emb = (const float*)d_in[7];
    const float* W_proj    = (const float*)d_in[8];
    const float* b_proj    = (const float*)d_in[9];
    float* out             = (float*)d_out;

    char* base = (char*)d_ws;
    size_t off = 0;
    auto alloc = [&](size_t bytes) { void* p = base + off; off = (off + bytes + 255) & ~255ULL; return p; };
    float* qkv_x    = (float*)alloc((size_t)B_ * XL_ * TDIM_ * 4);     // 50.3 MB
    float* qkv_k    = (float*)alloc((size_t)B_ * KL_ * TDIM_ * 4);     // 1.6 MB
    float* xout_pre = (float*)alloc((size_t)B_ * XL_ * DIM_ * 4);      // 16.8 MB
    float* kout_pre = (float*)alloc((size_t)B_ * KL_ * DIM_ * 4);      // 0.5 MB
    int* main_ori   = (int*)alloc(B_ * H_ * KL_ * 4);
    float* part     = (float*)alloc((size_t)B_ * H_ * KL_ * NS_ * 36 * 4);  // 2.4 MB
    __hip_bfloat16* Sg = (__hip_bfloat16*)alloc((size_t)B_ * H_ * KL_ * XL_ * 2);  // 33.5 MB
    unsigned short* wph = (unsigned short*)alloc((size_t)DIM_ * DIM_ * 2);  // 0.13 MB (fresh)
    unsigned short* wpl = (unsigned short*)alloc((size_t)DIM_ * DIM_ * 2);  // 0.13 MB (fresh)

    // Aliases into dead regions (timeline-checked):
    float* binspart = xout_pre;                        // dead until attn_x_mfma
    const size_t MX = (size_t)B_ * XL_;                // 16384
    unsigned short* xh = (unsigned short*)Sg;          // Sg written later by score_bins
    unsigned short* xl_ = xh + MX * DIM_;              // 16.8 MB total, fits in 33.5
    unsigned short* wqh = (unsigned short*)part;       // part written later by flash_cached
    unsigned short* wql = wqh + (size_t)TDIM_ * DIM_;  // 0.8 MB total, fits in 2.4
    unsigned short* oh = (unsigned short*)Sg;          // Sg dead after flash_cached
    unsigned short* ol = oh + MX * DIM_;

    // --- operand conversion ---
    cvt_mat<<<dim3((MX * DIM_ / 4 + 255) / 256), 256, 0, stream>>>(x, xh, xl_, MX * DIM_ / 4);
    cvt_wT<<<dim3(TDIM_), DIM_, 0, stream>>>(W_qkv, wqh, wql, DIM_, TDIM_);
    cvt_wT<<<dim3(DIM_), DIM_, 0, stream>>>(W_proj, wph, wpl, DIM_, DIM_);

    // --- qkv projections ---
    gemm_mfma<<<dim3(TDIM_ / 128, MX / 128), 256, 0, stream>>>(
        xh, xl_, wqh, wql, qkv_x, nullptr, MX, TDIM_, DIM_);
    gemm64<<<dim3(TDIM_ / 64, (B_ * KL_) / 64), 256, 0, stream>>>(
        kernal, W_qkv, qkv_k, nullptr, B_ * KL_, TDIM_, DIM_);

    // --- k-direction ---
    score_bins_mfma<<<dim3(NCH_, H_, B_), 256, 0, stream>>>(
        qkv_k, qkv_x, rd, polar_pos, att_mask, dis_embed, Sg, binspart);
    bins_argmax<<<dim3(B_ * H_ * KL_ / 4), 256, 0, stream>>>(binspart, main_ori);
    flash_cached<<<dim3((KL_ / KC_) * NS_, H_, B_), 256, 0, stream>>>(
        qkv_x, Sg, polar_pos, polar_emb, main_ori, part);
    merge_cached<<<dim3(B_ * H_ * KL_ / 8), 256, 0, stream>>>(part, kout_pre);

    // --- x-direction ---
    attn_x_mfma<<<dim3(XL_ / 64, H_, B_), 256, 0, stream>>>(
        qkv_x, qkv_k, rd, polar_pos, att_mask, dis_embed, polar_emb, main_ori, xout_pre);

    // --- output projections ---
    cvt_mat<<<dim3((MX * DIM_ / 4 + 255) / 256), 256, 0, stream>>>(xout_pre, oh, ol, MX * DIM_ / 4);
    gemm_mfma<<<dim3(DIM_ / 128, MX / 128), 256, 0, stream>>>(
        oh, ol, wph, wpl, out, b_proj, MX, DIM_, DIM_);
    gemm64<<<dim3(DIM_ / 64, (B_ * KL_) / 64), 256, 0, stream>>>(
        kout_pre, W_proj, out + (size_t)B_ * XL_ * DIM_, b_proj, B_ * KL_, DIM_, DIM_);
}

// Round 14
// 381.981 us; speedup vs baseline: 1.6007x; 1.0469x over previous
//
#include <hip/hip_runtime.h>
#include <hip/hip_bf16.h>

#define B_    4
#define KL_   128
#define XL_   4096
#define DIM_  256
#define H_    8
#define HD_   32
#define PB_   8
#define NDIS_ 66
#define TDIM_ 768
#define SCALE_ 0.17677669529663687f
#define XT_   64
#define KC_   8
#define NS_   4
#define XCH_  (XL_ / NS_)
#define NCH_  64

typedef float v4f __attribute__((ext_vector_type(4)));
typedef short v8s __attribute__((ext_vector_type(8)));

__device__ __forceinline__ unsigned short f2bf(float f) {
    __hip_bfloat16 h = __float2bfloat16(f);
    return __builtin_bit_cast(unsigned short, h);
}
__device__ __forceinline__ float bf2f(unsigned short u) {
    return __bfloat162float(__builtin_bit_cast(__hip_bfloat16, u));
}
__device__ __forceinline__ void cvt_hilo(float v, unsigned short& hi, unsigned short& lo) {
    hi = f2bf(v);
    lo = f2bf(v - bf2f(hi));
}

// ---------------------------------------------------------------------------
// cvt: f32 row-major -> hi/lo bf16 row-major
// ---------------------------------------------------------------------------
__global__ __launch_bounds__(256) void cvt_mat(const float* __restrict__ A,
                                               unsigned short* __restrict__ Ah,
                                               unsigned short* __restrict__ Al,
                                               size_t n4) {
    size_t i = ((size_t)blockIdx.x * 256 + threadIdx.x);
    if (i >= n4) return;
    float4 v = *(const float4*)&A[i * 4];
    ushort4 h, l;
    cvt_hilo(v.x, h.x, l.x);
    cvt_hilo(v.y, h.y, l.y);
    cvt_hilo(v.z, h.z, l.z);
    cvt_hilo(v.w, h.w, l.w);
    *(ushort4*)&Ah[i * 4] = h;
    *(ushort4*)&Al[i * 4] = l;
}

// cvt + transpose: W f32 [K][N] -> Wh/Wl bf16 [N][K]
__global__ __launch_bounds__(256) void cvt_wT(const float* __restrict__ W,
                                              unsigned short* __restrict__ Wh,
                                              unsigned short* __restrict__ Wl,
                                              int K, int N) {
    int n = blockIdx.x, k = threadIdx.x;
    float v = W[(size_t)k * N + n];
    unsigned short h, l;
    cvt_hilo(v, h, l);
    Wh[(size_t)n * K + k] = h;
    Wl[(size_t)n * K + k] = l;
}

// cvt k_q slice: qkv_k q-part -> Kqg hi/lo [bh][k][32]
__global__ __launch_bounds__(256) void cvt_kq(const float* __restrict__ qkv_k,
                                              unsigned short* __restrict__ Kqh_g,
                                              unsigned short* __restrict__ Kql_g) {
    const int bh = blockIdx.x;
    const int b = bh >> 3, h = bh & 7;
    const int tid = threadIdx.x;
    const int k = tid >> 1, dg = (tid & 1) * 16;
    const float* src = &qkv_k[((size_t)(b * KL_ + k)) * TDIM_ + h * HD_ + dg];
    unsigned short hi[16], lo[16];
#pragma unroll
    for (int j4 = 0; j4 < 4; ++j4) {
        float4 v = *(const float4*)&src[j4 * 4];
        cvt_hilo(v.x, hi[j4 * 4 + 0], lo[j4 * 4 + 0]);
        cvt_hilo(v.y, hi[j4 * 4 + 1], lo[j4 * 4 + 1]);
        cvt_hilo(v.z, hi[j4 * 4 + 2], lo[j4 * 4 + 2]);
        cvt_hilo(v.w, hi[j4 * 4 + 3], lo[j4 * 4 + 3]);
    }
    unsigned short* dh = &Kqh_g[((size_t)bh * KL_ + k) * HD_ + dg];
    unsigned short* dl = &Kql_g[((size_t)bh * KL_ + k) * HD_ + dg];
    *(uint4*)&dh[0] = *(uint4*)&hi[0];
    *(uint4*)&dh[8] = *(uint4*)&hi[8];
    *(uint4*)&dl[0] = *(uint4*)&lo[0];
    *(uint4*)&dl[8] = *(uint4*)&lo[8];
}

// ---------------------------------------------------------------------------
// Split-bf16 MFMA GEMM (unchanged from R13)
// ---------------------------------------------------------------------------
__global__ __launch_bounds__(256) void gemm_mfma(const unsigned short* __restrict__ Ah,
                                                 const unsigned short* __restrict__ Al,
                                                 const unsigned short* __restrict__ Bh,
                                                 const unsigned short* __restrict__ Bl,
                                                 float* __restrict__ C,
                                                 const float* __restrict__ bias,
                                                 int M, int N, int K) {
    __shared__ __align__(16) unsigned short Ah_s[128][40];
    __shared__ __align__(16) unsigned short Al_s[128][40];
    __shared__ __align__(16) unsigned short Bh_s[128][40];
    __shared__ __align__(16) unsigned short Bl_s[128][40];
    const int tid = threadIdx.x;
    const int w = tid >> 6, lane = tid & 63;
    const int c = lane & 15, q = lane >> 4;
    const int bm = blockIdx.y * 128, bn = blockIdx.x * 128;
    const int srow = tid >> 1, shf = (tid & 1) * 16;

    v4f acc[2][8] = {};
    for (int k0 = 0; k0 < K; k0 += 32) {
        __syncthreads();
        {
            const size_t ab = (size_t)(bm + srow) * K + k0 + shf;
            *(uint4*)&Ah_s[srow][shf] = *(const uint4*)&Ah[ab];
            *(uint4*)&Ah_s[srow][shf + 8] = *(const uint4*)&Ah[ab + 8];
            *(uint4*)&Al_s[srow][shf] = *(const uint4*)&Al[ab];
            *(uint4*)&Al_s[srow][shf + 8] = *(const uint4*)&Al[ab + 8];
            const size_t bb = (size_t)(bn + srow) * K + k0 + shf;
            *(uint4*)&Bh_s[srow][shf] = *(const uint4*)&Bh[bb];
            *(uint4*)&Bh_s[srow][shf + 8] = *(const uint4*)&Bh[bb + 8];
            *(uint4*)&Bl_s[srow][shf] = *(const uint4*)&Bl[bb];
            *(uint4*)&Bl_s[srow][shf + 8] = *(const uint4*)&Bl[bb + 8];
        }
        __syncthreads();
        v8s afh[2], afl[2];
#pragma unroll
        for (int mt = 0; mt < 2; ++mt) {
            afh[mt] = *(v8s*)&Ah_s[w * 32 + mt * 16 + c][q * 8];
            afl[mt] = *(v8s*)&Al_s[w * 32 + mt * 16 + c][q * 8];
        }
#pragma unroll
        for (int nt = 0; nt < 8; ++nt) {
            v8s bfh = *(v8s*)&Bh_s[nt * 16 + c][q * 8];
            v8s bfl = *(v8s*)&Bl_s[nt * 16 + c][q * 8];
#pragma unroll
            for (int mt = 0; mt < 2; ++mt) {
                acc[mt][nt] = __builtin_amdgcn_mfma_f32_16x16x32_bf16(afl[mt], bfh, acc[mt][nt], 0, 0, 0);
                acc[mt][nt] = __builtin_amdgcn_mfma_f32_16x16x32_bf16(afh[mt], bfl, acc[mt][nt], 0, 0, 0);
                acc[mt][nt] = __builtin_amdgcn_mfma_f32_16x16x32_bf16(afh[mt], bfh, acc[mt][nt], 0, 0, 0);
            }
        }
    }
#pragma unroll
    for (int mt = 0; mt < 2; ++mt) {
#pragma unroll
        for (int nt = 0; nt < 8; ++nt) {
            int col = bn + nt * 16 + c;
            float bv = bias ? bias[col] : 0.0f;
#pragma unroll
            for (int r = 0; r < 4; ++r) {
                int row = bm + w * 32 + mt * 16 + q * 4 + r;
                C[(size_t)row * N + col] = acc[mt][nt][r] + bv;
            }
        }
    }
}

// ---------------------------------------------------------------------------
// 64x64 f32 GEMM (small-M)
// ---------------------------------------------------------------------------
__global__ __launch_bounds__(256) void gemm64(const float* __restrict__ A,
                                              const float* __restrict__ Bw,
                                              float* __restrict__ C,
                                              const float* __restrict__ bias,
                                              int M, int N, int K) {
    __shared__ __align__(16) float As[16][68];
    __shared__ __align__(16) float Bs[16][64];
    const int tid = threadIdx.x;
    const int tx = tid & 15, ty = tid >> 4;
    const int bn = blockIdx.x * 64, bm = blockIdx.y * 64;
    const int am = tid >> 2, ac = tid & 3;
    float acc[4][4] = {};
    for (int k0 = 0; k0 < K; k0 += 16) {
        float4 a4 = *(const float4*)&A[(size_t)(bm + am) * K + k0 + ac * 4];
        As[ac * 4 + 0][am] = a4.x;
        As[ac * 4 + 1][am] = a4.y;
        As[ac * 4 + 2][am] = a4.z;
        As[ac * 4 + 3][am] = a4.w;
        *(float4*)&Bs[ty][tx * 4] = *(const float4*)&Bw[(size_t)(k0 + ty) * N + bn + tx * 4];
        __syncthreads();
#pragma unroll
        for (int kk = 0; kk < 16; ++kk) {
            float4 av = *(const float4*)&As[kk][ty * 4];
            float4 bv = *(const float4*)&Bs[kk][tx * 4];
            float a[4] = {av.x, av.y, av.z, av.w};
            float b[4] = {bv.x, bv.y, bv.z, bv.w};
#pragma unroll
            for (int i = 0; i < 4; ++i)
#pragma unroll
                for (int j = 0; j < 4; ++j) acc[i][j] += a[i] * b[j];
        }
        __syncthreads();
    }
#pragma unroll
    for (int i = 0; i < 4; ++i) {
        int m = bm + ty * 4 + i;
#pragma unroll
        for (int j = 0; j < 4; ++j) {
            int n = bn + tx * 4 + j;
            float v = acc[i][j];
            if (bias) v += bias[n];
            C[(size_t)m * N + n] = v;
        }
    }
}

// ===========================================================================
// K1 v2: score_bins_mfma2 — barrier-light. Kq preconverted; A-frag in regs;
// rd/pol direct int4; mask bit-tile; wave-private bins slices, 1 end barrier.
// ===========================================================================
__global__ __launch_bounds__(256) void score_bins_mfma2(const float* __restrict__ qkv_x,
                                                        const unsigned short* __restrict__ Kqh_g,
                                                        const unsigned short* __restrict__ Kql_g,
                                                        const int* __restrict__ rd,
                                                        const int* __restrict__ polar_pos,
                                                        const int* __restrict__ att_mask,
                                                        const float* __restrict__ dis_embed,
                                                        __hip_bfloat16* __restrict__ Sg,
                                                        float* __restrict__ binspart) {
    const int b = blockIdx.z, h = blockIdx.y, xc = blockIdx.x;
    const int x0 = xc * 64;
    const int tid = threadIdx.x;
    const int w = tid >> 6, lane = tid & 63;
    const int c15 = lane & 15, q = lane >> 4;
    const size_t bh = (size_t)(b * H_ + h);

    __shared__ __align__(16) unsigned short Kqh_s[KL_][40];
    __shared__ __align__(16) unsigned short Kql_s[KL_][40];
    __shared__ unsigned int mskb[64][5];
    __shared__ float de_h[NDIS_];
    __shared__ float binsL[8][4][16][PB_];

    // stage Kq (preconverted)
    {
        int k = tid >> 1, dg = (tid & 1) * 16;
        const unsigned short* sh = &Kqh_g[(bh * KL_ + k) * HD_ + dg];
        const unsigned short* sl = &Kql_g[(bh * KL_ + k) * HD_ + dg];
        *(uint4*)&Kqh_s[k][dg] = *(const uint4*)&sh[0];
        *(uint4*)&Kqh_s[k][dg + 8] = *(const uint4*)&sh[8];
        *(uint4*)&Kql_s[k][dg] = *(const uint4*)&sl[0];
        *(uint4*)&Kql_s[k][dg + 8] = *(const uint4*)&sl[8];
    }
    // mask -> bit tile
    {
        int xr = tid >> 2, kg = tid & 3;
        size_t gb = (bh * XL_ + x0 + xr) * KL_ + kg * 32;
        unsigned bits = 0;
#pragma unroll
        for (int i = 0; i < 8; ++i) {
            int4 m4 = *(const int4*)&att_mask[gb + i * 4];
            bits |= (m4.x ? 1u : 0u) << (i * 4 + 0);
            bits |= (m4.y ? 1u : 0u) << (i * 4 + 1);
            bits |= (m4.z ? 1u : 0u) << (i * 4 + 2);
            bits |= (m4.w ? 1u : 0u) << (i * 4 + 3);
        }
        mskb[xr][kg] = bits;
    }
    if (tid < NDIS_) de_h[tid] = dis_embed[tid * H_ + h];
    __syncthreads();

    // A-fragment in registers (own x row, hi/lo)
    v8s axh, axl;
    {
        const float* src = &qkv_x[((size_t)b * XL_ + x0 + w * 16 + c15) * TDIM_ + DIM_ + h * HD_ + q * 8];
        float4 v0 = *(const float4*)&src[0];
        float4 v1 = *(const float4*)&src[4];
        float vv[8] = {v0.x, v0.y, v0.z, v0.w, v1.x, v1.y, v1.z, v1.w};
#pragma unroll
        for (int j = 0; j < 8; ++j) {
            unsigned short hi, lo;
            cvt_hilo(vv[j], hi, lo);
            ((short*)&axh)[j] = (short)hi;
            ((short*)&axl)[j] = (short)lo;
        }
    }

    const int xw = x0 + w * 16;

#pragma unroll
    for (int nt = 0; nt < 8; ++nt) {
        const int k = nt * 16 + c15;
        v8s bqh = *(v8s*)&Kqh_s[k][q * 8];
        v8s bql = *(v8s*)&Kql_s[k][q * 8];
        v4f D = {0.f, 0.f, 0.f, 0.f};
        D = __builtin_amdgcn_mfma_f32_16x16x32_bf16(axl, bqh, D, 0, 0, 0);
        D = __builtin_amdgcn_mfma_f32_16x16x32_bf16(axh, bql, D, 0, 0, 0);
        D = __builtin_amdgcn_mfma_f32_16x16x32_bf16(axh, bqh, D, 0, 0, 0);

        const size_t rowoff = ((size_t)(b * KL_ + k)) * XL_ + xw + q * 4;
        int4 r4 = *(const int4*)&rd[rowoff];
        int4 p4 = *(const int4*)&polar_pos[rowoff];
        int rv[4] = {r4.x, r4.y, r4.z, r4.w};
        int pv[4] = {p4.x, p4.y, p4.z, p4.w};

        float bins[PB_] = {};
        ushort4 pack;
#pragma unroll
        for (int r = 0; r < 4; ++r) {
            float s = D[r] * SCALE_;
            float a = fabsf(s);
            int pp = pv[r];
#pragma unroll
            for (int pb = 0; pb < PB_; ++pb) bins[pb] += (pp == pb) ? a : 0.0f;
            int xloc = w * 16 + q * 4 + r;
            int mbit = (mskb[xloc][k >> 5] >> (k & 31)) & 1;
            float sp = (mbit ? -1e6f : s) + de_h[rv[r]];
            ((unsigned short*)&pack)[r] = f2bf(sp);
        }
        *(ushort4*)((unsigned short*)Sg + (bh * KL_ + k) * XL_ + xw + q * 4) = pack;

        // quad reduce (same k across 4 quads) — wave-private flush, no barrier
#pragma unroll
        for (int pb = 0; pb < PB_; ++pb) {
            bins[pb] += __shfl_xor(bins[pb], 16);
            bins[pb] += __shfl_xor(bins[pb], 32);
        }
        if (q == 0) {
#pragma unroll
            for (int pb = 0; pb < PB_; ++pb) binsL[nt][w][c15][pb] = bins[pb];
        }
    }
    __syncthreads();
    // final cross-wave reduce + coalesced write (layout matches bins_argmax)
    {
        int k = tid >> 1, half = tid & 1;
        int nt = k >> 4, c = k & 15;
        float4 s = {0.f, 0.f, 0.f, 0.f};
#pragma unroll
        for (int w4 = 0; w4 < 4; ++w4) {
            float4 v = *(float4*)&binsL[nt][w4][c][half * 4];
            s.x += v.x; s.y += v.y; s.z += v.z; s.w += v.w;
        }
        *(float4*)&binspart[(bh * KL_ + k) * (NCH_ * PB_) + xc * PB_ + half * 4] = s;
    }
}

// K2: argmax
__global__ __launch_bounds__(256) void bins_argmax(const float* __restrict__ binspart,
                                                   int* __restrict__ main_ori) {
    const int w = threadIdx.x >> 6, lane = threadIdx.x & 63;
    const int row = blockIdx.x * 4 + w;
    const float* bp = &binspart[(size_t)row * (NCH_ * PB_) + lane * PB_];
    float s[PB_];
#pragma unroll
    for (int pb = 0; pb < PB_; ++pb) s[pb] = bp[pb];
#pragma unroll
    for (int m = 1; m < 64; m <<= 1)
#pragma unroll
        for (int pb = 0; pb < PB_; ++pb) s[pb] += __shfl_xor(s[pb], m);
    if (lane == 0) {
        float best = s[0];
        int bi = 0;
#pragma unroll
        for (int pb = 1; pb < PB_; ++pb)
            if (s[pb] > best) { best = s[pb]; bi = pb; }
        main_ori[row] = bi;
    }
}

// K3: flash_cached (unchanged)
__global__ __launch_bounds__(256) void flash_cached(const float* __restrict__ qkv_x,
                                                    const __hip_bfloat16* __restrict__ Sg,
                                                    const int* __restrict__ polar_pos,
                                                    const float* __restrict__ polar_emb,
                                                    const int* __restrict__ main_ori,
                                                    float* __restrict__ part) {
    const int b = blockIdx.z, h = blockIdx.y;
    const int kch = blockIdx.x / NS_, xc = blockIdx.x % NS_;
    const int k0 = kch * KC_;
    const int tid = threadIdx.x;
    const int ki = tid >> 5, xt = tid & 31;

    __shared__ __align__(16) float4 vs[XT_][9];
    __shared__ int pol_s[KC_][68];
    __shared__ float pe[PB_];

    if (tid < PB_) pe[tid] = polar_emb[tid];
    const size_t xbase = (size_t)b * XL_;
    const size_t bh = (size_t)(b * H_ + h);
    const size_t row_k = bh * KL_ + k0 + ki;
    const int mo = main_ori[row_k];
    const int xbeg = xc * XCH_;

    float l = 0.f;
    float4 acc[8] = {};
    __syncthreads();
    for (int t = 0; t < XCH_ / XT_; ++t) {
        const int x0 = xbeg + t * XT_;
        __syncthreads();
#pragma unroll
        for (int i = 0; i < 2; ++i) {
            int id = tid + 256 * i;
            int row = id >> 3, c = id & 7;
            vs[row][c] = *(const float4*)&qkv_x[(xbase + x0 + row) * TDIM_ + 2 * DIM_ + h * HD_ + c * 4];
        }
        if (tid < 128) {
            int kk = tid >> 4, c = tid & 15;
            *(int4*)&pol_s[kk][c * 4] =
                *(const int4*)&polar_pos[(size_t)(b * KL_ + k0 + kk) * XL_ + x0 + c * 4];
        }
        __syncthreads();
#pragma unroll
        for (int j = 0; j < 2; ++j) {
            int xl = xt + 32 * j;
            int x = x0 + xl;
            float sp = __bfloat162float(Sg[row_k * XL_ + x]);
            int pp = pol_s[ki][xl];
            int np = pp - mo;
            np += (np >> 31) & PB_;
            float p = __expf(sp + pe[np]);
            l += p;
#pragma unroll
            for (int c = 0; c < 8; ++c) {
                float4 v = vs[xl][c];
                acc[c].x += p * v.x; acc[c].y += p * v.y;
                acc[c].z += p * v.z; acc[c].w += p * v.w;
            }
        }
    }
#pragma unroll
    for (int m = 1; m < 32; m <<= 1) {
        l += __shfl_xor(l, m);
#pragma unroll
        for (int c = 0; c < 8; ++c) {
            acc[c].x += __shfl_xor(acc[c].x, m);
            acc[c].y += __shfl_xor(acc[c].y, m);
            acc[c].z += __shfl_xor(acc[c].z, m);
            acc[c].w += __shfl_xor(acc[c].w, m);
        }
    }
    if (xt == 0) {
        float* dst = &part[(size_t)(row_k * NS_ + xc) * 36];
#pragma unroll
        for (int c = 0; c < 8; ++c) *(float4*)&dst[c * 4] = acc[c];
        dst[32] = l;
    }
}

// K4: merge
__global__ __launch_bounds__(256) void merge_cached(const float* __restrict__ part,
                                                    float* __restrict__ kout_pre) {
    const int tid = threadIdx.x;
    const int ri = tid >> 5, d = tid & 31;
    const int row = blockIdx.x * 8 + ri;
    float l = 0.f, a = 0.f;
#pragma unroll
    for (int c = 0; c < NS_; ++c) {
        const float* p = &part[(size_t)(row * NS_ + c) * 36];
        l += p[32];
        a += p[d];
    }
    int k = row & (KL_ - 1);
    int bh = row >> 7;
    int h = bh & (H_ - 1), b = bh >> 3;
    kout_pre[(size_t)(b * KL_ + k) * DIM_ + h * HD_ + d] = a / l;
}

// ===========================================================================
// attn_x_mfma (unchanged)
// ===========================================================================
__global__ __launch_bounds__(256) void attn_x_mfma(const float* __restrict__ qkv_x,
                                                   const float* __restrict__ qkv_k,
                                                   const int* __restrict__ rd,
                                                   const int* __restrict__ polar_pos,
                                                   const int* __restrict__ att_mask,
                                                   const float* __restrict__ dis_embed,
                                                   const float* __restrict__ polar_emb,
                                                   const int* __restrict__ main_ori,
                                                   float* __restrict__ xout_pre) {
    const int b = blockIdx.z, h = blockIdx.y;
    const int x0 = blockIdx.x * 64;
    const int tid = threadIdx.x;
    const int wave = tid >> 6, lane = tid & 63;
    const int c = lane & 15, q = lane >> 4;

    __shared__ __align__(16) unsigned short Kk_s[KL_][40];
    __shared__ __align__(16) unsigned short VT_s[HD_][136];
    __shared__ __align__(16) unsigned short P_s[4][16][136];
    __shared__ unsigned short rp_s[KL_][72];
    __shared__ float de_h[NDIS_];
    __shared__ float pe[PB_];
    __shared__ int mo_s[KL_];

    const size_t bh = (size_t)(b * H_ + h);
    if (tid < NDIS_) de_h[tid] = dis_embed[tid * H_ + h];
    if (tid < PB_) pe[tid] = polar_emb[tid];
    if (tid < KL_) mo_s[tid] = main_ori[bh * KL_ + tid];

    {
        int row = tid >> 1, half = tid & 1;
        const float* src = &qkv_k[(size_t)(b * KL_ + row) * TDIM_ + h * HD_ + half * 16];
#pragma unroll
        for (int j = 0; j < 16; ++j) Kk_s[row][half * 16 + j] = f2bf(src[DIM_ + j]);
#pragma unroll
        for (int j = 0; j < 16; ++j) VT_s[half * 16 + j][row] = f2bf(src[2 * DIM_ + j]);
    }
    __syncthreads();

#pragma unroll
    for (int i = 0; i < 8; ++i) {
        int id = tid + 256 * i;
        int k = id >> 4, cc = id & 15;
        size_t gb = (size_t)(b * KL_ + k) * XL_ + x0 + cc * 4;
        int4 r4 = *(const int4*)&rd[gb];
        int4 p4 = *(const int4*)&polar_pos[gb];
        int mo = mo_s[k];
        int n0 = p4.x - mo; n0 += (n0 >> 31) & PB_;
        int n1 = p4.y - mo; n1 += (n1 >> 31) & PB_;
        int n2 = p4.z - mo; n2 += (n2 >> 31) & PB_;
        int n3 = p4.w - mo; n3 += (n3 >> 31) & PB_;
        rp_s[k][cc * 4 + 0] = (unsigned short)(r4.x | (n0 << 8));
        rp_s[k][cc * 4 + 1] = (unsigned short)(r4.y | (n1 << 8));
        rp_s[k][cc * 4 + 2] = (unsigned short)(r4.z | (n2 << 8));
        rp_s[k][cc * 4 + 3] = (unsigned short)(r4.w | (n3 << 8));
    }
    __syncthreads();
#pragma unroll
    for (int i = 0; i < 8; ++i) {
        int id = tid + 256 * i;
        int xr = id >> 5, kc = id & 31;
        int4 m4 = *(const int4*)&att_mask[(bh * XL_ + x0 + xr) * KL_ + kc * 4];
        if (m4.x) rp_s[kc * 4 + 0][xr] |= 0x8000;
        if (m4.y) rp_s[kc * 4 + 1][xr] |= 0x8000;
        if (m4.z) rp_s[kc * 4 + 2][xr] |= 0x8000;
        if (m4.w) rp_s[kc * 4 + 3][xr] |= 0x8000;
    }
    __syncthreads();

    v8s aq;
    {
        const float* qp = &qkv_x[(size_t)(b * XL_ + x0 + wave * 16 + c) * TDIM_ + h * HD_ + q * 8];
        float4 q0 = *(const float4*)&qp[0];
        float4 q1 = *(const float4*)&qp[4];
        aq[0] = (short)f2bf(q0.x); aq[1] = (short)f2bf(q0.y);
        aq[2] = (short)f2bf(q0.z); aq[3] = (short)f2bf(q0.w);
        aq[4] = (short)f2bf(q1.x); aq[5] = (short)f2bf(q1.y);
        aq[6] = (short)f2bf(q1.z); aq[7] = (short)f2bf(q1.w);
    }

    v4f S[8];
#pragma unroll
    for (int t = 0; t < 8; ++t) {
        v8s bk = *(v8s*)&Kk_s[t * 16 + c][q * 8];
        S[t] = __builtin_amdgcn_mfma_f32_16x16x32_bf16(aq, bk, (v4f){0.f, 0.f, 0.f, 0.f}, 0, 0, 0);
    }

    const int xloc = wave * 16;
    float lr[4] = {0.f, 0.f, 0.f, 0.f};
#pragma unroll
    for (int t = 0; t < 8; ++t) {
#pragma unroll
        for (int r = 0; r < 4; ++r) {
            int krow = t * 16 + c;
            int xrow = q * 4 + r;
            unsigned short rp = rp_s[krow][xloc + xrow];
            float sval = S[t][r] * SCALE_;
            float tval = ((rp & 0x8000) ? -25.0f : sval) + de_h[rp & 0x7f] + pe[(rp >> 8) & 7];
            float p = __expf(tval);
            unsigned short pb = f2bf(p);
            P_s[wave][xrow][krow] = pb;
            lr[r] += bf2f(pb);
        }
    }
#pragma unroll
    for (int r = 0; r < 4; ++r) {
#pragma unroll
        for (int m = 1; m < 16; m <<= 1) lr[r] += __shfl_xor(lr[r], m);
    }
    __syncthreads();

    v4f O0 = {0.f, 0.f, 0.f, 0.f}, O1 = {0.f, 0.f, 0.f, 0.f};
#pragma unroll
    for (int kc = 0; kc < 4; ++kc) {
        v8s ap = *(v8s*)&P_s[wave][c][kc * 32 + q * 8];
        v8s bv0 = *(v8s*)&VT_s[c][kc * 32 + q * 8];
        v8s bv1 = *(v8s*)&VT_s[16 + c][kc * 32 + q * 8];
        O0 = __builtin_amdgcn_mfma_f32_16x16x32_bf16(ap, bv0, O0, 0, 0, 0);
        O1 = __builtin_amdgcn_mfma_f32_16x16x32_bf16(ap, bv1, O1, 0, 0, 0);
    }

#pragma unroll
    for (int r = 0; r < 4; ++r) {
        int xg = x0 + wave * 16 + q * 4 + r;
        float inv = 1.0f / lr[r];
        float* op = &xout_pre[(size_t)(b * XL_ + xg) * DIM_ + h * HD_];
        op[c] = O0[r] * inv;
        op[16 + c] = O1[r] * inv;
    }
}

// ---------------------------------------------------------------------------
extern "C" void kernel_launch(void* const* d_in, const int* in_sizes, int n_in,
                              void* d_out, int out_size, void* d_ws, size_t ws_size,
                              hipStream_t stream) {
    const float* x         = (const float*)d_in[0];
    const float* kernal    = (const float*)d_in[1];
    const int* rd          = (const int*)d_in[2];
    const int* polar_pos   = (const int*)d_in[3];
    const int* att_mask    = (const int*)d_in[4];
    const float* W_qkv     = (const float*)d_in[5];
    const float* dis_embed = (const float*)d_in[6];
    const float* polar_emb = (const float*)d_in[7];
    const float* W_proj    = (const float*)d_in[8];
    const float* b_proj    = (const float*)d_in[9];
    float* out             = (float*)d_out;

    char* base = (char*)d_ws;
    size_t off = 0;
    auto alloc = [&](size_t bytes) { void* p = base + off; off = (off + bytes + 255) & ~255ULL; return p; };
    float* qkv_x    = (float*)alloc((size_t)B_ * XL_ * TDIM_ * 4);
    float* qkv_k    = (float*)alloc((size_t)B_ * KL_ * TDIM_ * 4);
    float* xout_pre = (float*)alloc((size_t)B_ * XL_ * DIM_ * 4);
    float* kout_pre = (float*)alloc((size_t)B_ * KL_ * DIM_ * 4);
    int* main_ori   = (int*)alloc(B_ * H_ * KL_ * 4);
    float* part     = (float*)alloc((size_t)B_ * H_ * KL_ * NS_ * 36 * 4);  // 2.36 MB
    __hip_bfloat16* Sg = (__hip_bfloat16*)alloc((size_t)B_ * H_ * KL_ * XL_ * 2);
    unsigned short* wph = (unsigned short*)alloc((size_t)DIM_ * DIM_ * 2);
    unsigned short* wpl = (unsigned short*)alloc((size_t)DIM_ * DIM_ * 2);

    // Aliases into dead regions (timeline-checked):
    float* binspart = xout_pre;                        // dead until attn_x_mfma
    const size_t MX = (size_t)B_ * XL_;
    unsigned short* xh = (unsigned short*)Sg;          // Sg written later by score_bins
    unsigned short* xl_ = xh + MX * DIM_;
    unsigned short* wqh = (unsigned short*)part;       // part written later by flash_cached
    unsigned short* wql = wqh + (size_t)TDIM_ * DIM_;
    unsigned short* kqh_g = wqh + 2 * (size_t)TDIM_ * DIM_;   // after wq (0.79 MB), 0.52 MB
    unsigned short* kql_g = kqh_g + (size_t)B_ * H_ * KL_ * HD_;
    unsigned short* oh = (unsigned short*)Sg;          // Sg dead after flash_cached
    unsigned short* ol = oh + MX * DIM_;

    // --- operand conversion ---
    cvt_mat<<<dim3((MX * DIM_ / 4 + 255) / 256), 256, 0, stream>>>(x, xh, xl_, MX * DIM_ / 4);
    cvt_wT<<<dim3(TDIM_), DIM_, 0, stream>>>(W_qkv, wqh, wql, DIM_, TDIM_);
    cvt_wT<<<dim3(DIM_), DIM_, 0, stream>>>(W_proj, wph, wpl, DIM_, DIM_);

    // --- qkv projections ---
    gemm_mfma<<<dim3(TDIM_ / 128, MX / 128), 256, 0, stream>>>(
        xh, xl_, wqh, wql, qkv_x, nullptr, MX, TDIM_, DIM_);
    gemm64<<<dim3(TDIM_ / 64, (B_ * KL_) / 64), 256, 0, stream>>>(
        kernal, W_qkv, qkv_k, nullptr, B_ * KL_, TDIM_, DIM_);
    cvt_kq<<<dim3(B_ * H_), 256, 0, stream>>>(qkv_k, kqh_g, kql_g);

    // --- k-direction ---
    score_bins_mfma2<<<dim3(NCH_, H_, B_), 256, 0, stream>>>(
        qkv_x, kqh_g, kql_g, rd, polar_pos, att_mask, dis_embed, Sg, binspart);
    bins_argmax<<<dim3(B_ * H_ * KL_ / 4), 256, 0, stream>>>(binspart, main_ori);
    flash_cached<<<dim3((KL_ / KC_) * NS_, H_, B_), 256, 0, stream>>>(
        qkv_x, Sg, polar_pos, polar_emb, main_ori, part);
    merge_cached<<<dim3(B_ * H_ * KL_ / 8), 256, 0, stream>>>(part, kout_pre);

    // --- x-direction ---
    attn_x_mfma<<<dim3(XL_ / 64, H_, B_), 256, 0, stream>>>(
        qkv_x, qkv_k, rd, polar_pos, att_mask, dis_embed, polar_emb, main_ori, xout_pre);

    // --- output projections ---
    cvt_mat<<<dim3((MX * DIM_ / 4 + 255) / 256), 256, 0, stream>>>(xout_pre, oh, ol, MX * DIM_ / 4);
    gemm_mfma<<<dim3(DIM_ / 128, MX / 128), 256, 0, stream>>>(
        oh, ol, wph, wpl, out, b_proj, MX, DIM_, DIM_);
    gemm64<<<dim3(DIM_ / 64, (B_ * KL_) / 64), 256, 0, stream>>>(
        kout_pre, W_proj, out + (size_t)B_ * XL_ * DIM_, b_proj, B_ * KL_, DIM_, DIM_);
}

// Round 15
// 362.672 us; speedup vs baseline: 1.6860x; 1.0532x over previous
//
#include <hip/hip_runtime.h>
#include <hip/hip_bf16.h>

#define B_    4
#define KL_   128
#define XL_   4096
#define DIM_  256
#define H_    8
#define HD_   32
#define PB_   8
#define NDIS_ 66
#define TDIM_ 768
#define SCALE_ 0.17677669529663687f
#define NS_   4
#define XCH_  (XL_ / NS_)
#define NCH_  64
#define KC2_  16

typedef float v4f __attribute__((ext_vector_type(4)));
typedef short v8s __attribute__((ext_vector_type(8)));

__device__ __forceinline__ unsigned short f2bf(float f) {
    __hip_bfloat16 h = __float2bfloat16(f);
    return __builtin_bit_cast(unsigned short, h);
}
__device__ __forceinline__ float bf2f(unsigned short u) {
    return __bfloat162float(__builtin_bit_cast(__hip_bfloat16, u));
}
__device__ __forceinline__ void cvt_hilo(float v, unsigned short& hi, unsigned short& lo) {
    hi = f2bf(v);
    lo = f2bf(v - bf2f(hi));
}

// ---------------------------------------------------------------------------
// cvt: f32 row-major -> hi/lo bf16 row-major
// ---------------------------------------------------------------------------
__global__ __launch_bounds__(256) void cvt_mat(const float* __restrict__ A,
                                               unsigned short* __restrict__ Ah,
                                               unsigned short* __restrict__ Al,
                                               size_t n4) {
    size_t i = ((size_t)blockIdx.x * 256 + threadIdx.x);
    if (i >= n4) return;
    float4 v = *(const float4*)&A[i * 4];
    ushort4 h, l;
    cvt_hilo(v.x, h.x, l.x);
    cvt_hilo(v.y, h.y, l.y);
    cvt_hilo(v.z, h.z, l.z);
    cvt_hilo(v.w, h.w, l.w);
    *(ushort4*)&Ah[i * 4] = h;
    *(ushort4*)&Al[i * 4] = l;
}

// cvt + transpose: W f32 [K][N] -> Wh/Wl bf16 [N][K]
__global__ __launch_bounds__(256) void cvt_wT(const float* __restrict__ W,
                                              unsigned short* __restrict__ Wh,
                                              unsigned short* __restrict__ Wl,
                                              int K, int N) {
    int n = blockIdx.x, k = threadIdx.x;
    float v = W[(size_t)k * N + n];
    unsigned short h, l;
    cvt_hilo(v, h, l);
    Wh[(size_t)n * K + k] = h;
    Wl[(size_t)n * K + k] = l;
}

// cvt k_q slice: qkv_k q-part -> Kqg hi/lo [bh][k][32]
__global__ __launch_bounds__(256) void cvt_kq(const float* __restrict__ qkv_k,
                                              unsigned short* __restrict__ Kqh_g,
                                              unsigned short* __restrict__ Kql_g) {
    const int bh = blockIdx.x;
    const int b = bh >> 3, h = bh & 7;
    const int tid = threadIdx.x;
    const int k = tid >> 1, dg = (tid & 1) * 16;
    const float* src = &qkv_k[((size_t)(b * KL_ + k)) * TDIM_ + h * HD_ + dg];
    unsigned short hi[16], lo[16];
#pragma unroll
    for (int j4 = 0; j4 < 4; ++j4) {
        float4 v = *(const float4*)&src[j4 * 4];
        cvt_hilo(v.x, hi[j4 * 4 + 0], lo[j4 * 4 + 0]);
        cvt_hilo(v.y, hi[j4 * 4 + 1], lo[j4 * 4 + 1]);
        cvt_hilo(v.z, hi[j4 * 4 + 2], lo[j4 * 4 + 2]);
        cvt_hilo(v.w, hi[j4 * 4 + 3], lo[j4 * 4 + 3]);
    }
    unsigned short* dh = &Kqh_g[((size_t)bh * KL_ + k) * HD_ + dg];
    unsigned short* dl = &Kql_g[((size_t)bh * KL_ + k) * HD_ + dg];
    *(uint4*)&dh[0] = *(uint4*)&hi[0];
    *(uint4*)&dh[8] = *(uint4*)&hi[8];
    *(uint4*)&dl[0] = *(uint4*)&lo[0];
    *(uint4*)&dl[8] = *(uint4*)&lo[8];
}

// ---------------------------------------------------------------------------
// Split-bf16 MFMA GEMM (unchanged)
// ---------------------------------------------------------------------------
__global__ __launch_bounds__(256) void gemm_mfma(const unsigned short* __restrict__ Ah,
                                                 const unsigned short* __restrict__ Al,
                                                 const unsigned short* __restrict__ Bh,
                                                 const unsigned short* __restrict__ Bl,
                                                 float* __restrict__ C,
                                                 const float* __restrict__ bias,
                                                 int M, int N, int K) {
    __shared__ __align__(16) unsigned short Ah_s[128][40];
    __shared__ __align__(16) unsigned short Al_s[128][40];
    __shared__ __align__(16) unsigned short Bh_s[128][40];
    __shared__ __align__(16) unsigned short Bl_s[128][40];
    const int tid = threadIdx.x;
    const int w = tid >> 6, lane = tid & 63;
    const int c = lane & 15, q = lane >> 4;
    const int bm = blockIdx.y * 128, bn = blockIdx.x * 128;
    const int srow = tid >> 1, shf = (tid & 1) * 16;

    v4f acc[2][8] = {};
    for (int k0 = 0; k0 < K; k0 += 32) {
        __syncthreads();
        {
            const size_t ab = (size_t)(bm + srow) * K + k0 + shf;
            *(uint4*)&Ah_s[srow][shf] = *(const uint4*)&Ah[ab];
            *(uint4*)&Ah_s[srow][shf + 8] = *(const uint4*)&Ah[ab + 8];
            *(uint4*)&Al_s[srow][shf] = *(const uint4*)&Al[ab];
            *(uint4*)&Al_s[srow][shf + 8] = *(const uint4*)&Al[ab + 8];
            const size_t bb = (size_t)(bn + srow) * K + k0 + shf;
            *(uint4*)&Bh_s[srow][shf] = *(const uint4*)&Bh[bb];
            *(uint4*)&Bh_s[srow][shf + 8] = *(const uint4*)&Bh[bb + 8];
            *(uint4*)&Bl_s[srow][shf] = *(const uint4*)&Bl[bb];
            *(uint4*)&Bl_s[srow][shf + 8] = *(const uint4*)&Bl[bb + 8];
        }
        __syncthreads();
        v8s afh[2], afl[2];
#pragma unroll
        for (int mt = 0; mt < 2; ++mt) {
            afh[mt] = *(v8s*)&Ah_s[w * 32 + mt * 16 + c][q * 8];
            afl[mt] = *(v8s*)&Al_s[w * 32 + mt * 16 + c][q * 8];
        }
#pragma unroll
        for (int nt = 0; nt < 8; ++nt) {
            v8s bfh = *(v8s*)&Bh_s[nt * 16 + c][q * 8];
            v8s bfl = *(v8s*)&Bl_s[nt * 16 + c][q * 8];
#pragma unroll
            for (int mt = 0; mt < 2; ++mt) {
                acc[mt][nt] = __builtin_amdgcn_mfma_f32_16x16x32_bf16(afl[mt], bfh, acc[mt][nt], 0, 0, 0);
                acc[mt][nt] = __builtin_amdgcn_mfma_f32_16x16x32_bf16(afh[mt], bfl, acc[mt][nt], 0, 0, 0);
                acc[mt][nt] = __builtin_amdgcn_mfma_f32_16x16x32_bf16(afh[mt], bfh, acc[mt][nt], 0, 0, 0);
            }
        }
    }
#pragma unroll
    for (int mt = 0; mt < 2; ++mt) {
#pragma unroll
        for (int nt = 0; nt < 8; ++nt) {
            int col = bn + nt * 16 + c;
            float bv = bias ? bias[col] : 0.0f;
#pragma unroll
            for (int r = 0; r < 4; ++r) {
                int row = bm + w * 32 + mt * 16 + q * 4 + r;
                C[(size_t)row * N + col] = acc[mt][nt][r] + bv;
            }
        }
    }
}

// ---------------------------------------------------------------------------
// 64x64 f32 GEMM (small-M)
// ---------------------------------------------------------------------------
__global__ __launch_bounds__(256) void gemm64(const float* __restrict__ A,
                                              const float* __restrict__ Bw,
                                              float* __restrict__ C,
                                              const float* __restrict__ bias,
                                              int M, int N, int K) {
    __shared__ __align__(16) float As[16][68];
    __shared__ __align__(16) float Bs[16][64];
    const int tid = threadIdx.x;
    const int tx = tid & 15, ty = tid >> 4;
    const int bn = blockIdx.x * 64, bm = blockIdx.y * 64;
    const int am = tid >> 2, ac = tid & 3;
    float acc[4][4] = {};
    for (int k0 = 0; k0 < K; k0 += 16) {
        float4 a4 = *(const float4*)&A[(size_t)(bm + am) * K + k0 + ac * 4];
        As[ac * 4 + 0][am] = a4.x;
        As[ac * 4 + 1][am] = a4.y;
        As[ac * 4 + 2][am] = a4.z;
        As[ac * 4 + 3][am] = a4.w;
        *(float4*)&Bs[ty][tx * 4] = *(const float4*)&Bw[(size_t)(k0 + ty) * N + bn + tx * 4];
        __syncthreads();
#pragma unroll
        for (int kk = 0; kk < 16; ++kk) {
            float4 av = *(const float4*)&As[kk][ty * 4];
            float4 bv = *(const float4*)&Bs[kk][tx * 4];
            float a[4] = {av.x, av.y, av.z, av.w};
            float b[4] = {bv.x, bv.y, bv.z, bv.w};
#pragma unroll
            for (int i = 0; i < 4; ++i)
#pragma unroll
                for (int j = 0; j < 4; ++j) acc[i][j] += a[i] * b[j];
        }
        __syncthreads();
    }
#pragma unroll
    for (int i = 0; i < 4; ++i) {
        int m = bm + ty * 4 + i;
#pragma unroll
        for (int j = 0; j < 4; ++j) {
            int n = bn + tx * 4 + j;
            float v = acc[i][j];
            if (bias) v += bias[n];
            C[(size_t)m * N + n] = v;
        }
    }
}

// ===========================================================================
// K1 v3: score_bins_mfma3 — no Kq LDS (B-frags direct from global table);
// LDS ~18 KB -> 8 blocks/CU.
// ===========================================================================
__global__ __launch_bounds__(256) void score_bins_mfma3(const float* __restrict__ qkv_x,
                                                        const unsigned short* __restrict__ Kqh_g,
                                                        const unsigned short* __restrict__ Kql_g,
                                                        const int* __restrict__ rd,
                                                        const int* __restrict__ polar_pos,
                                                        const int* __restrict__ att_mask,
                                                        const float* __restrict__ dis_embed,
                                                        __hip_bfloat16* __restrict__ Sg,
                                                        float* __restrict__ binspart) {
    const int b = blockIdx.z, h = blockIdx.y, xc = blockIdx.x;
    const int x0 = xc * 64;
    const int tid = threadIdx.x;
    const int w = tid >> 6, lane = tid & 63;
    const int c15 = lane & 15, q = lane >> 4;
    const size_t bh = (size_t)(b * H_ + h);

    __shared__ unsigned int mskb[64][5];
    __shared__ float de_h[NDIS_];
    __shared__ float binsL[8][4][16][PB_];

    // mask -> bit tile
    {
        int xr = tid >> 2, kg = tid & 3;
        size_t gb = (bh * XL_ + x0 + xr) * KL_ + kg * 32;
        unsigned bits = 0;
#pragma unroll
        for (int i = 0; i < 8; ++i) {
            int4 m4 = *(const int4*)&att_mask[gb + i * 4];
            bits |= (m4.x ? 1u : 0u) << (i * 4 + 0);
            bits |= (m4.y ? 1u : 0u) << (i * 4 + 1);
            bits |= (m4.z ? 1u : 0u) << (i * 4 + 2);
            bits |= (m4.w ? 1u : 0u) << (i * 4 + 3);
        }
        mskb[xr][kg] = bits;
    }
    if (tid < NDIS_) de_h[tid] = dis_embed[tid * H_ + h];
    __syncthreads();

    // A-fragment in registers (own x row, hi/lo)
    v8s axh, axl;
    {
        const float* src = &qkv_x[((size_t)b * XL_ + x0 + w * 16 + c15) * TDIM_ + DIM_ + h * HD_ + q * 8];
        float4 v0 = *(const float4*)&src[0];
        float4 v1 = *(const float4*)&src[4];
        float vv[8] = {v0.x, v0.y, v0.z, v0.w, v1.x, v1.y, v1.z, v1.w};
#pragma unroll
        for (int j = 0; j < 8; ++j) {
            unsigned short hi, lo;
            cvt_hilo(vv[j], hi, lo);
            ((short*)&axh)[j] = (short)hi;
            ((short*)&axl)[j] = (short)lo;
        }
    }

    const int xw = x0 + w * 16;

#pragma unroll
    for (int nt = 0; nt < 8; ++nt) {
        const int k = nt * 16 + c15;
        const size_t kqoff = (bh * KL_ + k) * HD_ + q * 8;
        v8s bqh = *(const v8s*)&Kqh_g[kqoff];
        v8s bql = *(const v8s*)&Kql_g[kqoff];
        v4f D = {0.f, 0.f, 0.f, 0.f};
        D = __builtin_amdgcn_mfma_f32_16x16x32_bf16(axl, bqh, D, 0, 0, 0);
        D = __builtin_amdgcn_mfma_f32_16x16x32_bf16(axh, bql, D, 0, 0, 0);
        D = __builtin_amdgcn_mfma_f32_16x16x32_bf16(axh, bqh, D, 0, 0, 0);

        const size_t rowoff = ((size_t)(b * KL_ + k)) * XL_ + xw + q * 4;
        int4 r4 = *(const int4*)&rd[rowoff];
        int4 p4 = *(const int4*)&polar_pos[rowoff];
        int rv[4] = {r4.x, r4.y, r4.z, r4.w};
        int pv[4] = {p4.x, p4.y, p4.z, p4.w};

        float bins[PB_] = {};
        ushort4 pack;
#pragma unroll
        for (int r = 0; r < 4; ++r) {
            float s = D[r] * SCALE_;
            float a = fabsf(s);
            int pp = pv[r];
#pragma unroll
            for (int pb = 0; pb < PB_; ++pb) bins[pb] += (pp == pb) ? a : 0.0f;
            int xloc = w * 16 + q * 4 + r;
            int mbit = (mskb[xloc][k >> 5] >> (k & 31)) & 1;
            float sp = (mbit ? -1e6f : s) + de_h[rv[r]];
            ((unsigned short*)&pack)[r] = f2bf(sp);
        }
        *(ushort4*)((unsigned short*)Sg + (bh * KL_ + k) * XL_ + xw + q * 4) = pack;

#pragma unroll
        for (int pb = 0; pb < PB_; ++pb) {
            bins[pb] += __shfl_xor(bins[pb], 16);
            bins[pb] += __shfl_xor(bins[pb], 32);
        }
        if (q == 0) {
#pragma unroll
            for (int pb = 0; pb < PB_; ++pb) binsL[nt][w][c15][pb] = bins[pb];
        }
    }
    __syncthreads();
    {
        int k = tid >> 1, half = tid & 1;
        int nt = k >> 4, c = k & 15;
        float4 s = {0.f, 0.f, 0.f, 0.f};
#pragma unroll
        for (int w4 = 0; w4 < 4; ++w4) {
            float4 v = *(float4*)&binsL[nt][w4][c][half * 4];
            s.x += v.x; s.y += v.y; s.z += v.z; s.w += v.w;
        }
        *(float4*)&binspart[(bh * KL_ + k) * (NCH_ * PB_) + xc * PB_ + half * 4] = s;
    }
}

// K2: argmax
__global__ __launch_bounds__(256) void bins_argmax(const float* __restrict__ binspart,
                                                   int* __restrict__ main_ori) {
    const int w = threadIdx.x >> 6, lane = threadIdx.x & 63;
    const int row = blockIdx.x * 4 + w;
    const float* bp = &binspart[(size_t)row * (NCH_ * PB_) + lane * PB_];
    float s[PB_];
#pragma unroll
    for (int pb = 0; pb < PB_; ++pb) s[pb] = bp[pb];
#pragma unroll
    for (int m = 1; m < 64; m <<= 1)
#pragma unroll
        for (int pb = 0; pb < PB_; ++pb) s[pb] += __shfl_xor(s[pb], m);
    if (lane == 0) {
        float best = s[0];
        int bi = 0;
#pragma unroll
        for (int pb = 1; pb < PB_; ++pb)
            if (s[pb] > best) { best = s[pb]; bi = pb; }
        main_ori[row] = bi;
    }
}

// ===========================================================================
// K3 v2: flash_cached2 — KC=16 k-rows per block (2x V reuse, half the
// barrier-stalls). Block = 16 ki x 16 xt; each lane covers 4 x per 64-tile.
// ===========================================================================
__global__ __launch_bounds__(256) void flash_cached2(const float* __restrict__ qkv_x,
                                                     const __hip_bfloat16* __restrict__ Sg,
                                                     const int* __restrict__ polar_pos,
                                                     const float* __restrict__ polar_emb,
                                                     const int* __restrict__ main_ori,
                                                     float* __restrict__ part) {
    const int b = blockIdx.z, h = blockIdx.y;
    const int kch = blockIdx.x / NS_, xc = blockIdx.x % NS_;
    const int k0 = kch * KC2_;
    const int tid = threadIdx.x;
    const int ki = tid >> 4, xt = tid & 15;

    __shared__ __align__(16) float4 vs[64][9];
    __shared__ int pol_s[KC2_][68];
    __shared__ float pe[PB_];

    if (tid < PB_) pe[tid] = polar_emb[tid];
    const size_t xbase = (size_t)b * XL_;
    const size_t bh = (size_t)(b * H_ + h);
    const size_t row_k = bh * KL_ + k0 + ki;
    const int mo = main_ori[row_k];
    const int xbeg = xc * XCH_;

    float l = 0.f;
    float4 acc[8] = {};
    __syncthreads();
    for (int t = 0; t < XCH_ / 64; ++t) {
        const int x0 = xbeg + t * 64;
        __syncthreads();
#pragma unroll
        for (int i = 0; i < 2; ++i) {
            int id = tid + 256 * i;
            int row = id >> 3, c = id & 7;
            vs[row][c] = *(const float4*)&qkv_x[(xbase + x0 + row) * TDIM_ + 2 * DIM_ + h * HD_ + c * 4];
        }
        {
            int kk = tid >> 4, c = tid & 15;
            *(int4*)&pol_s[kk][c * 4] =
                *(const int4*)&polar_pos[(size_t)(b * KL_ + k0 + kk) * XL_ + x0 + c * 4];
        }
        __syncthreads();
#pragma unroll
        for (int j = 0; j < 4; ++j) {
            int xl = xt + 16 * j;
            int x = x0 + xl;
            float sp = __bfloat162float(Sg[row_k * XL_ + x]);
            int pp = pol_s[ki][xl];
            int np = pp - mo;
            np += (np >> 31) & PB_;
            float p = __expf(sp + pe[np]);
            l += p;
#pragma unroll
            for (int c = 0; c < 8; ++c) {
                float4 v = vs[xl][c];
                acc[c].x += p * v.x; acc[c].y += p * v.y;
                acc[c].z += p * v.z; acc[c].w += p * v.w;
            }
        }
    }
#pragma unroll
    for (int m = 1; m < 16; m <<= 1) {
        l += __shfl_xor(l, m, 16);
#pragma unroll
        for (int c = 0; c < 8; ++c) {
            acc[c].x += __shfl_xor(acc[c].x, m, 16);
            acc[c].y += __shfl_xor(acc[c].y, m, 16);
            acc[c].z += __shfl_xor(acc[c].z, m, 16);
            acc[c].w += __shfl_xor(acc[c].w, m, 16);
        }
    }
    if (xt == 0) {
        float* dst = &part[(size_t)(row_k * NS_ + xc) * 36];
#pragma unroll
        for (int c = 0; c < 8; ++c) *(float4*)&dst[c * 4] = acc[c];
        dst[32] = l;
    }
}

// K4: merge
__global__ __launch_bounds__(256) void merge_cached(const float* __restrict__ part,
                                                    float* __restrict__ kout_pre) {
    const int tid = threadIdx.x;
    const int ri = tid >> 5, d = tid & 31;
    const int row = blockIdx.x * 8 + ri;
    float l = 0.f, a = 0.f;
#pragma unroll
    for (int c = 0; c < NS_; ++c) {
        const float* p = &part[(size_t)(row * NS_ + c) * 36];
        l += p[32];
        a += p[d];
    }
    int k = row & (KL_ - 1);
    int bh = row >> 7;
    int h = bh & (H_ - 1), b = bh >> 3;
    kout_pre[(size_t)(b * KL_ + k) * DIM_ + h * HD_ + d] = a / l;
}

// ===========================================================================
// attn_x_mfma — now writes hi/lo bf16 proj operands directly (no cvt pass).
// ===========================================================================
__global__ __launch_bounds__(256) void attn_x_mfma(const float* __restrict__ qkv_x,
                                                   const float* __restrict__ qkv_k,
                                                   const int* __restrict__ rd,
                                                   const int* __restrict__ polar_pos,
                                                   const int* __restrict__ att_mask,
                                                   const float* __restrict__ dis_embed,
                                                   const float* __restrict__ polar_emb,
                                                   const int* __restrict__ main_ori,
                                                   unsigned short* __restrict__ oh,
                                                   unsigned short* __restrict__ ol) {
    const int b = blockIdx.z, h = blockIdx.y;
    const int x0 = blockIdx.x * 64;
    const int tid = threadIdx.x;
    const int wave = tid >> 6, lane = tid & 63;
    const int c = lane & 15, q = lane >> 4;

    __shared__ __align__(16) unsigned short Kk_s[KL_][40];
    __shared__ __align__(16) unsigned short VT_s[HD_][136];
    __shared__ __align__(16) unsigned short P_s[4][16][136];
    __shared__ unsigned short rp_s[KL_][72];
    __shared__ float de_h[NDIS_];
    __shared__ float pe[PB_];
    __shared__ int mo_s[KL_];

    const size_t bh = (size_t)(b * H_ + h);
    if (tid < NDIS_) de_h[tid] = dis_embed[tid * H_ + h];
    if (tid < PB_) pe[tid] = polar_emb[tid];
    if (tid < KL_) mo_s[tid] = main_ori[bh * KL_ + tid];

    {
        int row = tid >> 1, half = tid & 1;
        const float* src = &qkv_k[(size_t)(b * KL_ + row) * TDIM_ + h * HD_ + half * 16];
#pragma unroll
        for (int j = 0; j < 16; ++j) Kk_s[row][half * 16 + j] = f2bf(src[DIM_ + j]);
#pragma unroll
        for (int j = 0; j < 16; ++j) VT_s[half * 16 + j][row] = f2bf(src[2 * DIM_ + j]);
    }
    __syncthreads();

#pragma unroll
    for (int i = 0; i < 8; ++i) {
        int id = tid + 256 * i;
        int k = id >> 4, cc = id & 15;
        size_t gb = (size_t)(b * KL_ + k) * XL_ + x0 + cc * 4;
        int4 r4 = *(const int4*)&rd[gb];
        int4 p4 = *(const int4*)&polar_pos[gb];
        int mo = mo_s[k];
        int n0 = p4.x - mo; n0 += (n0 >> 31) & PB_;
        int n1 = p4.y - mo; n1 += (n1 >> 31) & PB_;
        int n2 = p4.z - mo; n2 += (n2 >> 31) & PB_;
        int n3 = p4.w - mo; n3 += (n3 >> 31) & PB_;
        rp_s[k][cc * 4 + 0] = (unsigned short)(r4.x | (n0 << 8));
        rp_s[k][cc * 4 + 1] = (unsigned short)(r4.y | (n1 << 8));
        rp_s[k][cc * 4 + 2] = (unsigned short)(r4.z | (n2 << 8));
        rp_s[k][cc * 4 + 3] = (unsigned short)(r4.w | (n3 << 8));
    }
    __syncthreads();
#pragma unroll
    for (int i = 0; i < 8; ++i) {
        int id = tid + 256 * i;
        int xr = id >> 5, kc = id & 31;
        int4 m4 = *(const int4*)&att_mask[(bh * XL_ + x0 + xr) * KL_ + kc * 4];
        if (m4.x) rp_s[kc * 4 + 0][xr] |= 0x8000;
        if (m4.y) rp_s[kc * 4 + 1][xr] |= 0x8000;
        if (m4.z) rp_s[kc * 4 + 2][xr] |= 0x8000;
        if (m4.w) rp_s[kc * 4 + 3][xr] |= 0x8000;
    }
    __syncthreads();

    v8s aq;
    {
        const float* qp = &qkv_x[(size_t)(b * XL_ + x0 + wave * 16 + c) * TDIM_ + h * HD_ + q * 8];
        float4 q0 = *(const float4*)&qp[0];
        float4 q1 = *(const float4*)&qp[4];
        aq[0] = (short)f2bf(q0.x); aq[1] = (short)f2bf(q0.y);
        aq[2] = (short)f2bf(q0.z); aq[3] = (short)f2bf(q0.w);
        aq[4] = (short)f2bf(q1.x); aq[5] = (short)f2bf(q1.y);
        aq[6] = (short)f2bf(q1.z); aq[7] = (short)f2bf(q1.w);
    }

    v4f S[8];
#pragma unroll
    for (int t = 0; t < 8; ++t) {
        v8s bk = *(v8s*)&Kk_s[t * 16 + c][q * 8];
        S[t] = __builtin_amdgcn_mfma_f32_16x16x32_bf16(aq, bk, (v4f){0.f, 0.f, 0.f, 0.f}, 0, 0, 0);
    }

    const int xloc = wave * 16;
    float lr[4] = {0.f, 0.f, 0.f, 0.f};
#pragma unroll
    for (int t = 0; t < 8; ++t) {
#pragma unroll
        for (int r = 0; r < 4; ++r) {
            int krow = t * 16 + c;
            int xrow = q * 4 + r;
            unsigned short rp = rp_s[krow][xloc + xrow];
            float sval = S[t][r] * SCALE_;
            float tval = ((rp & 0x8000) ? -25.0f : sval) + de_h[rp & 0x7f] + pe[(rp >> 8) & 7];
            float p = __expf(tval);
            unsigned short pb = f2bf(p);
            P_s[wave][xrow][krow] = pb;
            lr[r] += bf2f(pb);
        }
    }
#pragma unroll
    for (int r = 0; r < 4; ++r) {
#pragma unroll
        for (int m = 1; m < 16; m <<= 1) lr[r] += __shfl_xor(lr[r], m);
    }
    __syncthreads();

    v4f O0 = {0.f, 0.f, 0.f, 0.f}, O1 = {0.f, 0.f, 0.f, 0.f};
#pragma unroll
    for (int kc = 0; kc < 4; ++kc) {
        v8s ap = *(v8s*)&P_s[wave][c][kc * 32 + q * 8];
        v8s bv0 = *(v8s*)&VT_s[c][kc * 32 + q * 8];
        v8s bv1 = *(v8s*)&VT_s[16 + c][kc * 32 + q * 8];
        O0 = __builtin_amdgcn_mfma_f32_16x16x32_bf16(ap, bv0, O0, 0, 0, 0);
        O1 = __builtin_amdgcn_mfma_f32_16x16x32_bf16(ap, bv1, O1, 0, 0, 0);
    }

#pragma unroll
    for (int r = 0; r < 4; ++r) {
        int xg = x0 + wave * 16 + q * 4 + r;
        float inv = 1.0f / lr[r];
        size_t obase = (size_t)(b * XL_ + xg) * DIM_ + h * HD_;
        float v0 = O0[r] * inv;
        float v1 = O1[r] * inv;
        unsigned short h0, l0, h1, l1;
        cvt_hilo(v0, h0, l0);
        cvt_hilo(v1, h1, l1);
        oh[obase + c] = h0;
        ol[obase + c] = l0;
        oh[obase + 16 + c] = h1;
        ol[obase + 16 + c] = l1;
    }
}

// ---------------------------------------------------------------------------
extern "C" void kernel_launch(void* const* d_in, const int* in_sizes, int n_in,
                              void* d_out, int out_size, void* d_ws, size_t ws_size,
                              hipStream_t stream) {
    const float* x         = (const float*)d_in[0];
    const float* kernal    = (const float*)d_in[1];
    const int* rd          = (const int*)d_in[2];
    const int* polar_pos   = (const int*)d_in[3];
    const int* att_mask    = (const int*)d_in[4];
    const float* W_qkv     = (const float*)d_in[5];
    const float* dis_embed = (const float*)d_in[6];
    const float* polar_emb = (const float*)d_in[7];
    const float* W_proj    = (const float*)d_in[8];
    const float* b_proj    = (const float*)d_in[9];
    float* out             = (float*)d_out;

    char* base = (char*)d_ws;
    size_t off = 0;
    auto alloc = [&](size_t bytes) { void* p = base + off; off = (off + bytes + 255) & ~255ULL; return p; };
    float* qkv_x    = (float*)alloc((size_t)B_ * XL_ * TDIM_ * 4);
    float* qkv_k    = (float*)alloc((size_t)B_ * KL_ * TDIM_ * 4);
    float* xout_pre = (float*)alloc((size_t)B_ * XL_ * DIM_ * 4);   // used only as binspart alias now
    float* kout_pre = (float*)alloc((size_t)B_ * KL_ * DIM_ * 4);
    int* main_ori   = (int*)alloc(B_ * H_ * KL_ * 4);
    float* part     = (float*)alloc((size_t)B_ * H_ * KL_ * NS_ * 36 * 4);
    __hip_bfloat16* Sg = (__hip_bfloat16*)alloc((size_t)B_ * H_ * KL_ * XL_ * 2);
    unsigned short* wph = (unsigned short*)alloc((size_t)DIM_ * DIM_ * 2);
    unsigned short* wpl = (unsigned short*)alloc((size_t)DIM_ * DIM_ * 2);

    // Aliases into dead regions (timeline-checked):
    float* binspart = xout_pre;                        // dead after bins_argmax
    const size_t MX = (size_t)B_ * XL_;
    unsigned short* xh = (unsigned short*)Sg;          // Sg written later by score_bins
    unsigned short* xl_ = xh + MX * DIM_;
    unsigned short* wqh = (unsigned short*)part;       // part written later by flash_cached
    unsigned short* wql = wqh + (size_t)TDIM_ * DIM_;
    unsigned short* kqh_g = wqh + 2 * (size_t)TDIM_ * DIM_;
    unsigned short* kql_g = kqh_g + (size_t)B_ * H_ * KL_ * HD_;
    unsigned short* oh = (unsigned short*)Sg;          // Sg dead after flash_cached2
    unsigned short* ol = oh + MX * DIM_;

    // --- operand conversion ---
    cvt_mat<<<dim3((MX * DIM_ / 4 + 255) / 256), 256, 0, stream>>>(x, xh, xl_, MX * DIM_ / 4);
    cvt_wT<<<dim3(TDIM_), DIM_, 0, stream>>>(W_qkv, wqh, wql, DIM_, TDIM_);
    cvt_wT<<<dim3(DIM_), DIM_, 0, stream>>>(W_proj, wph, wpl, DIM_, DIM_);

    // --- qkv projections ---
    gemm_mfma<<<dim3(TDIM_ / 128, MX / 128), 256, 0, stream>>>(
        xh, xl_, wqh, wql, qkv_x, nullptr, MX, TDIM_, DIM_);
    gemm64<<<dim3(TDIM_ / 64, (B_ * KL_) / 64), 256, 0, stream>>>(
        kernal, W_qkv, qkv_k, nullptr, B_ * KL_, TDIM_, DIM_);
    cvt_kq<<<dim3(B_ * H_), 256, 0, stream>>>(qkv_k, kqh_g, kql_g);

    // --- k-direction ---
    score_bins_mfma3<<<dim3(NCH_, H_, B_), 256, 0, stream>>>(
        qkv_x, kqh_g, kql_g, rd, polar_pos, att_mask, dis_embed, Sg, binspart);
    bins_argmax<<<dim3(B_ * H_ * KL_ / 4), 256, 0, stream>>>(binspart, main_ori);
    flash_cached2<<<dim3((KL_ / KC2_) * NS_, H_, B_), 256, 0, stream>>>(
        qkv_x, Sg, polar_pos, polar_emb, main_ori, part);
    merge_cached<<<dim3(B_ * H_ * KL_ / 8), 256, 0, stream>>>(part, kout_pre);

    // --- x-direction (writes hi/lo proj operands directly) ---
    attn_x_mfma<<<dim3(XL_ / 64, H_, B_), 256, 0, stream>>>(
        qkv_x, qkv_k, rd, polar_pos, att_mask, dis_embed, polar_emb, main_ori, oh, ol);

    // --- output projections ---
    gemm_mfma<<<dim3(DIM_ / 128, MX / 128), 256, 0, stream>>>(
        oh, ol, wph, wpl, out, b_proj, MX, DIM_, DIM_);
    gemm64<<<dim3(DIM_ / 64, (B_ * KL_) / 64), 256, 0, stream>>>(
        kout_pre, W_proj, out + (size_t)B_ * XL_ * DIM_, b_proj, B_ * KL_, DIM_, DIM_);
}

// Round 16
// 357.231 us; speedup vs baseline: 1.7117x; 1.0152x over previous
//
#include <hip/hip_runtime.h>
#include <hip/hip_bf16.h>

#define B_    4
#define KL_   128
#define XL_   4096
#define DIM_  256
#define H_    8
#define HD_   32
#define PB_   8
#define NDIS_ 66
#define TDIM_ 768
#define SCALE_ 0.17677669529663687f
#define NS_   4
#define XCH_  (XL_ / NS_)
#define NCH2_ 32
#define KC2_  16

typedef float v4f __attribute__((ext_vector_type(4)));
typedef short v8s __attribute__((ext_vector_type(8)));

__device__ __forceinline__ unsigned short f2bf(float f) {
    __hip_bfloat16 h = __float2bfloat16(f);
    return __builtin_bit_cast(unsigned short, h);
}
__device__ __forceinline__ float bf2f(unsigned short u) {
    return __bfloat162float(__builtin_bit_cast(__hip_bfloat16, u));
}
__device__ __forceinline__ void cvt_hilo(float v, unsigned short& hi, unsigned short& lo) {
    hi = f2bf(v);
    lo = f2bf(v - bf2f(hi));
}

// ---------------------------------------------------------------------------
// cvt: f32 row-major -> hi/lo bf16 row-major
// ---------------------------------------------------------------------------
__global__ __launch_bounds__(256) void cvt_mat(const float* __restrict__ A,
                                               unsigned short* __restrict__ Ah,
                                               unsigned short* __restrict__ Al,
                                               size_t n4) {
    size_t i = ((size_t)blockIdx.x * 256 + threadIdx.x);
    if (i >= n4) return;
    float4 v = *(const float4*)&A[i * 4];
    ushort4 h, l;
    cvt_hilo(v.x, h.x, l.x);
    cvt_hilo(v.y, h.y, l.y);
    cvt_hilo(v.z, h.z, l.z);
    cvt_hilo(v.w, h.w, l.w);
    *(ushort4*)&Ah[i * 4] = h;
    *(ushort4*)&Al[i * 4] = l;
}

// cvt + transpose: W f32 [K][N] -> Wh/Wl bf16 [N][K]
__global__ __launch_bounds__(256) void cvt_wT(const float* __restrict__ W,
                                              unsigned short* __restrict__ Wh,
                                              unsigned short* __restrict__ Wl,
                                              int K, int N) {
    int n = blockIdx.x, k = threadIdx.x;
    float v = W[(size_t)k * N + n];
    unsigned short h, l;
    cvt_hilo(v, h, l);
    Wh[(size_t)n * K + k] = h;
    Wl[(size_t)n * K + k] = l;
}

// cvt k_q slice: qkv_k q-part -> Kqg hi/lo [bh][k][32]
__global__ __launch_bounds__(256) void cvt_kq(const float* __restrict__ qkv_k,
                                              unsigned short* __restrict__ Kqh_g,
                                              unsigned short* __restrict__ Kql_g) {
    const int bh = blockIdx.x;
    const int b = bh >> 3, h = bh & 7;
    const int tid = threadIdx.x;
    const int k = tid >> 1, dg = (tid & 1) * 16;
    const float* src = &qkv_k[((size_t)(b * KL_ + k)) * TDIM_ + h * HD_ + dg];
    unsigned short hi[16], lo[16];
#pragma unroll
    for (int j4 = 0; j4 < 4; ++j4) {
        float4 v = *(const float4*)&src[j4 * 4];
        cvt_hilo(v.x, hi[j4 * 4 + 0], lo[j4 * 4 + 0]);
        cvt_hilo(v.y, hi[j4 * 4 + 1], lo[j4 * 4 + 1]);
        cvt_hilo(v.z, hi[j4 * 4 + 2], lo[j4 * 4 + 2]);
        cvt_hilo(v.w, hi[j4 * 4 + 3], lo[j4 * 4 + 3]);
    }
    unsigned short* dh = &Kqh_g[((size_t)bh * KL_ + k) * HD_ + dg];
    unsigned short* dl = &Kql_g[((size_t)bh * KL_ + k) * HD_ + dg];
    *(uint4*)&dh[0] = *(uint4*)&hi[0];
    *(uint4*)&dh[8] = *(uint4*)&hi[8];
    *(uint4*)&dl[0] = *(uint4*)&lo[0];
    *(uint4*)&dl[8] = *(uint4*)&lo[8];
}

// ---------------------------------------------------------------------------
// Split-bf16 MFMA GEMM (unchanged)
// ---------------------------------------------------------------------------
__global__ __launch_bounds__(256) void gemm_mfma(const unsigned short* __restrict__ Ah,
                                                 const unsigned short* __restrict__ Al,
                                                 const unsigned short* __restrict__ Bh,
                                                 const unsigned short* __restrict__ Bl,
                                                 float* __restrict__ C,
                                                 const float* __restrict__ bias,
                                                 int M, int N, int K) {
    __shared__ __align__(16) unsigned short Ah_s[128][40];
    __shared__ __align__(16) unsigned short Al_s[128][40];
    __shared__ __align__(16) unsigned short Bh_s[128][40];
    __shared__ __align__(16) unsigned short Bl_s[128][40];
    const int tid = threadIdx.x;
    const int w = tid >> 6, lane = tid & 63;
    const int c = lane & 15, q = lane >> 4;
    const int bm = blockIdx.y * 128, bn = blockIdx.x * 128;
    const int srow = tid >> 1, shf = (tid & 1) * 16;

    v4f acc[2][8] = {};
    for (int k0 = 0; k0 < K; k0 += 32) {
        __syncthreads();
        {
            const size_t ab = (size_t)(bm + srow) * K + k0 + shf;
            *(uint4*)&Ah_s[srow][shf] = *(const uint4*)&Ah[ab];
            *(uint4*)&Ah_s[srow][shf + 8] = *(const uint4*)&Ah[ab + 8];
            *(uint4*)&Al_s[srow][shf] = *(const uint4*)&Al[ab];
            *(uint4*)&Al_s[srow][shf + 8] = *(const uint4*)&Al[ab + 8];
            const size_t bb = (size_t)(bn + srow) * K + k0 + shf;
            *(uint4*)&Bh_s[srow][shf] = *(const uint4*)&Bh[bb];
            *(uint4*)&Bh_s[srow][shf + 8] = *(const uint4*)&Bh[bb + 8];
            *(uint4*)&Bl_s[srow][shf] = *(const uint4*)&Bl[bb];
            *(uint4*)&Bl_s[srow][shf + 8] = *(const uint4*)&Bl[bb + 8];
        }
        __syncthreads();
        v8s afh[2], afl[2];
#pragma unroll
        for (int mt = 0; mt < 2; ++mt) {
            afh[mt] = *(v8s*)&Ah_s[w * 32 + mt * 16 + c][q * 8];
            afl[mt] = *(v8s*)&Al_s[w * 32 + mt * 16 + c][q * 8];
        }
#pragma unroll
        for (int nt = 0; nt < 8; ++nt) {
            v8s bfh = *(v8s*)&Bh_s[nt * 16 + c][q * 8];
            v8s bfl = *(v8s*)&Bl_s[nt * 16 + c][q * 8];
#pragma unroll
            for (int mt = 0; mt < 2; ++mt) {
                acc[mt][nt] = __builtin_amdgcn_mfma_f32_16x16x32_bf16(afl[mt], bfh, acc[mt][nt], 0, 0, 0);
                acc[mt][nt] = __builtin_amdgcn_mfma_f32_16x16x32_bf16(afh[mt], bfl, acc[mt][nt], 0, 0, 0);
                acc[mt][nt] = __builtin_amdgcn_mfma_f32_16x16x32_bf16(afh[mt], bfh, acc[mt][nt], 0, 0, 0);
            }
        }
    }
#pragma unroll
    for (int mt = 0; mt < 2; ++mt) {
#pragma unroll
        for (int nt = 0; nt < 8; ++nt) {
            int col = bn + nt * 16 + c;
            float bv = bias ? bias[col] : 0.0f;
#pragma unroll
            for (int r = 0; r < 4; ++r) {
                int row = bm + w * 32 + mt * 16 + q * 4 + r;
                C[(size_t)row * N + col] = acc[mt][nt][r] + bv;
            }
        }
    }
}

// ---------------------------------------------------------------------------
// 64x64 f32 GEMM (small-M)
// ---------------------------------------------------------------------------
__global__ __launch_bounds__(256) void gemm64(const float* __restrict__ A,
                                              const float* __restrict__ Bw,
                                              float* __restrict__ C,
                                              const float* __restrict__ bias,
                                              int M, int N, int K) {
    __shared__ __align__(16) float As[16][68];
    __shared__ __align__(16) float Bs[16][64];
    const int tid = threadIdx.x;
    const int tx = tid & 15, ty = tid >> 4;
    const int bn = blockIdx.x * 64, bm = blockIdx.y * 64;
    const int am = tid >> 2, ac = tid & 3;
    float acc[4][4] = {};
    for (int k0 = 0; k0 < K; k0 += 16) {
        float4 a4 = *(const float4*)&A[(size_t)(bm + am) * K + k0 + ac * 4];
        As[ac * 4 + 0][am] = a4.x;
        As[ac * 4 + 1][am] = a4.y;
        As[ac * 4 + 2][am] = a4.z;
        As[ac * 4 + 3][am] = a4.w;
        *(float4*)&Bs[ty][tx * 4] = *(const float4*)&Bw[(size_t)(k0 + ty) * N + bn + tx * 4];
        __syncthreads();
#pragma unroll
        for (int kk = 0; kk < 16; ++kk) {
            float4 av = *(const float4*)&As[kk][ty * 4];
            float4 bv = *(const float4*)&Bs[kk][tx * 4];
            float a[4] = {av.x, av.y, av.z, av.w};
            float b[4] = {bv.x, bv.y, bv.z, bv.w};
#pragma unroll
            for (int i = 0; i < 4; ++i)
#pragma unroll
                for (int j = 0; j < 4; ++j) acc[i][j] += a[i] * b[j];
        }
        __syncthreads();
    }
#pragma unroll
    for (int i = 0; i < 4; ++i) {
        int m = bm + ty * 4 + i;
#pragma unroll
        for (int j = 0; j < 4; ++j) {
            int n = bn + tx * 4 + j;
            float v = acc[i][j];
            if (bias) v += bias[n];
            C[(size_t)m * N + n] = v;
        }
    }
}

// ===========================================================================
// K1 v4: score_bins_mfma4 — 128-x blocks (2 tiles/wave share Kq frags) +
// explicit 2-deep register prefetch pipeline.
// ===========================================================================
__global__ __launch_bounds__(256) void score_bins_mfma4(const float* __restrict__ qkv_x,
                                                        const unsigned short* __restrict__ Kqh_g,
                                                        const unsigned short* __restrict__ Kql_g,
                                                        const int* __restrict__ rd,
                                                        const int* __restrict__ polar_pos,
                                                        const int* __restrict__ att_mask,
                                                        const float* __restrict__ dis_embed,
                                                        __hip_bfloat16* __restrict__ Sg,
                                                        float* __restrict__ binspart) {
    const int b = blockIdx.z, h = blockIdx.y, xc = blockIdx.x;
    const int x0 = xc * 128;
    const int tid = threadIdx.x;
    const int w = tid >> 6, lane = tid & 63;
    const int c15 = lane & 15, q = lane >> 4;
    const size_t bh = (size_t)(b * H_ + h);

    __shared__ unsigned int mskb[128][5];
    __shared__ float de_h[NDIS_];
    __shared__ float binsL[8][4][16][PB_];

    // mask -> bit tile (128 x rows, 4 k-groups of 32)
#pragma unroll
    for (int it = 0; it < 2; ++it) {
        int id = tid + 256 * it;
        int xr = id >> 2, kg = id & 3;
        size_t gb = (bh * XL_ + x0 + xr) * KL_ + kg * 32;
        unsigned bits = 0;
#pragma unroll
        for (int i = 0; i < 8; ++i) {
            int4 m4 = *(const int4*)&att_mask[gb + i * 4];
            bits |= (m4.x ? 1u : 0u) << (i * 4 + 0);
            bits |= (m4.y ? 1u : 0u) << (i * 4 + 1);
            bits |= (m4.z ? 1u : 0u) << (i * 4 + 2);
            bits |= (m4.w ? 1u : 0u) << (i * 4 + 3);
        }
        mskb[xr][kg] = bits;
    }
    if (tid < NDIS_) de_h[tid] = dis_embed[tid * H_ + h];
    __syncthreads();

    // Two A-fragments per wave (x-tiles at x0+w*16 and x0+64+w*16)
    v8s axh[2], axl[2];
#pragma unroll
    for (int t = 0; t < 2; ++t) {
        const float* src = &qkv_x[((size_t)b * XL_ + x0 + t * 64 + w * 16 + c15) * TDIM_ + DIM_ + h * HD_ + q * 8];
        float4 v0 = *(const float4*)&src[0];
        float4 v1 = *(const float4*)&src[4];
        float vv[8] = {v0.x, v0.y, v0.z, v0.w, v1.x, v1.y, v1.z, v1.w};
#pragma unroll
        for (int j = 0; j < 8; ++j) {
            unsigned short hi, lo;
            cvt_hilo(vv[j], hi, lo);
            ((short*)&axh[t])[j] = (short)hi;
            ((short*)&axl[t])[j] = (short)lo;
        }
    }

    // 2-deep prefetch pipeline state
    v8s bqh[2], bql[2];
    int4 r4[2][2], p4[2][2];
    auto load_nt = [&](int nt, int s) {
        const int k = nt * 16 + c15;
        const size_t kqoff = (bh * KL_ + k) * HD_ + q * 8;
        bqh[s] = *(const v8s*)&Kqh_g[kqoff];
        bql[s] = *(const v8s*)&Kql_g[kqoff];
#pragma unroll
        for (int t = 0; t < 2; ++t) {
            const size_t rowoff = ((size_t)(b * KL_ + k)) * XL_ + x0 + t * 64 + w * 16 + q * 4;
            r4[s][t] = *(const int4*)&rd[rowoff];
            p4[s][t] = *(const int4*)&polar_pos[rowoff];
        }
    };
    load_nt(0, 0);

#pragma unroll
    for (int nt = 0; nt < 8; ++nt) {
        const int s = nt & 1;
        if (nt < 7) load_nt(nt + 1, s ^ 1);

        const int k = nt * 16 + c15;
        v4f D[2] = {{0.f, 0.f, 0.f, 0.f}, {0.f, 0.f, 0.f, 0.f}};
#pragma unroll
        for (int t = 0; t < 2; ++t) {
            D[t] = __builtin_amdgcn_mfma_f32_16x16x32_bf16(axl[t], bqh[s], D[t], 0, 0, 0);
            D[t] = __builtin_amdgcn_mfma_f32_16x16x32_bf16(axh[t], bql[s], D[t], 0, 0, 0);
            D[t] = __builtin_amdgcn_mfma_f32_16x16x32_bf16(axh[t], bqh[s], D[t], 0, 0, 0);
        }

        float bins[PB_] = {};
#pragma unroll
        for (int t = 0; t < 2; ++t) {
            int rv[4] = {r4[s][t].x, r4[s][t].y, r4[s][t].z, r4[s][t].w};
            int pv[4] = {p4[s][t].x, p4[s][t].y, p4[s][t].z, p4[s][t].w};
            ushort4 pack;
#pragma unroll
            for (int r = 0; r < 4; ++r) {
                float sc = D[t][r] * SCALE_;
                float a = fabsf(sc);
                int pp = pv[r];
#pragma unroll
                for (int pb = 0; pb < PB_; ++pb) bins[pb] += (pp == pb) ? a : 0.0f;
                int xloc = t * 64 + w * 16 + q * 4 + r;
                int mbit = (mskb[xloc][k >> 5] >> (k & 31)) & 1;
                float sp = (mbit ? -1e6f : sc) + de_h[rv[r]];
                ((unsigned short*)&pack)[r] = f2bf(sp);
            }
            *(ushort4*)((unsigned short*)Sg + (bh * KL_ + k) * XL_ + x0 + t * 64 + w * 16 + q * 4) = pack;
        }

#pragma unroll
        for (int pb = 0; pb < PB_; ++pb) {
            bins[pb] += __shfl_xor(bins[pb], 16);
            bins[pb] += __shfl_xor(bins[pb], 32);
        }
        if (q == 0) {
#pragma unroll
            for (int pb = 0; pb < PB_; ++pb) binsL[nt][w][c15][pb] = bins[pb];
        }
    }
    __syncthreads();
    {
        int k = tid >> 1, half = tid & 1;
        int nt = k >> 4, c = k & 15;
        float4 s = {0.f, 0.f, 0.f, 0.f};
#pragma unroll
        for (int w4 = 0; w4 < 4; ++w4) {
            float4 v = *(float4*)&binsL[nt][w4][c][half * 4];
            s.x += v.x; s.y += v.y; s.z += v.z; s.w += v.w;
        }
        *(float4*)&binspart[(bh * KL_ + k) * (NCH2_ * PB_) + xc * PB_ + half * 4] = s;
    }
}

// K2: argmax over 32 chunks (lanes 0-31 active; zero-padded reduce)
__global__ __launch_bounds__(256) void bins_argmax(const float* __restrict__ binspart,
                                                   int* __restrict__ main_ori) {
    const int w = threadIdx.x >> 6, lane = threadIdx.x & 63;
    const int row = blockIdx.x * 4 + w;
    float s[PB_];
#pragma unroll
    for (int pb = 0; pb < PB_; ++pb) s[pb] = 0.0f;
    if (lane < NCH2_) {
        const float* bp = &binspart[(size_t)row * (NCH2_ * PB_) + lane * PB_];
#pragma unroll
        for (int pb = 0; pb < PB_; ++pb) s[pb] = bp[pb];
    }
#pragma unroll
    for (int m = 1; m < 64; m <<= 1)
#pragma unroll
        for (int pb = 0; pb < PB_; ++pb) s[pb] += __shfl_xor(s[pb], m);
    if (lane == 0) {
        float best = s[0];
        int bi = 0;
#pragma unroll
        for (int pb = 1; pb < PB_; ++pb)
            if (s[pb] > best) { best = s[pb]; bi = pb; }
        main_ori[row] = bi;
    }
}

// ===========================================================================
// K3 v2: flash_cached2 (unchanged)
// ===========================================================================
__global__ __launch_bounds__(256) void flash_cached2(const float* __restrict__ qkv_x,
                                                     const __hip_bfloat16* __restrict__ Sg,
                                                     const int* __restrict__ polar_pos,
                                                     const float* __restrict__ polar_emb,
                                                     const int* __restrict__ main_ori,
                                                     float* __restrict__ part) {
    const int b = blockIdx.z, h = blockIdx.y;
    const int kch = blockIdx.x / NS_, xc = blockIdx.x % NS_;
    const int k0 = kch * KC2_;
    const int tid = threadIdx.x;
    const int ki = tid >> 4, xt = tid & 15;

    __shared__ __align__(16) float4 vs[64][9];
    __shared__ int pol_s[KC2_][68];
    __shared__ float pe[PB_];

    if (tid < PB_) pe[tid] = polar_emb[tid];
    const size_t xbase = (size_t)b * XL_;
    const size_t bh = (size_t)(b * H_ + h);
    const size_t row_k = bh * KL_ + k0 + ki;
    const int mo = main_ori[row_k];
    const int xbeg = xc * XCH_;

    float l = 0.f;
    float4 acc[8] = {};
    __syncthreads();
    for (int t = 0; t < XCH_ / 64; ++t) {
        const int x0 = xbeg + t * 64;
        __syncthreads();
#pragma unroll
        for (int i = 0; i < 2; ++i) {
            int id = tid + 256 * i;
            int row = id >> 3, c = id & 7;
            vs[row][c] = *(const float4*)&qkv_x[(xbase + x0 + row) * TDIM_ + 2 * DIM_ + h * HD_ + c * 4];
        }
        {
            int kk = tid >> 4, c = tid & 15;
            *(int4*)&pol_s[kk][c * 4] =
                *(const int4*)&polar_pos[(size_t)(b * KL_ + k0 + kk) * XL_ + x0 + c * 4];
        }
        __syncthreads();
#pragma unroll
        for (int j = 0; j < 4; ++j) {
            int xl = xt + 16 * j;
            int x = x0 + xl;
            float sp = __bfloat162float(Sg[row_k * XL_ + x]);
            int pp = pol_s[ki][xl];
            int np = pp - mo;
            np += (np >> 31) & PB_;
            float p = __expf(sp + pe[np]);
            l += p;
#pragma unroll
            for (int c = 0; c < 8; ++c) {
                float4 v = vs[xl][c];
                acc[c].x += p * v.x; acc[c].y += p * v.y;
                acc[c].z += p * v.z; acc[c].w += p * v.w;
            }
        }
    }
#pragma unroll
    for (int m = 1; m < 16; m <<= 1) {
        l += __shfl_xor(l, m, 16);
#pragma unroll
        for (int c = 0; c < 8; ++c) {
            acc[c].x += __shfl_xor(acc[c].x, m, 16);
            acc[c].y += __shfl_xor(acc[c].y, m, 16);
            acc[c].z += __shfl_xor(acc[c].z, m, 16);
            acc[c].w += __shfl_xor(acc[c].w, m, 16);
        }
    }
    if (xt == 0) {
        float* dst = &part[(size_t)(row_k * NS_ + xc) * 36];
#pragma unroll
        for (int c = 0; c < 8; ++c) *(float4*)&dst[c * 4] = acc[c];
        dst[32] = l;
    }
}

// K4: merge
__global__ __launch_bounds__(256) void merge_cached(const float* __restrict__ part,
                                                    float* __restrict__ kout_pre) {
    const int tid = threadIdx.x;
    const int ri = tid >> 5, d = tid & 31;
    const int row = blockIdx.x * 8 + ri;
    float l = 0.f, a = 0.f;
#pragma unroll
    for (int c = 0; c < NS_; ++c) {
        const float* p = &part[(size_t)(row * NS_ + c) * 36];
        l += p[32];
        a += p[d];
    }
    int k = row & (KL_ - 1);
    int bh = row >> 7;
    int h = bh & (H_ - 1), b = bh >> 3;
    kout_pre[(size_t)(b * KL_ + k) * DIM_ + h * HD_ + d] = a / l;
}

// ===========================================================================
// attn_x_mfma (unchanged; writes hi/lo proj operands directly)
// ===========================================================================
__global__ __launch_bounds__(256) void attn_x_mfma(const float* __restrict__ qkv_x,
                                                   const float* __restrict__ qkv_k,
                                                   const int* __restrict__ rd,
                                                   const int* __restrict__ polar_pos,
                                                   const int* __restrict__ att_mask,
                                                   const float* __restrict__ dis_embed,
                                                   const float* __restrict__ polar_emb,
                                                   const int* __restrict__ main_ori,
                                                   unsigned short* __restrict__ oh,
                                                   unsigned short* __restrict__ ol) {
    const int b = blockIdx.z, h = blockIdx.y;
    const int x0 = blockIdx.x * 64;
    const int tid = threadIdx.x;
    const int wave = tid >> 6, lane = tid & 63;
    const int c = lane & 15, q = lane >> 4;

    __shared__ __align__(16) unsigned short Kk_s[KL_][40];
    __shared__ __align__(16) unsigned short VT_s[HD_][136];
    __shared__ __align__(16) unsigned short P_s[4][16][136];
    __shared__ unsigned short rp_s[KL_][72];
    __shared__ float de_h[NDIS_];
    __shared__ float pe[PB_];
    __shared__ int mo_s[KL_];

    const size_t bh = (size_t)(b * H_ + h);
    if (tid < NDIS_) de_h[tid] = dis_embed[tid * H_ + h];
    if (tid < PB_) pe[tid] = polar_emb[tid];
    if (tid < KL_) mo_s[tid] = main_ori[bh * KL_ + tid];

    {
        int row = tid >> 1, half = tid & 1;
        const float* src = &qkv_k[(size_t)(b * KL_ + row) * TDIM_ + h * HD_ + half * 16];
#pragma unroll
        for (int j = 0; j < 16; ++j) Kk_s[row][half * 16 + j] = f2bf(src[DIM_ + j]);
#pragma unroll
        for (int j = 0; j < 16; ++j) VT_s[half * 16 + j][row] = f2bf(src[2 * DIM_ + j]);
    }
    __syncthreads();

#pragma unroll
    for (int i = 0; i < 8; ++i) {
        int id = tid + 256 * i;
        int k = id >> 4, cc = id & 15;
        size_t gb = (size_t)(b * KL_ + k) * XL_ + x0 + cc * 4;
        int4 r4 = *(const int4*)&rd[gb];
        int4 p4 = *(const int4*)&polar_pos[gb];
        int mo = mo_s[k];
        int n0 = p4.x - mo; n0 += (n0 >> 31) & PB_;
        int n1 = p4.y - mo; n1 += (n1 >> 31) & PB_;
        int n2 = p4.z - mo; n2 += (n2 >> 31) & PB_;
        int n3 = p4.w - mo; n3 += (n3 >> 31) & PB_;
        rp_s[k][cc * 4 + 0] = (unsigned short)(r4.x | (n0 << 8));
        rp_s[k][cc * 4 + 1] = (unsigned short)(r4.y | (n1 << 8));
        rp_s[k][cc * 4 + 2] = (unsigned short)(r4.z | (n2 << 8));
        rp_s[k][cc * 4 + 3] = (unsigned short)(r4.w | (n3 << 8));
    }
    __syncthreads();
#pragma unroll
    for (int i = 0; i < 8; ++i) {
        int id = tid + 256 * i;
        int xr = id >> 5, kc = id & 31;
        int4 m4 = *(const int4*)&att_mask[(bh * XL_ + x0 + xr) * KL_ + kc * 4];
        if (m4.x) rp_s[kc * 4 + 0][xr] |= 0x8000;
        if (m4.y) rp_s[kc * 4 + 1][xr] |= 0x8000;
        if (m4.z) rp_s[kc * 4 + 2][xr] |= 0x8000;
        if (m4.w) rp_s[kc * 4 + 3][xr] |= 0x8000;
    }
    __syncthreads();

    v8s aq;
    {
        const float* qp = &qkv_x[(size_t)(b * XL_ + x0 + wave * 16 + c) * TDIM_ + h * HD_ + q * 8];
        float4 q0 = *(const float4*)&qp[0];
        float4 q1 = *(const float4*)&qp[4];
        aq[0] = (short)f2bf(q0.x); aq[1] = (short)f2bf(q0.y);
        aq[2] = (short)f2bf(q0.z); aq[3] = (short)f2bf(q0.w);
        aq[4] = (short)f2bf(q1.x); aq[5] = (short)f2bf(q1.y);
        aq[6] = (short)f2bf(q1.z); aq[7] = (short)f2bf(q1.w);
    }

    v4f S[8];
#pragma unroll
    for (int t = 0; t < 8; ++t) {
        v8s bk = *(v8s*)&Kk_s[t * 16 + c][q * 8];
        S[t] = __builtin_amdgcn_mfma_f32_16x16x32_bf16(aq, bk, (v4f){0.f, 0.f, 0.f, 0.f}, 0, 0, 0);
    }

    const int xloc = wave * 16;
    float lr[4] = {0.f, 0.f, 0.f, 0.f};
#pragma unroll
    for (int t = 0; t < 8; ++t) {
#pragma unroll
        for (int r = 0; r < 4; ++r) {
            int krow = t * 16 + c;
            int xrow = q * 4 + r;
            unsigned short rp = rp_s[krow][xloc + xrow];
            float sval = S[t][r] * SCALE_;
            float tval = ((rp & 0x8000) ? -25.0f : sval) + de_h[rp & 0x7f] + pe[(rp >> 8) & 7];
            float p = __expf(tval);
            unsigned short pb = f2bf(p);
            P_s[wave][xrow][krow] = pb;
            lr[r] += bf2f(pb);
        }
    }
#pragma unroll
    for (int r = 0; r < 4; ++r) {
#pragma unroll
        for (int m = 1; m < 16; m <<= 1) lr[r] += __shfl_xor(lr[r], m);
    }
    __syncthreads();

    v4f O0 = {0.f, 0.f, 0.f, 0.f}, O1 = {0.f, 0.f, 0.f, 0.f};
#pragma unroll
    for (int kc = 0; kc < 4; ++kc) {
        v8s ap = *(v8s*)&P_s[wave][c][kc * 32 + q * 8];
        v8s bv0 = *(v8s*)&VT_s[c][kc * 32 + q * 8];
        v8s bv1 = *(v8s*)&VT_s[16 + c][kc * 32 + q * 8];
        O0 = __builtin_amdgcn_mfma_f32_16x16x32_bf16(ap, bv0, O0, 0, 0, 0);
        O1 = __builtin_amdgcn_mfma_f32_16x16x32_bf16(ap, bv1, O1, 0, 0, 0);
    }

#pragma unroll
    for (int r = 0; r < 4; ++r) {
        int xg = x0 + wave * 16 + q * 4 + r;
        float inv = 1.0f / lr[r];
        size_t obase = (size_t)(b * XL_ + xg) * DIM_ + h * HD_;
        float v0 = O0[r] * inv;
        float v1 = O1[r] * inv;
        unsigned short h0, l0, h1, l1;
        cvt_hilo(v0, h0, l0);
        cvt_hilo(v1, h1, l1);
        oh[obase + c] = h0;
        ol[obase + c] = l0;
        oh[obase + 16 + c] = h1;
        ol[obase + 16 + c] = l1;
    }
}

// ---------------------------------------------------------------------------
extern "C" void kernel_launch(void* const* d_in, const int* in_sizes, int n_in,
                              void* d_out, int out_size, void* d_ws, size_t ws_size,
                              hipStream_t stream) {
    const float* x         = (const float*)d_in[0];
    const float* kernal    = (const float*)d_in[1];
    const int* rd          = (const int*)d_in[2];
    const int* polar_pos   = (const int*)d_in[3];
    const int* att_mask    = (const int*)d_in[4];
    const float* W_qkv     = (const float*)d_in[5];
    const float* dis_embed = (const float*)d_in[6];
    const float* polar_emb = (const float*)d_in[7];
    const float* W_proj    = (const float*)d_in[8];
    const float* b_proj    = (const float*)d_in[9];
    float* out             = (float*)d_out;

    char* base = (char*)d_ws;
    size_t off = 0;
    auto alloc = [&](size_t bytes) { void* p = base + off; off = (off + bytes + 255) & ~255ULL; return p; };
    float* qkv_x    = (float*)alloc((size_t)B_ * XL_ * TDIM_ * 4);
    float* qkv_k    = (float*)alloc((size_t)B_ * KL_ * TDIM_ * 4);
    float* xout_pre = (float*)alloc((size_t)B_ * XL_ * DIM_ * 4);   // binspart alias
    float* kout_pre = (float*)alloc((size_t)B_ * KL_ * DIM_ * 4);
    int* main_ori   = (int*)alloc(B_ * H_ * KL_ * 4);
    float* part     = (float*)alloc((size_t)B_ * H_ * KL_ * NS_ * 36 * 4);
    __hip_bfloat16* Sg = (__hip_bfloat16*)alloc((size_t)B_ * H_ * KL_ * XL_ * 2);
    unsigned short* wph = (unsigned short*)alloc((size_t)DIM_ * DIM_ * 2);
    unsigned short* wpl = (unsigned short*)alloc((size_t)DIM_ * DIM_ * 2);

    float* binspart = xout_pre;                        // dead region alias
    const size_t MX = (size_t)B_ * XL_;
    unsigned short* xh = (unsigned short*)Sg;
    unsigned short* xl_ = xh + MX * DIM_;
    unsigned short* wqh = (unsigned short*)part;
    unsigned short* wql = wqh + (size_t)TDIM_ * DIM_;
    unsigned short* kqh_g = wqh + 2 * (size_t)TDIM_ * DIM_;
    unsigned short* kql_g = kqh_g + (size_t)B_ * H_ * KL_ * HD_;
    unsigned short* oh = (unsigned short*)Sg;
    unsigned short* ol = oh + MX * DIM_;

    // --- operand conversion ---
    cvt_mat<<<dim3((MX * DIM_ / 4 + 255) / 256), 256, 0, stream>>>(x, xh, xl_, MX * DIM_ / 4);
    cvt_wT<<<dim3(TDIM_), DIM_, 0, stream>>>(W_qkv, wqh, wql, DIM_, TDIM_);
    cvt_wT<<<dim3(DIM_), DIM_, 0, stream>>>(W_proj, wph, wpl, DIM_, DIM_);

    // --- qkv projections ---
    gemm_mfma<<<dim3(TDIM_ / 128, MX / 128), 256, 0, stream>>>(
        xh, xl_, wqh, wql, qkv_x, nullptr, MX, TDIM_, DIM_);
    gemm64<<<dim3(TDIM_ / 64, (B_ * KL_) / 64), 256, 0, stream>>>(
        kernal, W_qkv, qkv_k, nullptr, B_ * KL_, TDIM_, DIM_);
    cvt_kq<<<dim3(B_ * H_), 256, 0, stream>>>(qkv_k, kqh_g, kql_g);

    // --- k-direction ---
    score_bins_mfma4<<<dim3(NCH2_, H_, B_), 256, 0, stream>>>(
        qkv_x, kqh_g, kql_g, rd, polar_pos, att_mask, dis_embed, Sg, binspart);
    bins_argmax<<<dim3(B_ * H_ * KL_ / 4), 256, 0, stream>>>(binspart, main_ori);
    flash_cached2<<<dim3((KL_ / KC2_) * NS_, H_, B_), 256, 0, stream>>>(
        qkv_x, Sg, polar_pos, polar_emb, main_ori, part);
    merge_cached<<<dim3(B_ * H_ * KL_ / 8), 256, 0, stream>>>(part, kout_pre);

    // --- x-direction ---
    attn_x_mfma<<<dim3(XL_ / 64, H_, B_), 256, 0, stream>>>(
        qkv_x, qkv_k, rd, polar_pos, att_mask, dis_embed, polar_emb, main_ori, oh, ol);

    // --- output projections ---
    gemm_mfma<<<dim3(DIM_ / 128, MX / 128), 256, 0, stream>>>(
        oh, ol, wph, wpl, out, b_proj, MX, DIM_, DIM_);
    gemm64<<<dim3(DIM_ / 64, (B_ * KL_) / 64), 256, 0, stream>>>(
        kout_pre, W_proj, out + (size_t)B_ * XL_ * DIM_, b_proj, B_ * KL_, DIM_, DIM_);
}